// Round 3
// baseline (1973.969 us; speedup 1.0000x reference)
//
#include <hip/hip_runtime.h>
#include <math.h>

#define NND 8192
#define FIN 256
#define NE 131072
#define TOTE (NE + NND)
#define KTOP 17
#define NSELN 4096
#define NCLSN 10
#define EPSF 1e-8f
#define RSTRIP 512
#define NSTRIP (NND / RSTRIP)

#define BKK 32
#define LDP 68
#define LDS2 132

// ---------------- utility fills ----------------
__global__ void fill_f32(float* p, float v, int n) {
  int i = blockIdx.x * blockDim.x + threadIdx.x;
  int st = gridDim.x * blockDim.x;
  for (; i < n; i += st) p[i] = v;
}
__global__ void fill_i32(int* p, int v, int n) {
  int i = blockIdx.x * blockDim.x + threadIdx.x;
  int st = gridDim.x * blockDim.x;
  for (; i < n; i += st) p[i] = v;
}

// ---------------- fea = elu(x * (c0*ps + c1*st)) ----------------
__global__ void fea_elu_kernel(const float* __restrict__ x, const float* __restrict__ cw,
                               const float* __restrict__ ps, const float* __restrict__ st,
                               float* __restrict__ fea) {
  int i = blockIdx.x * blockDim.x + threadIdx.x;
  const int total = NND * FIN / 4;
  int stride = gridDim.x * blockDim.x;
  float c0 = cw[0], c1 = cw[1];
  const float4* x4 = (const float4*)x;
  const float4* ps4 = (const float4*)ps;
  const float4* st4 = (const float4*)st;
  float4* f4 = (float4*)fea;
  for (; i < total; i += stride) {
    int j4 = i & (FIN / 4 - 1);
    float4 xv = x4[i], pv = ps4[j4], sv = st4[j4];
    float4 r;
    float t;
    t = xv.x * (c0 * pv.x + c1 * sv.x); r.x = t > 0.0f ? t : expm1f(t);
    t = xv.y * (c0 * pv.y + c1 * sv.y); r.y = t > 0.0f ? t : expm1f(t);
    t = xv.z * (c0 * pv.z + c1 * sv.z); r.z = t > 0.0f ? t : expm1f(t);
    t = xv.w * (c0 * pv.w + c1 * sv.w); r.w = t > 0.0f ? t : expm1f(t);
    f4[i] = r;
  }
}

// ---------------- degree (dst occurrences) ----------------
__global__ void deg_kernel(const int* __restrict__ ei, float* __restrict__ deg) {
  int e = blockIdx.x * blockDim.x + threadIdx.x;
  if (e < NE) atomicAdd(&deg[ei[NE + e]], 1.0f);
}

__global__ void dinv_kernel(const float* __restrict__ deg, float* __restrict__ dinv,
                            int* __restrict__ cntN) {
  int i = blockIdx.x * blockDim.x + threadIdx.x;
  if (i < NND) {
    float d = deg[i];
    dinv[i] = 1.0f / sqrtf(d);
    cntN[i] = (int)(d + 0.5f);
  }
}

// ---------------- exclusive scan of 8192 ints, one block of 1024 ----------------
__global__ __launch_bounds__(1024) void scan_kernel(const int* __restrict__ cnt,
                                                    int* __restrict__ rowptr) {
  __shared__ int wtot[17];
  int tid = threadIdx.x;
  int lane = tid & 63;
  int v[8], pre[8];
  int s = 0;
  int base = tid * 8;
#pragma unroll
  for (int u = 0; u < 8; ++u) { v[u] = cnt[base + u]; s += v[u]; pre[u] = s; }
  int tsum = s;
  int x = tsum;
#pragma unroll
  for (int off = 1; off < 64; off <<= 1) {
    int t = __shfl_up(x, off);
    if (lane >= off) x += t;
  }
  if (lane == 63) wtot[tid >> 6] = x;
  __syncthreads();
  if (tid == 0) {
    int run = 0;
    for (int w = 0; w < 16; ++w) { int t = wtot[w]; wtot[w] = run; run += t; }
    wtot[16] = run;
  }
  __syncthreads();
  int basex = wtot[tid >> 6] + (x - tsum);
#pragma unroll
  for (int u = 0; u < 8; ++u) rowptr[base + u] = basex + pre[u] - v[u];
  if (tid == 0) rowptr[NND] = wtot[16];
}

// ---------------- CSR fill for normalized graph (row = dst, col = src) ----------------
__global__ void csr_norm_kernel(const int* __restrict__ ei, const float* __restrict__ dinv,
                                const int* __restrict__ rowptr, int* __restrict__ cur,
                                int* __restrict__ col, float* __restrict__ w) {
  int e = blockIdx.x * blockDim.x + threadIdx.x;
  if (e >= TOTE) return;
  int s, d;
  if (e < NE) { s = ei[e]; d = ei[NE + e]; } else { s = e - NE; d = s; }
  int pos = atomicAdd(&cur[d], 1);
  int at = rowptr[d] + pos;
  col[at] = s;
  w[at] = dinv[s] * dinv[d];
}

// ---------------- agg + h + row-normalize -> hn (N x 512) ----------------
__global__ __launch_bounds__(256) void agg_hn_kernel(const float* __restrict__ fea,
    const int* __restrict__ rpN, const int* __restrict__ colN, const float* __restrict__ wN,
    const float* __restrict__ bal, float* __restrict__ hn) {
  int i = blockIdx.x, j = threadIdx.x;
  float f = fea[(size_t)i * 256 + j];
  float acc = 0.0f;
  int e0 = rpN[i], e1 = rpN[i + 1];
  for (int e = e0; e < e1; ++e) acc += wN[e] * fea[(size_t)colN[e] * 256 + j];
  float hl = f * bal[j];
  float hh = acc * bal[256 + j];
  float ss = hl * hl + hh * hh;
  __shared__ float red[4];
  __shared__ float bc;
#pragma unroll
  for (int off = 32; off >= 1; off >>= 1) ss += __shfl_down(ss, off);
  if ((j & 63) == 0) red[j >> 6] = ss;
  __syncthreads();
  if (j == 0) bc = sqrtf(red[0] + red[1] + red[2] + red[3]);
  __syncthreads();
  float inv = 1.0f / (bc + EPSF);
  hn[(size_t)i * 512 + j] = hl * inv;
  hn[(size_t)i * 512 + 256 + j] = hh * inv;
}

// ---------------- strip GEMM: strip[r - r0][c] = hn[r] . hn[c], 128x128 tiles ----------------
__global__ __launch_bounds__(256) void gemm_strip_kernel(const float* __restrict__ hn,
                                                         float* __restrict__ strip, int r0) {
  __shared__ float As[16 * LDS2];
  __shared__ float Bs[16 * LDS2];
  int arow0 = r0 + blockIdx.y * 128;
  int brow0 = blockIdx.x * 128;
  int tid = threadIdx.x;
  int tx = tid & 15, ty = tid >> 4;
  int g4 = tid & 3;       // float4 index within the 16-K slab
  int rbase = tid >> 2;   // 0..63
  const float4* hn4 = (const float4*)hn;
  float acc[8][8] = {{0.f}};
  for (int kt = 0; kt < 32; ++kt) {
    __syncthreads();
#pragma unroll
    for (int h = 0; h < 2; ++h) {
      int row = rbase + h * 64;
      float4 a = hn4[(size_t)(arow0 + row) * 128 + kt * 4 + g4];
      As[(g4 * 4 + 0) * LDS2 + row] = a.x;
      As[(g4 * 4 + 1) * LDS2 + row] = a.y;
      As[(g4 * 4 + 2) * LDS2 + row] = a.z;
      As[(g4 * 4 + 3) * LDS2 + row] = a.w;
      float4 b = hn4[(size_t)(brow0 + row) * 128 + kt * 4 + g4];
      Bs[(g4 * 4 + 0) * LDS2 + row] = b.x;
      Bs[(g4 * 4 + 1) * LDS2 + row] = b.y;
      Bs[(g4 * 4 + 2) * LDS2 + row] = b.z;
      Bs[(g4 * 4 + 3) * LDS2 + row] = b.w;
    }
    __syncthreads();
#pragma unroll
    for (int k = 0; k < 16; ++k) {
      float4 a0 = *(const float4*)&As[k * LDS2 + ty * 8];
      float4 a1 = *(const float4*)&As[k * LDS2 + ty * 8 + 4];
      float4 b0 = *(const float4*)&Bs[k * LDS2 + tx * 8];
      float4 b1 = *(const float4*)&Bs[k * LDS2 + tx * 8 + 4];
      float aa[8] = {a0.x, a0.y, a0.z, a0.w, a1.x, a1.y, a1.z, a1.w};
      float bb[8] = {b0.x, b0.y, b0.z, b0.w, b1.x, b1.y, b1.z, b1.w};
#pragma unroll
      for (int q = 0; q < 8; ++q)
#pragma unroll
        for (int c = 0; c < 8; ++c) acc[q][c] = fmaf(aa[q], bb[c], acc[q][c]);
    }
  }
  int lr = blockIdx.y * 128 + ty * 8;   // row within strip
  int gc = brow0 + tx * 8;
#pragma unroll
  for (int q = 0; q < 8; ++q) {
    *(float4*)&strip[(size_t)(lr + q) * NND + gc] =
        make_float4(acc[q][0], acc[q][1], acc[q][2], acc[q][3]);
    *(float4*)&strip[(size_t)(lr + q) * NND + gc + 4] =
        make_float4(acc[q][4], acc[q][5], acc[q][6], acc[q][7]);
  }
}

// ---------------- top-17 per strip row (registers, 17 argmax rounds) ----------------
__global__ __launch_bounds__(256) void topk_kernel(const float* __restrict__ strip,
                                                   float* __restrict__ tkv,
                                                   int* __restrict__ tki, int r0) {
  int gi = r0 + blockIdx.x;
  int tid = threadIdx.x;
  const float* srow = strip + (size_t)blockIdx.x * NND;
  float v[32];
#pragma unroll
  for (int u = 0; u < 32; ++u) v[u] = srow[u * 256 + tid];
  __shared__ float wv[4];
  __shared__ int wi[4];
  __shared__ int bgi;
  for (int r = 0; r < KTOP; ++r) {
    float mx = v[0];
    int mu = 0;
#pragma unroll
    for (int u = 1; u < 32; ++u)
      if (v[u] > mx) { mx = v[u]; mu = u; }
    int mcol = mu * 256 + tid;
#pragma unroll
    for (int off = 32; off >= 1; off >>= 1) {
      float ov = __shfl_down(mx, off);
      int oc = __shfl_down(mcol, off);
      if (ov > mx || (ov == mx && oc < mcol)) { mx = ov; mcol = oc; }
    }
    if ((tid & 63) == 0) { wv[tid >> 6] = mx; wi[tid >> 6] = mcol; }
    __syncthreads();
    if (tid == 0) {
      float b = wv[0];
      int bcid = wi[0];
#pragma unroll
      for (int w2 = 1; w2 < 4; ++w2)
        if (wv[w2] > b || (wv[w2] == b && wi[w2] < bcid)) { b = wv[w2]; bcid = wi[w2]; }
      tkv[gi * KTOP + r] = b;
      tki[gi * KTOP + r] = bcid;
      bgi = bcid;
    }
    __syncthreads();
    int wcol = bgi;
    if ((wcol & 255) == tid) {
      int uu = wcol >> 8;
#pragma unroll
      for (int u = 0; u < 32; ++u)
        if (u == uu) v[u] = -3.0e38f;
    }
    __syncthreads();
  }
}

// ---------------- symmetrized kNN weights + mirror counts ----------------
__global__ void sym_kernel(const float* __restrict__ tkv, const int* __restrict__ tki,
                           float* __restrict__ symw, int* __restrict__ symflag,
                           int* __restrict__ cntK) {
  int s = blockIdx.x * blockDim.x + threadIdx.x;
  if (s >= NND * KTOP) return;
  int i = s / KTOP;
  int j = tki[s];
  float vv = tkv[s];
  float v2 = 0.0f;
  int found = 0;
#pragma unroll
  for (int t = 0; t < KTOP; ++t) {
    if (tki[j * KTOP + t] == i) { found = 1; v2 = tkv[j * KTOP + t]; }
  }
  float w = found ? 0.5f * (vv + v2) : vv;
  w = fmaxf(w, 0.0f);
  symw[s] = w;
  symflag[s] = 1 - found;
  if (!found) atomicAdd(&cntK[j], 1);
}

__global__ void csr_knn_kernel(const int* __restrict__ tki, const float* __restrict__ symw,
                               const int* __restrict__ symflag, const int* __restrict__ rpK,
                               int* __restrict__ curK, int* __restrict__ colK,
                               float* __restrict__ wK) {
  int s = blockIdx.x * blockDim.x + threadIdx.x;
  if (s >= NND * KTOP) return;
  int i = s / KTOP, k = s - i * KTOP;
  int j = tki[s];
  float w = symw[s];
  int at = rpK[i] + k;
  colK[at] = j;
  wK[at] = w;
  if (symflag[s]) {
    int p = atomicAdd(&curK[j], 1);
    int at2 = rpK[j] + KTOP + p;
    colK[at2] = i;
    wK[at2] = w;
  }
}

// ---------------- dense C(8192x256) = A(8192xK) @ B(Kx256) ----------------
__global__ __launch_bounds__(256) void gemm_rm_kernel(const float* __restrict__ A,
                                                      const float* __restrict__ B,
                                                      float* __restrict__ C, int K) {
  __shared__ float As[BKK * LDP];
  __shared__ float Bs[BKK * LDP];
  int bj = blockIdx.x, bi = blockIdx.y;
  int tid = threadIdx.x;
  int tx = tid & 15, ty = tid >> 4;
  const float4* A4 = (const float4*)A;
  const float4* B4 = (const float4*)B;
  int K4 = K >> 2;
  float acc[4][4] = {{0.f}};
  for (int kt = 0; kt < K / BKK; ++kt) {
    __syncthreads();
    {
      int rr = tid >> 3, k4 = tid & 7;
#pragma unroll
      for (int h = 0; h < 2; ++h) {
        int row = rr + h * 32;
        float4 a = A4[(size_t)(bi * 64 + row) * K4 + kt * 8 + k4];
        As[(k4 * 4 + 0) * LDP + row] = a.x;
        As[(k4 * 4 + 1) * LDP + row] = a.y;
        As[(k4 * 4 + 2) * LDP + row] = a.z;
        As[(k4 * 4 + 3) * LDP + row] = a.w;
      }
      int kk = tid >> 4, c4 = tid & 15;
#pragma unroll
      for (int h = 0; h < 2; ++h) {
        int krow = kk + h * 16;
        float4 b = B4[(size_t)(kt * 32 + krow) * 64 + bj * 16 + c4];
        *(float4*)&Bs[krow * LDP + c4 * 4] = b;
      }
    }
    __syncthreads();
#pragma unroll
    for (int k = 0; k < BKK; ++k) {
      float4 av = *(const float4*)&As[k * LDP + ty * 4];
      float4 bv = *(const float4*)&Bs[k * LDP + tx * 4];
      float aa[4] = {av.x, av.y, av.z, av.w};
      float bb[4] = {bv.x, bv.y, bv.z, bv.w};
#pragma unroll
      for (int q = 0; q < 4; ++q)
#pragma unroll
        for (int c = 0; c < 4; ++c) acc[q][c] = fmaf(aa[q], bb[c], acc[q][c]);
    }
  }
  int r0 = bi * 64 + ty * 4, c0 = bj * 64 + tx * 4;
#pragma unroll
  for (int q = 0; q < 4; ++q) {
    float4 v = make_float4(acc[q][0], acc[q][1], acc[q][2], acc[q][3]);
    *(float4*)&C[(size_t)(r0 + q) * 256 + c0] = v;
  }
}

// ---------------- SpMM: out = alpha*Anorm@X + (1-alpha)*Wsym@X (+relu) ----------------
__global__ __launch_bounds__(256) void spmm_kernel(const float* __restrict__ X,
    const int* __restrict__ rpN, const int* __restrict__ colN, const float* __restrict__ wN,
    const int* __restrict__ rpK, const int* __restrict__ colK, const float* __restrict__ wK,
    const float* __restrict__ alphaP, float* __restrict__ out, int doRelu) {
  int i = blockIdx.x, j = threadIdx.x;
  float alpha = alphaP[0];
  float accN = 0.0f, accK = 0.0f;
  int e0 = rpN[i], e1 = rpN[i + 1];
  for (int e = e0; e < e1; ++e) accN += wN[e] * X[(size_t)colN[e] * 256 + j];
  e0 = rpK[i];
  e1 = rpK[i + 1];
  for (int e = e0; e < e1; ++e) accK += wK[e] * X[(size_t)colK[e] * 256 + j];
  float r = alpha * accN + (1.0f - alpha) * accK;
  if (doRelu) r = fmaxf(r, 0.0f);
  out[(size_t)i * 256 + j] = r;
}

// ---------------- prototypes ----------------
__global__ void proto_kernel(const float* __restrict__ emb, const int* __restrict__ labels,
                             const int* __restrict__ nodeidx, float* __restrict__ proto,
                             float* __restrict__ cntC) {
  int rr = blockIdx.x, j = threadIdx.x;
  int lab = labels[rr], ni = nodeidx[rr];
  atomicAdd(&proto[lab * 256 + j], emb[(size_t)ni * 256 + j]);
  if (j == 0) atomicAdd(&cntC[lab], 1.0f);
}

__global__ void pn_kernel(const float* __restrict__ proto, const float* __restrict__ cntC,
                          float* __restrict__ pn) {
  int c = blockIdx.x, j = threadIdx.x;
  float p = proto[c * 256 + j] / fmaxf(cntC[c], 1.0f);
  float ss = p * p;
  __shared__ float red[4];
  __shared__ float bc;
#pragma unroll
  for (int off = 32; off >= 1; off >>= 1) ss += __shfl_down(ss, off);
  if ((j & 63) == 0) red[j >> 6] = ss;
  __syncthreads();
  if (j == 0) bc = sqrtf(red[0] + red[1] + red[2] + red[3]);
  __syncthreads();
  pn[c * 256 + j] = p / (bc + EPSF);
}

__global__ void out_kernel(const float* __restrict__ emb, const int* __restrict__ nodeidx,
                           const float* __restrict__ pn, float* __restrict__ outp) {
  int rr = blockIdx.x, j = threadIdx.x;
  int ni = nodeidx[rr];
  float v = emb[(size_t)ni * 256 + j];
  __shared__ float red[4];
  __shared__ float bc;
  float ss = v * v;
#pragma unroll
  for (int off = 32; off >= 1; off >>= 1) ss += __shfl_down(ss, off);
  if ((j & 63) == 0) red[j >> 6] = ss;
  __syncthreads();
  if (j == 0) bc = sqrtf(red[0] + red[1] + red[2] + red[3]);
  __syncthreads();
  float inv = 1.0f / (bc + EPSF);
  for (int c = 0; c < NCLSN; ++c) {
    float part = v * pn[c * 256 + j];
#pragma unroll
    for (int off = 32; off >= 1; off >>= 1) part += __shfl_down(part, off);
    __syncthreads();
    if ((j & 63) == 0) red[j >> 6] = part;
    __syncthreads();
    if (j == 0) outp[rr * NCLSN + c] = ((red[0] + red[1] + red[2] + red[3]) * inv) / 0.2f;
  }
}

// ---------------- host launcher ----------------
extern "C" void kernel_launch(void* const* d_in, const int* in_sizes, int n_in,
                              void* d_out, int out_size, void* d_ws, size_t ws_size,
                              hipStream_t stream) {
  (void)in_sizes; (void)n_in;
  const float* x      = (const float*)d_in[0];
  const float* cw     = (const float*)d_in[1];
  const float* alphaP = (const float*)d_in[2];
  const float* ps     = (const float*)d_in[3];
  const float* st     = (const float*)d_in[4];
  const float* bal    = (const float*)d_in[5];
  const float* W1     = (const float*)d_in[6];
  const float* W2     = (const float*)d_in[7];
  const int*   ei     = (const int*)d_in[8];
  const int*   labels = (const int*)d_in[9];
  const int*   nodei  = (const int*)d_in[10];
  float* out = (float*)d_out;

  char* base = (char*)d_ws;
  size_t off = 0;
  auto alloc = [&](size_t bytes) -> void* {
    void* p = base + off;
    off += (bytes + 255) & ~(size_t)255;
    return p;
  };
  // Total footprint ~46 MB (was ~286 MB with dense sims -> ws bail -> zero output).
  float* fea    = (float*)alloc((size_t)NND * 256 * 4);      // 8 MB; reused as t2 later
  float* hn     = (float*)alloc((size_t)NND * 512 * 4);      // 16 MB; reused as emb later
  float* strip  = (float*)alloc((size_t)RSTRIP * NND * 4);   // 16 MB; reused as t1/h1 later
  float* deg    = (float*)alloc((size_t)NND * 4);
  float* dinv   = (float*)alloc((size_t)NND * 4);
  int*   cntN   = (int*)alloc((size_t)NND * 4);
  int*   rpN    = (int*)alloc((size_t)(NND + 1) * 4);
  int*   curN   = (int*)alloc((size_t)NND * 4);
  int*   colN   = (int*)alloc((size_t)TOTE * 4);
  float* wN     = (float*)alloc((size_t)TOTE * 4);
  float* tkv    = (float*)alloc((size_t)NND * KTOP * 4);
  int*   tki    = (int*)alloc((size_t)NND * KTOP * 4);
  float* symw   = (float*)alloc((size_t)NND * KTOP * 4);
  int*   symf   = (int*)alloc((size_t)NND * KTOP * 4);
  int*   cntK   = (int*)alloc((size_t)NND * 4);
  int*   rpK    = (int*)alloc((size_t)(NND + 1) * 4);
  int*   curK   = (int*)alloc((size_t)NND * 4);
  int*   colK   = (int*)alloc((size_t)2 * NND * KTOP * 4);
  float* wKv    = (float*)alloc((size_t)2 * NND * KTOP * 4);
  float* proto  = (float*)alloc((size_t)NCLSN * 256 * 4);
  float* cntC   = (float*)alloc((size_t)NCLSN * 4);
  float* pn     = (float*)alloc((size_t)NCLSN * 256 * 4);
  if (off > ws_size) {
    // sentinel: if this fires, out reads ~12345 (distinguishable from all-zeros)
    fill_f32<<<64, 256, 0, stream>>>(out, 12345.0f, out_size);
    return;
  }

  // aliases (lifetimes disjoint in stream order):
  float* t1  = strip;                               // after last topk
  float* h1  = strip + (size_t)NND * 256;           // second half of strip
  float* t2  = fea;                                 // fea dead after gemm_rm #1
  float* emb = hn;                                  // hn dead after last strip

  fill_f32<<<64, 256, 0, stream>>>(deg, 1.0f, NND);
  fill_i32<<<64, 256, 0, stream>>>(curN, 0, NND);
  fill_i32<<<64, 256, 0, stream>>>(cntK, KTOP, NND);
  fill_i32<<<64, 256, 0, stream>>>(curK, 0, NND);
  fill_f32<<<16, 256, 0, stream>>>(proto, 0.0f, NCLSN * 256);
  fill_f32<<<1, 64, 0, stream>>>(cntC, 0.0f, NCLSN);

  fea_elu_kernel<<<2048, 256, 0, stream>>>(x, cw, ps, st, fea);
  deg_kernel<<<NE / 256, 256, 0, stream>>>(ei, deg);
  dinv_kernel<<<NND / 256, 256, 0, stream>>>(deg, dinv, cntN);
  scan_kernel<<<1, 1024, 0, stream>>>(cntN, rpN);
  csr_norm_kernel<<<(TOTE + 255) / 256, 256, 0, stream>>>(ei, dinv, rpN, curN, colN, wN);
  agg_hn_kernel<<<NND, 256, 0, stream>>>(fea, rpN, colN, wN, bal, hn);

  for (int s = 0; s < NSTRIP; ++s) {
    gemm_strip_kernel<<<dim3(NND / 128, RSTRIP / 128), 256, 0, stream>>>(hn, strip,
                                                                         s * RSTRIP);
    topk_kernel<<<RSTRIP, 256, 0, stream>>>(strip, tkv, tki, s * RSTRIP);
  }

  sym_kernel<<<(NND * KTOP + 255) / 256, 256, 0, stream>>>(tkv, tki, symw, symf, cntK);
  scan_kernel<<<1, 1024, 0, stream>>>(cntK, rpK);
  csr_knn_kernel<<<(NND * KTOP + 255) / 256, 256, 0, stream>>>(tki, symw, symf, rpK, curK,
                                                               colK, wKv);

  gemm_rm_kernel<<<dim3(4, 128), 256, 0, stream>>>(fea, W1, t1, 256);
  spmm_kernel<<<NND, 256, 0, stream>>>(t1, rpN, colN, wN, rpK, colK, wKv, alphaP, h1, 1);
  gemm_rm_kernel<<<dim3(4, 128), 256, 0, stream>>>(h1, W2, t2, 256);
  spmm_kernel<<<NND, 256, 0, stream>>>(t2, rpN, colN, wN, rpK, colK, wKv, alphaP, emb, 0);

  proto_kernel<<<NSELN, 256, 0, stream>>>(emb, labels, nodei, proto, cntC);
  pn_kernel<<<NCLSN, 256, 0, stream>>>(proto, cntC, pn);
  out_kernel<<<NSELN, 256, 0, stream>>>(emb, nodei, pn, out);
}

// Round 4
// 1373.883 us; speedup vs baseline: 1.4368x; 1.4368x over previous
//
#include <hip/hip_runtime.h>
#include <hip/hip_bf16.h>
#include <math.h>

#define NND 8192
#define FIN 256
#define NE 131072
#define TOTE (NE + NND)
#define KTOP 17
#define NSELN 4096
#define NCLSN 10
#define EPSF 1e-8f
#define RSTRIP 512
#define NSTRIP (NND / RSTRIP)

#define BKK 32
#define LDP 68

typedef __attribute__((ext_vector_type(8))) short short8;
typedef __attribute__((ext_vector_type(4))) float f32x4;

// ---------------- utility fills ----------------
__global__ void fill_f32(float* p, float v, int n) {
  int i = blockIdx.x * blockDim.x + threadIdx.x;
  int st = gridDim.x * blockDim.x;
  for (; i < n; i += st) p[i] = v;
}
__global__ void fill_i32(int* p, int v, int n) {
  int i = blockIdx.x * blockDim.x + threadIdx.x;
  int st = gridDim.x * blockDim.x;
  for (; i < n; i += st) p[i] = v;
}

__device__ __forceinline__ void split_bf16(float v, short& h, short& l) {
  __hip_bfloat16 bh = __float2bfloat16(v);
  float fh = __bfloat162float(bh);
  __hip_bfloat16 bl = __float2bfloat16(v - fh);
  h = *reinterpret_cast<short*>(&bh);
  l = *reinterpret_cast<short*>(&bl);
}

// ---------------- fea = elu(x * (c0*ps + c1*st)) ----------------
__global__ void fea_elu_kernel(const float* __restrict__ x, const float* __restrict__ cw,
                               const float* __restrict__ ps, const float* __restrict__ st,
                               float* __restrict__ fea) {
  int i = blockIdx.x * blockDim.x + threadIdx.x;
  const int total = NND * FIN / 4;
  int stride = gridDim.x * blockDim.x;
  float c0 = cw[0], c1 = cw[1];
  const float4* x4 = (const float4*)x;
  const float4* ps4 = (const float4*)ps;
  const float4* st4 = (const float4*)st;
  float4* f4 = (float4*)fea;
  for (; i < total; i += stride) {
    int j4 = i & (FIN / 4 - 1);
    float4 xv = x4[i], pv = ps4[j4], sv = st4[j4];
    float4 r;
    float t;
    t = xv.x * (c0 * pv.x + c1 * sv.x); r.x = t > 0.0f ? t : expm1f(t);
    t = xv.y * (c0 * pv.y + c1 * sv.y); r.y = t > 0.0f ? t : expm1f(t);
    t = xv.z * (c0 * pv.z + c1 * sv.z); r.z = t > 0.0f ? t : expm1f(t);
    t = xv.w * (c0 * pv.w + c1 * sv.w); r.w = t > 0.0f ? t : expm1f(t);
    f4[i] = r;
  }
}

// ---------------- degree (dst occurrences) ----------------
__global__ void deg_kernel(const int* __restrict__ ei, float* __restrict__ deg) {
  int e = blockIdx.x * blockDim.x + threadIdx.x;
  if (e < NE) atomicAdd(&deg[ei[NE + e]], 1.0f);
}

__global__ void dinv_kernel(const float* __restrict__ deg, float* __restrict__ dinv,
                            int* __restrict__ cntN) {
  int i = blockIdx.x * blockDim.x + threadIdx.x;
  if (i < NND) {
    float d = deg[i];
    dinv[i] = 1.0f / sqrtf(d);
    cntN[i] = (int)(d + 0.5f);
  }
}

// ---------------- exclusive scan of 8192 ints, one block of 1024 ----------------
__global__ __launch_bounds__(1024) void scan_kernel(const int* __restrict__ cnt,
                                                    int* __restrict__ rowptr) {
  __shared__ int wtot[17];
  int tid = threadIdx.x;
  int lane = tid & 63;
  int v[8], pre[8];
  int s = 0;
  int base = tid * 8;
#pragma unroll
  for (int u = 0; u < 8; ++u) { v[u] = cnt[base + u]; s += v[u]; pre[u] = s; }
  int tsum = s;
  int x = tsum;
#pragma unroll
  for (int off = 1; off < 64; off <<= 1) {
    int t = __shfl_up(x, off);
    if (lane >= off) x += t;
  }
  if (lane == 63) wtot[tid >> 6] = x;
  __syncthreads();
  if (tid == 0) {
    int run = 0;
    for (int w = 0; w < 16; ++w) { int t = wtot[w]; wtot[w] = run; run += t; }
    wtot[16] = run;
  }
  __syncthreads();
  int basex = wtot[tid >> 6] + (x - tsum);
#pragma unroll
  for (int u = 0; u < 8; ++u) rowptr[base + u] = basex + pre[u] - v[u];
  if (tid == 0) rowptr[NND] = wtot[16];
}

// ---------------- CSR fill for normalized graph (row = dst, col = src) ----------------
__global__ void csr_norm_kernel(const int* __restrict__ ei, const float* __restrict__ dinv,
                                const int* __restrict__ rowptr, int* __restrict__ cur,
                                int* __restrict__ col, float* __restrict__ w) {
  int e = blockIdx.x * blockDim.x + threadIdx.x;
  if (e >= TOTE) return;
  int s, d;
  if (e < NE) { s = ei[e]; d = ei[NE + e]; } else { s = e - NE; d = s; }
  int pos = atomicAdd(&cur[d], 1);
  int at = rowptr[d] + pos;
  col[at] = s;
  w[at] = dinv[s] * dinv[d];
}

// ---- agg + h + row-normalize -> hi/lo bf16 split (N x 512 each) ----
__global__ __launch_bounds__(256) void agg_hn_kernel(const float* __restrict__ fea,
    const int* __restrict__ rpN, const int* __restrict__ colN, const float* __restrict__ wN,
    const float* __restrict__ bal, short* __restrict__ hhi, short* __restrict__ hlo) {
  int i = blockIdx.x, j = threadIdx.x;
  float f = fea[(size_t)i * 256 + j];
  float acc = 0.0f;
  int e0 = rpN[i], e1 = rpN[i + 1];
  for (int e = e0; e < e1; ++e) acc += wN[e] * fea[(size_t)colN[e] * 256 + j];
  float hl = f * bal[j];
  float hh = acc * bal[256 + j];
  float ss = hl * hl + hh * hh;
  __shared__ float red[4];
  __shared__ float bc;
#pragma unroll
  for (int off = 32; off >= 1; off >>= 1) ss += __shfl_down(ss, off);
  if ((j & 63) == 0) red[j >> 6] = ss;
  __syncthreads();
  if (j == 0) bc = sqrtf(red[0] + red[1] + red[2] + red[3]);
  __syncthreads();
  float inv = 1.0f / (bc + EPSF);
  short h0, l0, h1, l1;
  split_bf16(hl * inv, h0, l0);
  split_bf16(hh * inv, h1, l1);
  hhi[(size_t)i * 512 + j] = h0;
  hlo[(size_t)i * 512 + j] = l0;
  hhi[(size_t)i * 512 + 256 + j] = h1;
  hlo[(size_t)i * 512 + 256 + j] = l1;
}

// ---- strip GEMM via split-bf16 MFMA: strip[r-r0][c] = hn[r].hn[c] ----
// sims = hi.hi^T + hi.lo^T + lo.hi^T  (3 K-passes, fp32 accumulate in MFMA)
__global__ __launch_bounds__(256) void gemm_strip_mfma(const short* __restrict__ hhi,
                                                       const short* __restrict__ hlo,
                                                       float* __restrict__ strip, int r0) {
  __shared__ short As[128 * 32];
  __shared__ short Bs[128 * 32];
  int bx = blockIdx.x;   // col tile (0..63)
  int by = blockIdx.y;   // row tile within strip (0..RSTRIP/128-1)
  int tid = threadIdx.x;
  int lane = tid & 63;
  int wid = tid >> 6;
  int wm = wid >> 1, wn = wid & 1;   // 2x2 wave grid, 64x64 per wave
  int arow0 = r0 + by * 128;
  int brow0 = bx * 128;

  int srow = tid >> 2;        // staging row 0..63
  int sch = tid & 3;          // staging chunk 0..3 (16B chunks of 64B row)
  f32x4 acc[4][4];
#pragma unroll
  for (int m = 0; m < 4; ++m)
#pragma unroll
    for (int n = 0; n < 4; ++n) acc[m][n] = (f32x4){0.f, 0.f, 0.f, 0.f};

  for (int s = 0; s < 48; ++s) {
    int pass = s >> 4;
    int k0 = (s & 15) * 32;
    const short* Apt = (pass == 2) ? hlo : hhi;
    const short* Bpt = (pass == 1) ? hlo : hhi;
    __syncthreads();
    {
      int r1 = srow, r2 = srow + 64;
      int c1 = sch ^ ((r1 >> 1) & 3);
      int c2 = sch ^ ((r2 >> 1) & 3);
      int4 a1 = *(const int4*)&Apt[(size_t)(arow0 + r1) * 512 + k0 + sch * 8];
      int4 a2 = *(const int4*)&Apt[(size_t)(arow0 + r2) * 512 + k0 + sch * 8];
      *(int4*)&As[r1 * 32 + c1 * 8] = a1;
      *(int4*)&As[r2 * 32 + c2 * 8] = a2;
      int4 b1 = *(const int4*)&Bpt[(size_t)(brow0 + r1) * 512 + k0 + sch * 8];
      int4 b2 = *(const int4*)&Bpt[(size_t)(brow0 + r2) * 512 + k0 + sch * 8];
      *(int4*)&Bs[r1 * 32 + c1 * 8] = b1;
      *(int4*)&Bs[r2 * 32 + c2 * 8] = b2;
    }
    __syncthreads();
    short8 af[4], bf[4];
#pragma unroll
    for (int m = 0; m < 4; ++m) {
      int rr = wm * 64 + m * 16 + (lane & 15);
      int ca = (lane >> 4) ^ ((rr >> 1) & 3);
      af[m] = *(const short8*)&As[rr * 32 + ca * 8];
      int cc = wn * 64 + m * 16 + (lane & 15);
      int cb = (lane >> 4) ^ ((cc >> 1) & 3);
      bf[m] = *(const short8*)&Bs[cc * 32 + cb * 8];
    }
#pragma unroll
    for (int m = 0; m < 4; ++m)
#pragma unroll
      for (int n = 0; n < 4; ++n)
        acc[m][n] = __builtin_amdgcn_mfma_f32_16x16x32_bf16(af[m], bf[n], acc[m][n], 0, 0, 0);
  }
  // C/D layout: col = lane&15, row = (lane>>4)*4 + r   [m89]
#pragma unroll
  for (int m = 0; m < 4; ++m) {
    int lr = by * 128 + wm * 64 + m * 16 + ((lane >> 4) << 2);
#pragma unroll
    for (int n = 0; n < 4; ++n) {
      int gc = bx * 128 + wn * 64 + n * 16 + (lane & 15);
#pragma unroll
      for (int r = 0; r < 4; ++r)
        strip[(size_t)(lr + r) * NND + gc] = acc[m][n][r];
    }
  }
}

// ---------------- top-17 per strip row (registers, 17 argmax rounds) ----------------
__global__ __launch_bounds__(256) void topk_kernel(const float* __restrict__ strip,
                                                   float* __restrict__ tkv,
                                                   int* __restrict__ tki, int r0) {
  int gi = r0 + blockIdx.x;
  int tid = threadIdx.x;
  const float* srow = strip + (size_t)blockIdx.x * NND;
  float v[32];
#pragma unroll
  for (int u = 0; u < 32; ++u) v[u] = srow[u * 256 + tid];
  __shared__ float wv[4];
  __shared__ int wi[4];
  __shared__ int bgi;
  for (int r = 0; r < KTOP; ++r) {
    float mx = v[0];
    int mu = 0;
#pragma unroll
    for (int u = 1; u < 32; ++u)
      if (v[u] > mx) { mx = v[u]; mu = u; }
    int mcol = mu * 256 + tid;
#pragma unroll
    for (int off = 32; off >= 1; off >>= 1) {
      float ov = __shfl_down(mx, off);
      int oc = __shfl_down(mcol, off);
      if (ov > mx || (ov == mx && oc < mcol)) { mx = ov; mcol = oc; }
    }
    if ((tid & 63) == 0) { wv[tid >> 6] = mx; wi[tid >> 6] = mcol; }
    __syncthreads();
    if (tid == 0) {
      float b = wv[0];
      int bcid = wi[0];
#pragma unroll
      for (int w2 = 1; w2 < 4; ++w2)
        if (wv[w2] > b || (wv[w2] == b && wi[w2] < bcid)) { b = wv[w2]; bcid = wi[w2]; }
      tkv[gi * KTOP + r] = b;
      tki[gi * KTOP + r] = bcid;
      bgi = bcid;
    }
    __syncthreads();
    int wcol = bgi;
    if ((wcol & 255) == tid) {
      int uu = wcol >> 8;
#pragma unroll
      for (int u = 0; u < 32; ++u)
        if (u == uu) v[u] = -3.0e38f;
    }
    __syncthreads();
  }
}

// ---------------- symmetrized kNN weights + mirror counts ----------------
__global__ void sym_kernel(const float* __restrict__ tkv, const int* __restrict__ tki,
                           float* __restrict__ symw, int* __restrict__ symflag,
                           int* __restrict__ cntK) {
  int s = blockIdx.x * blockDim.x + threadIdx.x;
  if (s >= NND * KTOP) return;
  int i = s / KTOP;
  int j = tki[s];
  float vv = tkv[s];
  float v2 = 0.0f;
  int found = 0;
#pragma unroll
  for (int t = 0; t < KTOP; ++t) {
    if (tki[j * KTOP + t] == i) { found = 1; v2 = tkv[j * KTOP + t]; }
  }
  float w = found ? 0.5f * (vv + v2) : vv;
  w = fmaxf(w, 0.0f);
  symw[s] = w;
  symflag[s] = 1 - found;
  if (!found) atomicAdd(&cntK[j], 1);
}

__global__ void csr_knn_kernel(const int* __restrict__ tki, const float* __restrict__ symw,
                               const int* __restrict__ symflag, const int* __restrict__ rpK,
                               int* __restrict__ curK, int* __restrict__ colK,
                               float* __restrict__ wK) {
  int s = blockIdx.x * blockDim.x + threadIdx.x;
  if (s >= NND * KTOP) return;
  int i = s / KTOP, k = s - i * KTOP;
  int j = tki[s];
  float w = symw[s];
  int at = rpK[i] + k;
  colK[at] = j;
  wK[at] = w;
  if (symflag[s]) {
    int p = atomicAdd(&curK[j], 1);
    int at2 = rpK[j] + KTOP + p;
    colK[at2] = i;
    wK[at2] = w;
  }
}

// ---------------- dense C(8192x256) = A(8192xK) @ B(Kx256) ----------------
__global__ __launch_bounds__(256) void gemm_rm_kernel(const float* __restrict__ A,
                                                      const float* __restrict__ B,
                                                      float* __restrict__ C, int K) {
  __shared__ float As[BKK * LDP];
  __shared__ float Bs[BKK * LDP];
  int bj = blockIdx.x, bi = blockIdx.y;
  int tid = threadIdx.x;
  int tx = tid & 15, ty = tid >> 4;
  const float4* A4 = (const float4*)A;
  const float4* B4 = (const float4*)B;
  int K4 = K >> 2;
  float acc[4][4] = {{0.f}};
  for (int kt = 0; kt < K / BKK; ++kt) {
    __syncthreads();
    {
      int rr = tid >> 3, k4 = tid & 7;
#pragma unroll
      for (int h = 0; h < 2; ++h) {
        int row = rr + h * 32;
        float4 a = A4[(size_t)(bi * 64 + row) * K4 + kt * 8 + k4];
        As[(k4 * 4 + 0) * LDP + row] = a.x;
        As[(k4 * 4 + 1) * LDP + row] = a.y;
        As[(k4 * 4 + 2) * LDP + row] = a.z;
        As[(k4 * 4 + 3) * LDP + row] = a.w;
      }
      int kk = tid >> 4, c4 = tid & 15;
#pragma unroll
      for (int h = 0; h < 2; ++h) {
        int krow = kk + h * 16;
        float4 b = B4[(size_t)(kt * 32 + krow) * 64 + bj * 16 + c4];
        *(float4*)&Bs[krow * LDP + c4 * 4] = b;
      }
    }
    __syncthreads();
#pragma unroll
    for (int k = 0; k < BKK; ++k) {
      float4 av = *(const float4*)&As[k * LDP + ty * 4];
      float4 bv = *(const float4*)&Bs[k * LDP + tx * 4];
      float aa[4] = {av.x, av.y, av.z, av.w};
      float bb[4] = {bv.x, bv.y, bv.z, bv.w};
#pragma unroll
      for (int q = 0; q < 4; ++q)
#pragma unroll
        for (int c = 0; c < 4; ++c) acc[q][c] = fmaf(aa[q], bb[c], acc[q][c]);
    }
  }
  int r0 = bi * 64 + ty * 4, c0 = bj * 64 + tx * 4;
#pragma unroll
  for (int q = 0; q < 4; ++q) {
    float4 v = make_float4(acc[q][0], acc[q][1], acc[q][2], acc[q][3]);
    *(float4*)&C[(size_t)(r0 + q) * 256 + c0] = v;
  }
}

// ---- SpMM: out = alpha*Anorm@X + (1-alpha)*Wsym@X (+relu), 4-way edge-parallel ----
__global__ __launch_bounds__(256) void spmm_kernel(const float* __restrict__ X,
    const int* __restrict__ rpN, const int* __restrict__ colN, const float* __restrict__ wN,
    const int* __restrict__ rpK, const int* __restrict__ colK, const float* __restrict__ wK,
    const float* __restrict__ alphaP, float* __restrict__ out, int doRelu) {
  int i = blockIdx.x;
  int tid = threadIdx.x;
  int g = tid >> 6;    // edge group (wave)
  int jt = tid & 63;   // float4 column
  float alpha = alphaP[0];
  const float4* X4 = (const float4*)X;
  float ax = 0.f, ay = 0.f, az = 0.f, aw = 0.f;
  float kx = 0.f, ky = 0.f, kz = 0.f, kw = 0.f;
  int e1 = rpN[i + 1];
  for (int e = rpN[i] + g; e < e1; e += 4) {
    float w = wN[e];
    float4 xv = X4[(size_t)colN[e] * 64 + jt];
    ax = fmaf(w, xv.x, ax); ay = fmaf(w, xv.y, ay);
    az = fmaf(w, xv.z, az); aw = fmaf(w, xv.w, aw);
  }
  e1 = rpK[i + 1];
  for (int e = rpK[i] + g; e < e1; e += 4) {
    float w = wK[e];
    float4 xv = X4[(size_t)colK[e] * 64 + jt];
    kx = fmaf(w, xv.x, kx); ky = fmaf(w, xv.y, ky);
    kz = fmaf(w, xv.z, kz); kw = fmaf(w, xv.w, kw);
  }
  float b = 1.0f - alpha;
  __shared__ float4 red[256];
  red[tid] = make_float4(alpha * ax + b * kx, alpha * ay + b * ky,
                         alpha * az + b * kz, alpha * aw + b * kw);
  __syncthreads();
  if (g == 0) {
    float4 r0 = red[jt], r1 = red[64 + jt], r2 = red[128 + jt], r3 = red[192 + jt];
    float4 r = make_float4(r0.x + r1.x + r2.x + r3.x, r0.y + r1.y + r2.y + r3.y,
                           r0.z + r1.z + r2.z + r3.z, r0.w + r1.w + r2.w + r3.w);
    if (doRelu) {
      r.x = fmaxf(r.x, 0.f); r.y = fmaxf(r.y, 0.f);
      r.z = fmaxf(r.z, 0.f); r.w = fmaxf(r.w, 0.f);
    }
    *(float4*)&out[(size_t)i * 256 + jt * 4] = r;
  }
}

// ---------------- prototypes ----------------
__global__ void proto_kernel(const float* __restrict__ emb, const int* __restrict__ labels,
                             const int* __restrict__ nodeidx, float* __restrict__ proto,
                             float* __restrict__ cntC) {
  int rr = blockIdx.x, j = threadIdx.x;
  int lab = labels[rr], ni = nodeidx[rr];
  atomicAdd(&proto[lab * 256 + j], emb[(size_t)ni * 256 + j]);
  if (j == 0) atomicAdd(&cntC[lab], 1.0f);
}

__global__ void pn_kernel(const float* __restrict__ proto, const float* __restrict__ cntC,
                          float* __restrict__ pn) {
  int c = blockIdx.x, j = threadIdx.x;
  float p = proto[c * 256 + j] / fmaxf(cntC[c], 1.0f);
  float ss = p * p;
  __shared__ float red[4];
  __shared__ float bc;
#pragma unroll
  for (int off = 32; off >= 1; off >>= 1) ss += __shfl_down(ss, off);
  if ((j & 63) == 0) red[j >> 6] = ss;
  __syncthreads();
  if (j == 0) bc = sqrtf(red[0] + red[1] + red[2] + red[3]);
  __syncthreads();
  pn[c * 256 + j] = p / (bc + EPSF);
}

__global__ void out_kernel(const float* __restrict__ emb, const int* __restrict__ nodeidx,
                           const float* __restrict__ pn, float* __restrict__ outp) {
  int rr = blockIdx.x, j = threadIdx.x;
  int ni = nodeidx[rr];
  float v = emb[(size_t)ni * 256 + j];
  __shared__ float red[4];
  __shared__ float bc;
  float ss = v * v;
#pragma unroll
  for (int off = 32; off >= 1; off >>= 1) ss += __shfl_down(ss, off);
  if ((j & 63) == 0) red[j >> 6] = ss;
  __syncthreads();
  if (j == 0) bc = sqrtf(red[0] + red[1] + red[2] + red[3]);
  __syncthreads();
  float inv = 1.0f / (bc + EPSF);
  for (int c = 0; c < NCLSN; ++c) {
    float part = v * pn[c * 256 + j];
#pragma unroll
    for (int off = 32; off >= 1; off >>= 1) part += __shfl_down(part, off);
    __syncthreads();
    if ((j & 63) == 0) red[j >> 6] = part;
    __syncthreads();
    if (j == 0) outp[rr * NCLSN + c] = ((red[0] + red[1] + red[2] + red[3]) * inv) / 0.2f;
  }
}

// ---------------- host launcher ----------------
extern "C" void kernel_launch(void* const* d_in, const int* in_sizes, int n_in,
                              void* d_out, int out_size, void* d_ws, size_t ws_size,
                              hipStream_t stream) {
  (void)in_sizes; (void)n_in;
  const float* x      = (const float*)d_in[0];
  const float* cw     = (const float*)d_in[1];
  const float* alphaP = (const float*)d_in[2];
  const float* ps     = (const float*)d_in[3];
  const float* st     = (const float*)d_in[4];
  const float* bal    = (const float*)d_in[5];
  const float* W1     = (const float*)d_in[6];
  const float* W2     = (const float*)d_in[7];
  const int*   ei     = (const int*)d_in[8];
  const int*   labels = (const int*)d_in[9];
  const int*   nodei  = (const int*)d_in[10];
  float* out = (float*)d_out;

  char* base = (char*)d_ws;
  size_t off = 0;
  auto alloc = [&](size_t bytes) -> void* {
    void* p = base + off;
    off += (bytes + 255) & ~(size_t)255;
    return p;
  };
  // ~46 MB total
  float* fea    = (float*)alloc((size_t)NND * 256 * 4);      // 8 MB; reused as t2
  short* hhi    = (short*)alloc((size_t)NND * 512 * 2);      // 8 MB; reused as emb
  short* hlo    = (short*)alloc((size_t)NND * 512 * 2);      // 8 MB
  float* strip  = (float*)alloc((size_t)RSTRIP * NND * 4);   // 16 MB; reused as t1/h1
  float* deg    = (float*)alloc((size_t)NND * 4);
  float* dinv   = (float*)alloc((size_t)NND * 4);
  int*   cntN   = (int*)alloc((size_t)NND * 4);
  int*   rpN    = (int*)alloc((size_t)(NND + 1) * 4);
  int*   curN   = (int*)alloc((size_t)NND * 4);
  int*   colN   = (int*)alloc((size_t)TOTE * 4);
  float* wN     = (float*)alloc((size_t)TOTE * 4);
  float* tkv    = (float*)alloc((size_t)NND * KTOP * 4);
  int*   tki    = (int*)alloc((size_t)NND * KTOP * 4);
  float* symw   = (float*)alloc((size_t)NND * KTOP * 4);
  int*   symf   = (int*)alloc((size_t)NND * KTOP * 4);
  int*   cntK   = (int*)alloc((size_t)NND * 4);
  int*   rpK    = (int*)alloc((size_t)(NND + 1) * 4);
  int*   curK   = (int*)alloc((size_t)NND * 4);
  int*   colK   = (int*)alloc((size_t)2 * NND * KTOP * 4);
  float* wKv    = (float*)alloc((size_t)2 * NND * KTOP * 4);
  float* proto  = (float*)alloc((size_t)NCLSN * 256 * 4);
  float* cntC   = (float*)alloc((size_t)NCLSN * 4);
  float* pn     = (float*)alloc((size_t)NCLSN * 256 * 4);
  if (off > ws_size) {
    fill_f32<<<64, 256, 0, stream>>>(out, 12345.0f, out_size);
    return;
  }

  // aliases (lifetimes disjoint in stream order):
  float* t1  = strip;                         // strip dead after last topk
  float* h1  = strip + (size_t)NND * 256;
  float* t2  = fea;                           // fea dead after gemm_rm #1
  float* emb = (float*)hhi;                   // hhi/hlo dead after last strip GEMM

  fill_f32<<<64, 256, 0, stream>>>(deg, 1.0f, NND);
  fill_i32<<<64, 256, 0, stream>>>(curN, 0, NND);
  fill_i32<<<64, 256, 0, stream>>>(cntK, KTOP, NND);
  fill_i32<<<64, 256, 0, stream>>>(curK, 0, NND);
  fill_f32<<<16, 256, 0, stream>>>(proto, 0.0f, NCLSN * 256);
  fill_f32<<<1, 64, 0, stream>>>(cntC, 0.0f, NCLSN);

  fea_elu_kernel<<<2048, 256, 0, stream>>>(x, cw, ps, st, fea);
  deg_kernel<<<NE / 256, 256, 0, stream>>>(ei, deg);
  dinv_kernel<<<NND / 256, 256, 0, stream>>>(deg, dinv, cntN);
  scan_kernel<<<1, 1024, 0, stream>>>(cntN, rpN);
  csr_norm_kernel<<<(TOTE + 255) / 256, 256, 0, stream>>>(ei, dinv, rpN, curN, colN, wN);
  agg_hn_kernel<<<NND, 256, 0, stream>>>(fea, rpN, colN, wN, bal, hhi, hlo);

  for (int s = 0; s < NSTRIP; ++s) {
    gemm_strip_mfma<<<dim3(NND / 128, RSTRIP / 128), 256, 0, stream>>>(hhi, hlo, strip,
                                                                       s * RSTRIP);
    topk_kernel<<<RSTRIP, 256, 0, stream>>>(strip, tkv, tki, s * RSTRIP);
  }

  sym_kernel<<<(NND * KTOP + 255) / 256, 256, 0, stream>>>(tkv, tki, symw, symf, cntK);
  scan_kernel<<<1, 1024, 0, stream>>>(cntK, rpK);
  csr_knn_kernel<<<(NND * KTOP + 255) / 256, 256, 0, stream>>>(tki, symw, symf, rpK, curK,
                                                               colK, wKv);

  gemm_rm_kernel<<<dim3(4, 128), 256, 0, stream>>>(fea, W1, t1, 256);
  spmm_kernel<<<NND, 256, 0, stream>>>(t1, rpN, colN, wN, rpK, colK, wKv, alphaP, h1, 1);
  gemm_rm_kernel<<<dim3(4, 128), 256, 0, stream>>>(h1, W2, t2, 256);
  spmm_kernel<<<NND, 256, 0, stream>>>(t2, rpN, colN, wN, rpK, colK, wKv, alphaP, emb, 0);

  proto_kernel<<<NSELN, 256, 0, stream>>>(emb, labels, nodei, proto, cntC);
  pn_kernel<<<NCLSN, 256, 0, stream>>>(proto, cntC, pn);
  out_kernel<<<NSELN, 256, 0, stream>>>(emb, nodei, pn, out);
}

// Round 5
// 884.043 us; speedup vs baseline: 2.2329x; 1.5541x over previous
//
#include <hip/hip_runtime.h>
#include <hip/hip_bf16.h>
#include <math.h>

#define NND 8192
#define FIN 256
#define NE 131072
#define TOTE (NE + NND)
#define KTOP 17
#define NSELN 4096
#define NCLSN 10
#define EPSF 1e-8f

#define BKK 32
#define LDP 68

typedef __attribute__((ext_vector_type(8))) short short8;
typedef __attribute__((ext_vector_type(4))) float f32x4;

// ---------------- utility fills ----------------
__global__ void fill_f32(float* p, float v, int n) {
  int i = blockIdx.x * blockDim.x + threadIdx.x;
  int st = gridDim.x * blockDim.x;
  for (; i < n; i += st) p[i] = v;
}

__global__ void init_misc(float* deg, int* curN, int* cntK, int* curK,
                          float* proto, float* cntC) {
  int i = blockIdx.x * blockDim.x + threadIdx.x;
  if (i < NND) {
    deg[i] = 1.0f;
    curN[i] = 0;
    cntK[i] = KTOP;
    curK[i] = 0;
  }
  if (i < NCLSN * 256) proto[i] = 0.0f;
  if (i < NCLSN) cntC[i] = 0.0f;
}

__device__ __forceinline__ void split_bf16(float v, short& h, short& l) {
  __hip_bfloat16 bh = __float2bfloat16(v);
  float fh = __bfloat162float(bh);
  __hip_bfloat16 bl = __float2bfloat16(v - fh);
  h = *reinterpret_cast<short*>(&bh);
  l = *reinterpret_cast<short*>(&bl);
}

// ---------------- fea = elu(x * (c0*ps + c1*st)) ----------------
__global__ void fea_elu_kernel(const float* __restrict__ x, const float* __restrict__ cw,
                               const float* __restrict__ ps, const float* __restrict__ st,
                               float* __restrict__ fea) {
  int i = blockIdx.x * blockDim.x + threadIdx.x;
  const int total = NND * FIN / 4;
  int stride = gridDim.x * blockDim.x;
  float c0 = cw[0], c1 = cw[1];
  const float4* x4 = (const float4*)x;
  const float4* ps4 = (const float4*)ps;
  const float4* st4 = (const float4*)st;
  float4* f4 = (float4*)fea;
  for (; i < total; i += stride) {
    int j4 = i & (FIN / 4 - 1);
    float4 xv = x4[i], pv = ps4[j4], sv = st4[j4];
    float4 r;
    float t;
    t = xv.x * (c0 * pv.x + c1 * sv.x); r.x = t > 0.0f ? t : expm1f(t);
    t = xv.y * (c0 * pv.y + c1 * sv.y); r.y = t > 0.0f ? t : expm1f(t);
    t = xv.z * (c0 * pv.z + c1 * sv.z); r.z = t > 0.0f ? t : expm1f(t);
    t = xv.w * (c0 * pv.w + c1 * sv.w); r.w = t > 0.0f ? t : expm1f(t);
    f4[i] = r;
  }
}

// ---------------- degree (dst occurrences) ----------------
__global__ void deg_kernel(const int* __restrict__ ei, float* __restrict__ deg) {
  int e = blockIdx.x * blockDim.x + threadIdx.x;
  if (e < NE) atomicAdd(&deg[ei[NE + e]], 1.0f);
}

__global__ void dinv_kernel(const float* __restrict__ deg, float* __restrict__ dinv,
                            int* __restrict__ cntN) {
  int i = blockIdx.x * blockDim.x + threadIdx.x;
  if (i < NND) {
    float d = deg[i];
    dinv[i] = 1.0f / sqrtf(d);
    cntN[i] = (int)(d + 0.5f);
  }
}

// ---------------- exclusive scan of 8192 ints, one block of 1024 ----------------
__global__ __launch_bounds__(1024) void scan_kernel(const int* __restrict__ cnt,
                                                    int* __restrict__ rowptr) {
  __shared__ int wtot[17];
  int tid = threadIdx.x;
  int lane = tid & 63;
  int v[8], pre[8];
  int s = 0;
  int base = tid * 8;
#pragma unroll
  for (int u = 0; u < 8; ++u) { v[u] = cnt[base + u]; s += v[u]; pre[u] = s; }
  int tsum = s;
  int x = tsum;
#pragma unroll
  for (int off = 1; off < 64; off <<= 1) {
    int t = __shfl_up(x, off);
    if (lane >= off) x += t;
  }
  if (lane == 63) wtot[tid >> 6] = x;
  __syncthreads();
  if (tid == 0) {
    int run = 0;
    for (int w = 0; w < 16; ++w) { int t = wtot[w]; wtot[w] = run; run += t; }
    wtot[16] = run;
  }
  __syncthreads();
  int basex = wtot[tid >> 6] + (x - tsum);
#pragma unroll
  for (int u = 0; u < 8; ++u) rowptr[base + u] = basex + pre[u] - v[u];
  if (tid == 0) rowptr[NND] = wtot[16];
}

// ---------------- CSR fill for normalized graph (row = dst, col = src) ----------------
__global__ void csr_norm_kernel(const int* __restrict__ ei, const float* __restrict__ dinv,
                                const int* __restrict__ rowptr, int* __restrict__ cur,
                                int* __restrict__ col, float* __restrict__ w) {
  int e = blockIdx.x * blockDim.x + threadIdx.x;
  if (e >= TOTE) return;
  int s, d;
  if (e < NE) { s = ei[e]; d = ei[NE + e]; } else { s = e - NE; d = s; }
  int pos = atomicAdd(&cur[d], 1);
  int at = rowptr[d] + pos;
  col[at] = s;
  w[at] = dinv[s] * dinv[d];
}

// ---- agg + h + row-normalize -> hi/lo bf16 split (N x 512 each) ----
__global__ __launch_bounds__(256) void agg_hn_kernel(const float* __restrict__ fea,
    const int* __restrict__ rpN, const int* __restrict__ colN, const float* __restrict__ wN,
    const float* __restrict__ bal, short* __restrict__ hhi, short* __restrict__ hlo) {
  int i = blockIdx.x, j = threadIdx.x;
  float f = fea[(size_t)i * 256 + j];
  float acc = 0.0f;
  int e0 = rpN[i], e1 = rpN[i + 1];
  for (int e = e0; e < e1; ++e) acc += wN[e] * fea[(size_t)colN[e] * 256 + j];
  float hl = f * bal[j];
  float hh = acc * bal[256 + j];
  float ss = hl * hl + hh * hh;
  __shared__ float red[4];
  __shared__ float bc;
#pragma unroll
  for (int off = 32; off >= 1; off >>= 1) ss += __shfl_down(ss, off);
  if ((j & 63) == 0) red[j >> 6] = ss;
  __syncthreads();
  if (j == 0) bc = sqrtf(red[0] + red[1] + red[2] + red[3]);
  __syncthreads();
  float inv = 1.0f / (bc + EPSF);
  short h0, l0, h1, l1;
  split_bf16(hl * inv, h0, l0);
  split_bf16(hh * inv, h1, l1);
  hhi[(size_t)i * 512 + j] = h0;
  hlo[(size_t)i * 512 + j] = l0;
  hhi[(size_t)i * 512 + 256 + j] = h1;
  hlo[(size_t)i * 512 + 256 + j] = l1;
}

// ---- strip GEMM via split-bf16 MFMA, combined hi/lo staging per k0 ----
// sims = hi.hi^T + hi.lo^T + lo.hi^T  (3 passes per k0, fp32 MFMA accumulate)
// blockIdx.x = row tile within strip, blockIdx.y = col tile (XCD: same-x shares A panel)
__global__ __launch_bounds__(256, 2) void gemm_strip_mfma(const short* __restrict__ hhi,
                                                          const short* __restrict__ hlo,
                                                          float* __restrict__ strip, int r0) {
  __shared__ short As[2][128 * 32];
  __shared__ short Bs[2][128 * 32];
  int by = blockIdx.x;   // row tile within strip
  int bx = blockIdx.y;   // col tile (0..63)
  int tid = threadIdx.x;
  int lane = tid & 63;
  int wid = tid >> 6;
  int wm = wid >> 1, wn = wid & 1;   // 2x2 wave grid, 64x64 per wave
  int arow0 = r0 + by * 128;
  int brow0 = bx * 128;

  int srow = tid >> 2;        // staging row 0..63
  int sch = tid & 3;          // staging chunk 0..3 (16B chunks of 64B row)
  int r1 = srow, r2 = srow + 64;
  int c1 = sch ^ ((r1 >> 1) & 3);
  int c2 = sch ^ ((r2 >> 1) & 3);

  f32x4 acc[4][4];
#pragma unroll
  for (int m = 0; m < 4; ++m)
#pragma unroll
    for (int n = 0; n < 4; ++n) acc[m][n] = (f32x4){0.f, 0.f, 0.f, 0.f};

  for (int k0 = 0; k0 < 512; k0 += 32) {
    __syncthreads();
    {
      size_t a1o = (size_t)(arow0 + r1) * 512 + k0 + sch * 8;
      size_t a2o = (size_t)(arow0 + r2) * 512 + k0 + sch * 8;
      size_t b1o = (size_t)(brow0 + r1) * 512 + k0 + sch * 8;
      size_t b2o = (size_t)(brow0 + r2) * 512 + k0 + sch * 8;
      int4 ah1 = *(const int4*)&hhi[a1o];
      int4 ah2 = *(const int4*)&hhi[a2o];
      int4 al1 = *(const int4*)&hlo[a1o];
      int4 al2 = *(const int4*)&hlo[a2o];
      int4 bh1 = *(const int4*)&hhi[b1o];
      int4 bh2 = *(const int4*)&hhi[b2o];
      int4 bl1 = *(const int4*)&hlo[b1o];
      int4 bl2 = *(const int4*)&hlo[b2o];
      *(int4*)&As[0][r1 * 32 + c1 * 8] = ah1;
      *(int4*)&As[0][r2 * 32 + c2 * 8] = ah2;
      *(int4*)&As[1][r1 * 32 + c1 * 8] = al1;
      *(int4*)&As[1][r2 * 32 + c2 * 8] = al2;
      *(int4*)&Bs[0][r1 * 32 + c1 * 8] = bh1;
      *(int4*)&Bs[0][r2 * 32 + c2 * 8] = bh2;
      *(int4*)&Bs[1][r1 * 32 + c1 * 8] = bl1;
      *(int4*)&Bs[1][r2 * 32 + c2 * 8] = bl2;
    }
    __syncthreads();
    short8 ah[4], al[4], bh[4], bl[4];
#pragma unroll
    for (int m = 0; m < 4; ++m) {
      int rr = wm * 64 + m * 16 + (lane & 15);
      int ca = (lane >> 4) ^ ((rr >> 1) & 3);
      ah[m] = *(const short8*)&As[0][rr * 32 + ca * 8];
      al[m] = *(const short8*)&As[1][rr * 32 + ca * 8];
      int cc = wn * 64 + m * 16 + (lane & 15);
      int cb = (lane >> 4) ^ ((cc >> 1) & 3);
      bh[m] = *(const short8*)&Bs[0][cc * 32 + cb * 8];
      bl[m] = *(const short8*)&Bs[1][cc * 32 + cb * 8];
    }
#pragma unroll
    for (int m = 0; m < 4; ++m)
#pragma unroll
      for (int n = 0; n < 4; ++n)
        acc[m][n] = __builtin_amdgcn_mfma_f32_16x16x32_bf16(ah[m], bh[n], acc[m][n], 0, 0, 0);
#pragma unroll
    for (int m = 0; m < 4; ++m)
#pragma unroll
      for (int n = 0; n < 4; ++n)
        acc[m][n] = __builtin_amdgcn_mfma_f32_16x16x32_bf16(ah[m], bl[n], acc[m][n], 0, 0, 0);
#pragma unroll
    for (int m = 0; m < 4; ++m)
#pragma unroll
      for (int n = 0; n < 4; ++n)
        acc[m][n] = __builtin_amdgcn_mfma_f32_16x16x32_bf16(al[m], bh[n], acc[m][n], 0, 0, 0);
  }
  // C/D layout: col = lane&15, row = (lane>>4)*4 + r
#pragma unroll
  for (int m = 0; m < 4; ++m) {
    int lr = by * 128 + wm * 64 + m * 16 + ((lane >> 4) << 2);
#pragma unroll
    for (int n = 0; n < 4; ++n) {
      int gc = bx * 128 + wn * 64 + n * 16 + (lane & 15);
#pragma unroll
      for (int r = 0; r < 4; ++r)
        strip[(size_t)(lr + r) * NND + gc] = acc[m][n][r];
    }
  }
}

// ---------------- top-17 per strip row (registers, 17 argmax rounds) ----------------
__global__ __launch_bounds__(256) void topk_kernel(const float* __restrict__ strip,
                                                   float* __restrict__ tkv,
                                                   int* __restrict__ tki, int r0) {
  int gi = r0 + blockIdx.x;
  int tid = threadIdx.x;
  const float* srow = strip + (size_t)blockIdx.x * NND;
  float v[32];
#pragma unroll
  for (int u = 0; u < 32; ++u) v[u] = srow[u * 256 + tid];
  __shared__ float wv[4];
  __shared__ int wi[4];
  __shared__ int bgi;
  for (int r = 0; r < KTOP; ++r) {
    float mx = v[0];
    int mu = 0;
#pragma unroll
    for (int u = 1; u < 32; ++u)
      if (v[u] > mx) { mx = v[u]; mu = u; }
    int mcol = mu * 256 + tid;
#pragma unroll
    for (int off = 32; off >= 1; off >>= 1) {
      float ov = __shfl_down(mx, off);
      int oc = __shfl_down(mcol, off);
      if (ov > mx || (ov == mx && oc < mcol)) { mx = ov; mcol = oc; }
    }
    if ((tid & 63) == 0) { wv[tid >> 6] = mx; wi[tid >> 6] = mcol; }
    __syncthreads();
    if (tid == 0) {
      float b = wv[0];
      int bcid = wi[0];
#pragma unroll
      for (int w2 = 1; w2 < 4; ++w2)
        if (wv[w2] > b || (wv[w2] == b && wi[w2] < bcid)) { b = wv[w2]; bcid = wi[w2]; }
      tkv[gi * KTOP + r] = b;
      tki[gi * KTOP + r] = bcid;
      bgi = bcid;
    }
    __syncthreads();
    int wcol = bgi;
    if ((wcol & 255) == tid) {
      int uu = wcol >> 8;
#pragma unroll
      for (int u = 0; u < 32; ++u)
        if (u == uu) v[u] = -3.0e38f;
    }
    __syncthreads();
  }
}

// ---------------- symmetrized kNN weights + mirror counts ----------------
__global__ void sym_kernel(const float* __restrict__ tkv, const int* __restrict__ tki,
                           float* __restrict__ symw, int* __restrict__ symflag,
                           int* __restrict__ cntK) {
  int s = blockIdx.x * blockDim.x + threadIdx.x;
  if (s >= NND * KTOP) return;
  int i = s / KTOP;
  int j = tki[s];
  float vv = tkv[s];
  float v2 = 0.0f;
  int found = 0;
#pragma unroll
  for (int t = 0; t < KTOP; ++t) {
    if (tki[j * KTOP + t] == i) { found = 1; v2 = tkv[j * KTOP + t]; }
  }
  float w = found ? 0.5f * (vv + v2) : vv;
  w = fmaxf(w, 0.0f);
  symw[s] = w;
  symflag[s] = 1 - found;
  if (!found) atomicAdd(&cntK[j], 1);
}

__global__ void csr_knn_kernel(const int* __restrict__ tki, const float* __restrict__ symw,
                               const int* __restrict__ symflag, const int* __restrict__ rpK,
                               int* __restrict__ curK, int* __restrict__ colK,
                               float* __restrict__ wK) {
  int s = blockIdx.x * blockDim.x + threadIdx.x;
  if (s >= NND * KTOP) return;
  int i = s / KTOP, k = s - i * KTOP;
  int j = tki[s];
  float w = symw[s];
  int at = rpK[i] + k;
  colK[at] = j;
  wK[at] = w;
  if (symflag[s]) {
    int p = atomicAdd(&curK[j], 1);
    int at2 = rpK[j] + KTOP + p;
    colK[at2] = i;
    wK[at2] = w;
  }
}

// ---------------- dense C(8192x256) = A(8192xK) @ B(Kx256) ----------------
__global__ __launch_bounds__(256) void gemm_rm_kernel(const float* __restrict__ A,
                                                      const float* __restrict__ B,
                                                      float* __restrict__ C, int K) {
  __shared__ float As[BKK * LDP];
  __shared__ float Bs[BKK * LDP];
  int bj = blockIdx.x, bi = blockIdx.y;
  int tid = threadIdx.x;
  int tx = tid & 15, ty = tid >> 4;
  const float4* A4 = (const float4*)A;
  const float4* B4 = (const float4*)B;
  int K4 = K >> 2;
  float acc[4][4] = {{0.f}};
  for (int kt = 0; kt < K / BKK; ++kt) {
    __syncthreads();
    {
      int rr = tid >> 3, k4 = tid & 7;
#pragma unroll
      for (int h = 0; h < 2; ++h) {
        int row = rr + h * 32;
        float4 a = A4[(size_t)(bi * 64 + row) * K4 + kt * 8 + k4];
        As[(k4 * 4 + 0) * LDP + row] = a.x;
        As[(k4 * 4 + 1) * LDP + row] = a.y;
        As[(k4 * 4 + 2) * LDP + row] = a.z;
        As[(k4 * 4 + 3) * LDP + row] = a.w;
      }
      int kk = tid >> 4, c4 = tid & 15;
#pragma unroll
      for (int h = 0; h < 2; ++h) {
        int krow = kk + h * 16;
        float4 b = B4[(size_t)(kt * 32 + krow) * 64 + bj * 16 + c4];
        *(float4*)&Bs[krow * LDP + c4 * 4] = b;
      }
    }
    __syncthreads();
#pragma unroll
    for (int k = 0; k < BKK; ++k) {
      float4 av = *(const float4*)&As[k * LDP + ty * 4];
      float4 bv = *(const float4*)&Bs[k * LDP + tx * 4];
      float aa[4] = {av.x, av.y, av.z, av.w};
      float bb[4] = {bv.x, bv.y, bv.z, bv.w};
#pragma unroll
      for (int q = 0; q < 4; ++q)
#pragma unroll
        for (int c = 0; c < 4; ++c) acc[q][c] = fmaf(aa[q], bb[c], acc[q][c]);
    }
  }
  int r0 = bi * 64 + ty * 4, c0 = bj * 64 + tx * 4;
#pragma unroll
  for (int q = 0; q < 4; ++q) {
    float4 v = make_float4(acc[q][0], acc[q][1], acc[q][2], acc[q][3]);
    *(float4*)&C[(size_t)(r0 + q) * 256 + c0] = v;
  }
}

// ---- SpMM: out = alpha*Anorm@X + (1-alpha)*Wsym@X (+relu), 4-way edge-parallel ----
__global__ __launch_bounds__(256) void spmm_kernel(const float* __restrict__ X,
    const int* __restrict__ rpN, const int* __restrict__ colN, const float* __restrict__ wN,
    const int* __restrict__ rpK, const int* __restrict__ colK, const float* __restrict__ wK,
    const float* __restrict__ alphaP, float* __restrict__ out, int doRelu) {
  int i = blockIdx.x;
  int tid = threadIdx.x;
  int g = tid >> 6;    // edge group (wave)
  int jt = tid & 63;   // float4 column
  float alpha = alphaP[0];
  const float4* X4 = (const float4*)X;
  float ax = 0.f, ay = 0.f, az = 0.f, aw = 0.f;
  float kx = 0.f, ky = 0.f, kz = 0.f, kw = 0.f;
  int e1 = rpN[i + 1];
  for (int e = rpN[i] + g; e < e1; e += 4) {
    float w = wN[e];
    float4 xv = X4[(size_t)colN[e] * 64 + jt];
    ax = fmaf(w, xv.x, ax); ay = fmaf(w, xv.y, ay);
    az = fmaf(w, xv.z, az); aw = fmaf(w, xv.w, aw);
  }
  e1 = rpK[i + 1];
  for (int e = rpK[i] + g; e < e1; e += 4) {
    float w = wK[e];
    float4 xv = X4[(size_t)colK[e] * 64 + jt];
    kx = fmaf(w, xv.x, kx); ky = fmaf(w, xv.y, ky);
    kz = fmaf(w, xv.z, kz); kw = fmaf(w, xv.w, kw);
  }
  float b = 1.0f - alpha;
  __shared__ float4 red[256];
  red[tid] = make_float4(alpha * ax + b * kx, alpha * ay + b * ky,
                         alpha * az + b * kz, alpha * aw + b * kw);
  __syncthreads();
  if (g == 0) {
    float4 r0 = red[jt], r1 = red[64 + jt], r2 = red[128 + jt], r3 = red[192 + jt];
    float4 r = make_float4(r0.x + r1.x + r2.x + r3.x, r0.y + r1.y + r2.y + r3.y,
                           r0.z + r1.z + r2.z + r3.z, r0.w + r1.w + r2.w + r3.w);
    if (doRelu) {
      r.x = fmaxf(r.x, 0.f); r.y = fmaxf(r.y, 0.f);
      r.z = fmaxf(r.z, 0.f); r.w = fmaxf(r.w, 0.f);
    }
    *(float4*)&out[(size_t)i * 256 + jt * 4] = r;
  }
}

// ---- prototypes: class-owned scan, no hot atomics ----
// grid = NCLSN * 8 blocks; block (c, chunk of 512 rows)
__global__ __launch_bounds__(256) void proto_kernel(const float* __restrict__ emb,
                                                    const int* __restrict__ labels,
                                                    const int* __restrict__ nodeidx,
                                                    float* __restrict__ proto,
                                                    float* __restrict__ cntC) {
  int c = blockIdx.x >> 3;
  int chunk = blockIdx.x & 7;
  int j = threadIdx.x;
  __shared__ int labL[512];
  __shared__ int niL[512];
  int r0 = chunk * 512;
  labL[j] = labels[r0 + j];
  labL[256 + j] = labels[r0 + 256 + j];
  niL[j] = nodeidx[r0 + j];
  niL[256 + j] = nodeidx[r0 + 256 + j];
  __syncthreads();
  float a0 = 0.f, a1 = 0.f, a2 = 0.f, a3 = 0.f;
  int cnt = 0;
  for (int r = 0; r < 512; r += 4) {
    int l0 = labL[r], l1 = labL[r + 1], l2 = labL[r + 2], l3 = labL[r + 3];
    if (l0 == c) a0 += emb[(size_t)niL[r] * 256 + j];
    if (l1 == c) a1 += emb[(size_t)niL[r + 1] * 256 + j];
    if (l2 == c) a2 += emb[(size_t)niL[r + 2] * 256 + j];
    if (l3 == c) a3 += emb[(size_t)niL[r + 3] * 256 + j];
    cnt += (l0 == c) + (l1 == c) + (l2 == c) + (l3 == c);
  }
  atomicAdd(&proto[c * 256 + j], (a0 + a1) + (a2 + a3));
  if (j == 0) atomicAdd(&cntC[c], (float)cnt);
}

__global__ void pn_kernel(const float* __restrict__ proto, const float* __restrict__ cntC,
                          float* __restrict__ pn) {
  int c = blockIdx.x, j = threadIdx.x;
  float p = proto[c * 256 + j] / fmaxf(cntC[c], 1.0f);
  float ss = p * p;
  __shared__ float red[4];
  __shared__ float bc;
#pragma unroll
  for (int off = 32; off >= 1; off >>= 1) ss += __shfl_down(ss, off);
  if ((j & 63) == 0) red[j >> 6] = ss;
  __syncthreads();
  if (j == 0) bc = sqrtf(red[0] + red[1] + red[2] + red[3]);
  __syncthreads();
  pn[c * 256 + j] = p / (bc + EPSF);
}

__global__ void out_kernel(const float* __restrict__ emb, const int* __restrict__ nodeidx,
                           const float* __restrict__ pn, float* __restrict__ outp) {
  int rr = blockIdx.x, j = threadIdx.x;
  int ni = nodeidx[rr];
  float v = emb[(size_t)ni * 256 + j];
  __shared__ float red[4];
  __shared__ float bc;
  float ss = v * v;
#pragma unroll
  for (int off = 32; off >= 1; off >>= 1) ss += __shfl_down(ss, off);
  if ((j & 63) == 0) red[j >> 6] = ss;
  __syncthreads();
  if (j == 0) bc = sqrtf(red[0] + red[1] + red[2] + red[3]);
  __syncthreads();
  float inv = 1.0f / (bc + EPSF);
  for (int c = 0; c < NCLSN; ++c) {
    float part = v * pn[c * 256 + j];
#pragma unroll
    for (int off = 32; off >= 1; off >>= 1) part += __shfl_down(part, off);
    __syncthreads();
    if ((j & 63) == 0) red[j >> 6] = part;
    __syncthreads();
    if (j == 0) outp[rr * NCLSN + c] = ((red[0] + red[1] + red[2] + red[3]) * inv) / 0.2f;
  }
}

// ---------------- host launcher ----------------
extern "C" void kernel_launch(void* const* d_in, const int* in_sizes, int n_in,
                              void* d_out, int out_size, void* d_ws, size_t ws_size,
                              hipStream_t stream) {
  (void)in_sizes; (void)n_in;
  const float* x      = (const float*)d_in[0];
  const float* cw     = (const float*)d_in[1];
  const float* alphaP = (const float*)d_in[2];
  const float* ps     = (const float*)d_in[3];
  const float* st     = (const float*)d_in[4];
  const float* bal    = (const float*)d_in[5];
  const float* W1     = (const float*)d_in[6];
  const float* W2     = (const float*)d_in[7];
  const int*   ei     = (const int*)d_in[8];
  const int*   labels = (const int*)d_in[9];
  const int*   nodei  = (const int*)d_in[10];
  float* out = (float*)d_out;

  char* base = (char*)d_ws;
  size_t off = 0;
  auto alloc = [&](size_t bytes) -> void* {
    void* p = base + off;
    off += (bytes + 255) & ~(size_t)255;
    return p;
  };
  float* fea    = (float*)alloc((size_t)NND * 256 * 4);      // 8 MB; reused as t2
  short* hhi    = (short*)alloc((size_t)NND * 512 * 2);      // 8 MB; reused as emb
  short* hlo    = (short*)alloc((size_t)NND * 512 * 2);      // 8 MB
  float* deg    = (float*)alloc((size_t)NND * 4);
  float* dinv   = (float*)alloc((size_t)NND * 4);
  int*   cntN   = (int*)alloc((size_t)NND * 4);
  int*   rpN    = (int*)alloc((size_t)(NND + 1) * 4);
  int*   curN   = (int*)alloc((size_t)NND * 4);
  int*   colN   = (int*)alloc((size_t)TOTE * 4);
  float* wN     = (float*)alloc((size_t)TOTE * 4);
  float* tkv    = (float*)alloc((size_t)NND * KTOP * 4);
  int*   tki    = (int*)alloc((size_t)NND * KTOP * 4);
  float* symw   = (float*)alloc((size_t)NND * KTOP * 4);
  int*   symf   = (int*)alloc((size_t)NND * KTOP * 4);
  int*   cntK   = (int*)alloc((size_t)NND * 4);
  int*   rpK    = (int*)alloc((size_t)(NND + 1) * 4);
  int*   curK   = (int*)alloc((size_t)NND * 4);
  int*   colK   = (int*)alloc((size_t)2 * NND * KTOP * 4);
  float* wKv    = (float*)alloc((size_t)2 * NND * KTOP * 4);
  float* proto  = (float*)alloc((size_t)NCLSN * 256 * 4);
  float* cntC   = (float*)alloc((size_t)NCLSN * 4);
  float* pn     = (float*)alloc((size_t)NCLSN * 256 * 4);

  // strip buffer last: pick the largest strip size that fits (1024 preferred, 512 min)
  size_t rem = (ws_size > off) ? (ws_size - off) : 0;
  int RS;
  if (rem >= (size_t)1024 * NND * 4) RS = 1024;
  else if (rem >= (size_t)512 * NND * 4) RS = 512;
  else {
    fill_f32<<<64, 256, 0, stream>>>(out, 12345.0f, out_size);
    return;
  }
  float* strip = (float*)alloc((size_t)RS * NND * 4);
  if (off > ws_size) {
    fill_f32<<<64, 256, 0, stream>>>(out, 12345.0f, out_size);
    return;
  }

  // aliases (lifetimes disjoint in stream order):
  float* t1  = strip;                         // strip dead after last topk
  float* h1  = strip + (size_t)NND * 256;
  float* t2  = fea;                           // fea dead after gemm_rm #1
  float* emb = (float*)hhi;                   // hhi/hlo dead after last strip GEMM

  init_misc<<<32, 256, 0, stream>>>(deg, curN, cntK, curK, proto, cntC);

  fea_elu_kernel<<<2048, 256, 0, stream>>>(x, cw, ps, st, fea);
  deg_kernel<<<NE / 256, 256, 0, stream>>>(ei, deg);
  dinv_kernel<<<NND / 256, 256, 0, stream>>>(deg, dinv, cntN);
  scan_kernel<<<1, 1024, 0, stream>>>(cntN, rpN);
  csr_norm_kernel<<<(TOTE + 255) / 256, 256, 0, stream>>>(ei, dinv, rpN, curN, colN, wN);
  agg_hn_kernel<<<NND, 256, 0, stream>>>(fea, rpN, colN, wN, bal, hhi, hlo);

  for (int s = 0; s < NND / RS; ++s) {
    gemm_strip_mfma<<<dim3(RS / 128, 64), 256, 0, stream>>>(hhi, hlo, strip, s * RS);
    topk_kernel<<<RS, 256, 0, stream>>>(strip, tkv, tki, s * RS);
  }

  sym_kernel<<<(NND * KTOP + 255) / 256, 256, 0, stream>>>(tkv, tki, symw, symf, cntK);
  scan_kernel<<<1, 1024, 0, stream>>>(cntK, rpK);
  csr_knn_kernel<<<(NND * KTOP + 255) / 256, 256, 0, stream>>>(tki, symw, symf, rpK, curK,
                                                               colK, wKv);

  gemm_rm_kernel<<<dim3(4, 128), 256, 0, stream>>>(fea, W1, t1, 256);
  spmm_kernel<<<NND, 256, 0, stream>>>(t1, rpN, colN, wN, rpK, colK, wKv, alphaP, h1, 1);
  gemm_rm_kernel<<<dim3(4, 128), 256, 0, stream>>>(h1, W2, t2, 256);
  spmm_kernel<<<NND, 256, 0, stream>>>(t2, rpN, colN, wN, rpK, colK, wKv, alphaP, emb, 0);

  proto_kernel<<<NCLSN * 8, 256, 0, stream>>>(emb, labels, nodei, proto, cntC);
  pn_kernel<<<NCLSN, 256, 0, stream>>>(proto, cntC, pn);
  out_kernel<<<NSELN, 256, 0, stream>>>(emb, nodei, pn, out);
}

// Round 6
// 856.788 us; speedup vs baseline: 2.3039x; 1.0318x over previous
//
#include <hip/hip_runtime.h>
#include <hip/hip_bf16.h>
#include <math.h>

#define NND 8192
#define FIN 256
#define NE 131072
#define TOTE (NE + NND)
#define KTOP 17
#define NSELN 4096
#define NCLSN 10
#define EPSF 1e-8f

#define BKK 32
#define LDP 68

typedef __attribute__((ext_vector_type(8))) short short8;
typedef __attribute__((ext_vector_type(4))) float f32x4;

// ---------------- utility fills ----------------
__global__ void fill_f32(float* p, float v, int n) {
  int i = blockIdx.x * blockDim.x + threadIdx.x;
  int st = gridDim.x * blockDim.x;
  for (; i < n; i += st) p[i] = v;
}

__global__ void init_misc(float* deg, int* curN, int* cntK, int* curK,
                          float* proto, float* cntC) {
  int i = blockIdx.x * blockDim.x + threadIdx.x;
  if (i < NND) {
    deg[i] = 1.0f;
    curN[i] = 0;
    cntK[i] = KTOP;
    curK[i] = 0;
  }
  if (i < NCLSN * 256) proto[i] = 0.0f;
  if (i < NCLSN) cntC[i] = 0.0f;
}

__device__ __forceinline__ void split_bf16(float v, short& h, short& l) {
  __hip_bfloat16 bh = __float2bfloat16(v);
  float fh = __bfloat162float(bh);
  __hip_bfloat16 bl = __float2bfloat16(v - fh);
  h = *reinterpret_cast<short*>(&bh);
  l = *reinterpret_cast<short*>(&bl);
}

// ---------------- fea = elu(x * (c0*ps + c1*st)) ----------------
__global__ void fea_elu_kernel(const float* __restrict__ x, const float* __restrict__ cw,
                               const float* __restrict__ ps, const float* __restrict__ st,
                               float* __restrict__ fea) {
  int i = blockIdx.x * blockDim.x + threadIdx.x;
  const int total = NND * FIN / 4;
  int stride = gridDim.x * blockDim.x;
  float c0 = cw[0], c1 = cw[1];
  const float4* x4 = (const float4*)x;
  const float4* ps4 = (const float4*)ps;
  const float4* st4 = (const float4*)st;
  float4* f4 = (float4*)fea;
  for (; i < total; i += stride) {
    int j4 = i & (FIN / 4 - 1);
    float4 xv = x4[i], pv = ps4[j4], sv = st4[j4];
    float4 r;
    float t;
    t = xv.x * (c0 * pv.x + c1 * sv.x); r.x = t > 0.0f ? t : expm1f(t);
    t = xv.y * (c0 * pv.y + c1 * sv.y); r.y = t > 0.0f ? t : expm1f(t);
    t = xv.z * (c0 * pv.z + c1 * sv.z); r.z = t > 0.0f ? t : expm1f(t);
    t = xv.w * (c0 * pv.w + c1 * sv.w); r.w = t > 0.0f ? t : expm1f(t);
    f4[i] = r;
  }
}

// ---------------- degree (dst occurrences) ----------------
__global__ void deg_kernel(const int* __restrict__ ei, float* __restrict__ deg) {
  int e = blockIdx.x * blockDim.x + threadIdx.x;
  if (e < NE) atomicAdd(&deg[ei[NE + e]], 1.0f);
}

__global__ void dinv_kernel(const float* __restrict__ deg, float* __restrict__ dinv,
                            int* __restrict__ cntN) {
  int i = blockIdx.x * blockDim.x + threadIdx.x;
  if (i < NND) {
    float d = deg[i];
    dinv[i] = 1.0f / sqrtf(d);
    cntN[i] = (int)(d + 0.5f);
  }
}

// ---------------- exclusive scan of 8192 ints, one block of 1024 ----------------
__global__ __launch_bounds__(1024) void scan_kernel(const int* __restrict__ cnt,
                                                    int* __restrict__ rowptr) {
  __shared__ int wtot[17];
  int tid = threadIdx.x;
  int lane = tid & 63;
  int v[8], pre[8];
  int s = 0;
  int base = tid * 8;
#pragma unroll
  for (int u = 0; u < 8; ++u) { v[u] = cnt[base + u]; s += v[u]; pre[u] = s; }
  int tsum = s;
  int x = tsum;
#pragma unroll
  for (int off = 1; off < 64; off <<= 1) {
    int t = __shfl_up(x, off);
    if (lane >= off) x += t;
  }
  if (lane == 63) wtot[tid >> 6] = x;
  __syncthreads();
  if (tid == 0) {
    int run = 0;
    for (int w = 0; w < 16; ++w) { int t = wtot[w]; wtot[w] = run; run += t; }
    wtot[16] = run;
  }
  __syncthreads();
  int basex = wtot[tid >> 6] + (x - tsum);
#pragma unroll
  for (int u = 0; u < 8; ++u) rowptr[base + u] = basex + pre[u] - v[u];
  if (tid == 0) rowptr[NND] = wtot[16];
}

// ---------------- CSR fill for normalized graph (row = dst, col = src) ----------------
__global__ void csr_norm_kernel(const int* __restrict__ ei, const float* __restrict__ dinv,
                                const int* __restrict__ rowptr, int* __restrict__ cur,
                                int* __restrict__ col, float* __restrict__ w) {
  int e = blockIdx.x * blockDim.x + threadIdx.x;
  if (e >= TOTE) return;
  int s, d;
  if (e < NE) { s = ei[e]; d = ei[NE + e]; } else { s = e - NE; d = s; }
  int pos = atomicAdd(&cur[d], 1);
  int at = rowptr[d] + pos;
  col[at] = s;
  w[at] = dinv[s] * dinv[d];
}

// ---- agg + h + row-normalize -> hi/lo bf16 split (N x 512 each) ----
__global__ __launch_bounds__(256) void agg_hn_kernel(const float* __restrict__ fea,
    const int* __restrict__ rpN, const int* __restrict__ colN, const float* __restrict__ wN,
    const float* __restrict__ bal, short* __restrict__ hhi, short* __restrict__ hlo) {
  int i = blockIdx.x, j = threadIdx.x;
  float f = fea[(size_t)i * 256 + j];
  float acc = 0.0f;
  int e0 = rpN[i], e1 = rpN[i + 1];
  for (int e = e0; e < e1; ++e) acc += wN[e] * fea[(size_t)colN[e] * 256 + j];
  float hl = f * bal[j];
  float hh = acc * bal[256 + j];
  float ss = hl * hl + hh * hh;
  __shared__ float red[4];
  __shared__ float bc;
#pragma unroll
  for (int off = 32; off >= 1; off >>= 1) ss += __shfl_down(ss, off);
  if ((j & 63) == 0) red[j >> 6] = ss;
  __syncthreads();
  if (j == 0) bc = sqrtf(red[0] + red[1] + red[2] + red[3]);
  __syncthreads();
  float inv = 1.0f / (bc + EPSF);
  short h0, l0, h1, l1;
  split_bf16(hl * inv, h0, l0);
  split_bf16(hh * inv, h1, l1);
  hhi[(size_t)i * 512 + j] = h0;
  hlo[(size_t)i * 512 + j] = l0;
  hhi[(size_t)i * 512 + 256 + j] = h1;
  hlo[(size_t)i * 512 + 256 + j] = l1;
}

// ---- strip GEMM via split-bf16 MFMA, T14 async-STAGE (load k0+1 early, write late) ----
// sims = hi.hi^T + hi.lo^T + lo.hi^T  (3 passes per k0, fp32 MFMA accumulate)
__global__ __launch_bounds__(256, 2) void gemm_strip_mfma(const short* __restrict__ hhi,
                                                          const short* __restrict__ hlo,
                                                          float* __restrict__ strip, int r0) {
  __shared__ short As[2][128 * 32];
  __shared__ short Bs[2][128 * 32];
  int by = blockIdx.x;   // row tile within strip
  int bx = blockIdx.y;   // col tile (0..63)
  int tid = threadIdx.x;
  int lane = tid & 63;
  int wid = tid >> 6;
  int wm = wid >> 1, wn = wid & 1;   // 2x2 wave grid, 64x64 per wave
  int arow0 = r0 + by * 128;
  int brow0 = bx * 128;

  int srow = tid >> 2;        // staging row 0..63
  int sch = tid & 3;          // staging chunk 0..3 (16B chunks of 64B row)
  int r1 = srow, r2 = srow + 64;
  int c1 = sch ^ ((r1 >> 1) & 3);
  int c2 = sch ^ ((r2 >> 1) & 3);
  size_t a1b = (size_t)(arow0 + r1) * 512 + sch * 8;
  size_t a2b = (size_t)(arow0 + r2) * 512 + sch * 8;
  size_t b1b = (size_t)(brow0 + r1) * 512 + sch * 8;
  size_t b2b = (size_t)(brow0 + r2) * 512 + sch * 8;

  int4 ah1, ah2, al1, al2, bh1, bh2, bl1, bl2;
#define LOADK(K0)                                        \
  {                                                      \
    ah1 = *(const int4*)&hhi[a1b + (K0)];                \
    ah2 = *(const int4*)&hhi[a2b + (K0)];                \
    al1 = *(const int4*)&hlo[a1b + (K0)];                \
    al2 = *(const int4*)&hlo[a2b + (K0)];                \
    bh1 = *(const int4*)&hhi[b1b + (K0)];                \
    bh2 = *(const int4*)&hhi[b2b + (K0)];                \
    bl1 = *(const int4*)&hlo[b1b + (K0)];                \
    bl2 = *(const int4*)&hlo[b2b + (K0)];                \
  }

  f32x4 acc[4][4];
#pragma unroll
  for (int m = 0; m < 4; ++m)
#pragma unroll
    for (int n = 0; n < 4; ++n) acc[m][n] = (f32x4){0.f, 0.f, 0.f, 0.f};

  LOADK(0);
  for (int k0 = 0; k0 < 512; k0 += 32) {
    __syncthreads();   // previous LDS consumers done
    *(int4*)&As[0][r1 * 32 + c1 * 8] = ah1;
    *(int4*)&As[0][r2 * 32 + c2 * 8] = ah2;
    *(int4*)&As[1][r1 * 32 + c1 * 8] = al1;
    *(int4*)&As[1][r2 * 32 + c2 * 8] = al2;
    *(int4*)&Bs[0][r1 * 32 + c1 * 8] = bh1;
    *(int4*)&Bs[0][r2 * 32 + c2 * 8] = bh2;
    *(int4*)&Bs[1][r1 * 32 + c1 * 8] = bl1;
    *(int4*)&Bs[1][r2 * 32 + c2 * 8] = bl2;
    if (k0 + 32 < 512) LOADK(k0 + 32);   // in flight across MFMA below (T14)
    __syncthreads();   // LDS ready
    short8 ah[4], al[4], bh[4], bl[4];
#pragma unroll
    for (int m = 0; m < 4; ++m) {
      int rr = wm * 64 + m * 16 + (lane & 15);
      int ca = (lane >> 4) ^ ((rr >> 1) & 3);
      ah[m] = *(const short8*)&As[0][rr * 32 + ca * 8];
      al[m] = *(const short8*)&As[1][rr * 32 + ca * 8];
      int cc = wn * 64 + m * 16 + (lane & 15);
      int cb = (lane >> 4) ^ ((cc >> 1) & 3);
      bh[m] = *(const short8*)&Bs[0][cc * 32 + cb * 8];
      bl[m] = *(const short8*)&Bs[1][cc * 32 + cb * 8];
    }
#pragma unroll
    for (int m = 0; m < 4; ++m)
#pragma unroll
      for (int n = 0; n < 4; ++n)
        acc[m][n] = __builtin_amdgcn_mfma_f32_16x16x32_bf16(ah[m], bh[n], acc[m][n], 0, 0, 0);
#pragma unroll
    for (int m = 0; m < 4; ++m)
#pragma unroll
      for (int n = 0; n < 4; ++n)
        acc[m][n] = __builtin_amdgcn_mfma_f32_16x16x32_bf16(ah[m], bl[n], acc[m][n], 0, 0, 0);
#pragma unroll
    for (int m = 0; m < 4; ++m)
#pragma unroll
      for (int n = 0; n < 4; ++n)
        acc[m][n] = __builtin_amdgcn_mfma_f32_16x16x32_bf16(al[m], bh[n], acc[m][n], 0, 0, 0);
  }
#undef LOADK
  // C/D layout: col = lane&15, row = (lane>>4)*4 + r
#pragma unroll
  for (int m = 0; m < 4; ++m) {
    int lr = by * 128 + wm * 64 + m * 16 + ((lane >> 4) << 2);
#pragma unroll
    for (int n = 0; n < 4; ++n) {
      int gc = bx * 128 + wn * 64 + n * 16 + (lane & 15);
#pragma unroll
      for (int r = 0; r < 4; ++r)
        strip[(size_t)(lr + r) * NND + gc] = acc[m][n][r];
    }
  }
}

// ---- top-17 per strip row: cached lane-local argmax, 1 sync/round ----
__global__ __launch_bounds__(256) void topk_kernel(const float* __restrict__ strip,
                                                   float* __restrict__ tkv,
                                                   int* __restrict__ tki, int r0) {
  int gi = r0 + blockIdx.x;
  int tid = threadIdx.x;
  int lane = tid & 63, wvid = tid >> 6;
  const float* srow = strip + (size_t)blockIdx.x * NND;
  float v[32];
#pragma unroll
  for (int u = 0; u < 32; ++u) v[u] = srow[u * 256 + tid];
  // lane-local running argmax (recomputed only by the thread that loses its max)
  float lmx = v[0];
  int lmu = 0;
#pragma unroll
  for (int u = 1; u < 32; ++u)
    if (v[u] > lmx) { lmx = v[u]; lmu = u; }

  __shared__ float swv[2][4];
  __shared__ int swi[2][4];
  for (int r = 0; r < KTOP; ++r) {
    int p = r & 1;
    float mx = lmx;
    int mcol = lmu * 256 + tid;
#pragma unroll
    for (int off = 32; off >= 1; off >>= 1) {
      float ov = __shfl_down(mx, off);
      int oc = __shfl_down(mcol, off);
      if (ov > mx || (ov == mx && oc < mcol)) { mx = ov; mcol = oc; }
    }
    if (lane == 0) { swv[p][wvid] = mx; swi[p][wvid] = mcol; }
    __syncthreads();
    float b = swv[p][0];
    int bc = swi[p][0];
#pragma unroll
    for (int w = 1; w < 4; ++w) {
      float bw = swv[p][w];
      int iw = swi[p][w];
      if (bw > b || (bw == b && iw < bc)) { b = bw; bc = iw; }
    }
    if (tid == 0) { tkv[gi * KTOP + r] = b; tki[gi * KTOP + r] = bc; }
    if ((bc & 255) == tid) {
      // the winner is always this thread's current max; remove + recompute
      int uu = bc >> 8;
#pragma unroll
      for (int u = 0; u < 32; ++u)
        if (u == uu) v[u] = -3.0e38f;
      lmx = v[0]; lmu = 0;
#pragma unroll
      for (int u = 1; u < 32; ++u)
        if (v[u] > lmx) { lmx = v[u]; lmu = u; }
    }
  }
}

// ---------------- symmetrized kNN weights + mirror counts ----------------
__global__ void sym_kernel(const float* __restrict__ tkv, const int* __restrict__ tki,
                           float* __restrict__ symw, int* __restrict__ symflag,
                           int* __restrict__ cntK) {
  int s = blockIdx.x * blockDim.x + threadIdx.x;
  if (s >= NND * KTOP) return;
  int i = s / KTOP;
  int j = tki[s];
  float vv = tkv[s];
  float v2 = 0.0f;
  int found = 0;
#pragma unroll
  for (int t = 0; t < KTOP; ++t) {
    if (tki[j * KTOP + t] == i) { found = 1; v2 = tkv[j * KTOP + t]; }
  }
  float w = found ? 0.5f * (vv + v2) : vv;
  w = fmaxf(w, 0.0f);
  symw[s] = w;
  symflag[s] = 1 - found;
  if (!found) atomicAdd(&cntK[j], 1);
}

__global__ void csr_knn_kernel(const int* __restrict__ tki, const float* __restrict__ symw,
                               const int* __restrict__ symflag, const int* __restrict__ rpK,
                               int* __restrict__ curK, int* __restrict__ colK,
                               float* __restrict__ wK) {
  int s = blockIdx.x * blockDim.x + threadIdx.x;
  if (s >= NND * KTOP) return;
  int i = s / KTOP, k = s - i * KTOP;
  int j = tki[s];
  float w = symw[s];
  int at = rpK[i] + k;
  colK[at] = j;
  wK[at] = w;
  if (symflag[s]) {
    int p = atomicAdd(&curK[j], 1);
    int at2 = rpK[j] + KTOP + p;
    colK[at2] = i;
    wK[at2] = w;
  }
}

// ---------------- dense C(8192x256) = A(8192xK) @ B(Kx256) ----------------
__global__ __launch_bounds__(256) void gemm_rm_kernel(const float* __restrict__ A,
                                                      const float* __restrict__ B,
                                                      float* __restrict__ C, int K) {
  __shared__ float As[BKK * LDP];
  __shared__ float Bs[BKK * LDP];
  int bj = blockIdx.x, bi = blockIdx.y;
  int tid = threadIdx.x;
  int tx = tid & 15, ty = tid >> 4;
  const float4* A4 = (const float4*)A;
  const float4* B4 = (const float4*)B;
  int K4 = K >> 2;
  float acc[4][4] = {{0.f}};
  for (int kt = 0; kt < K / BKK; ++kt) {
    __syncthreads();
    {
      int rr = tid >> 3, k4 = tid & 7;
#pragma unroll
      for (int h = 0; h < 2; ++h) {
        int row = rr + h * 32;
        float4 a = A4[(size_t)(bi * 64 + row) * K4 + kt * 8 + k4];
        As[(k4 * 4 + 0) * LDP + row] = a.x;
        As[(k4 * 4 + 1) * LDP + row] = a.y;
        As[(k4 * 4 + 2) * LDP + row] = a.z;
        As[(k4 * 4 + 3) * LDP + row] = a.w;
      }
      int kk = tid >> 4, c4 = tid & 15;
#pragma unroll
      for (int h = 0; h < 2; ++h) {
        int krow = kk + h * 16;
        float4 b = B4[(size_t)(kt * 32 + krow) * 64 + bj * 16 + c4];
        *(float4*)&Bs[krow * LDP + c4 * 4] = b;
      }
    }
    __syncthreads();
#pragma unroll
    for (int k = 0; k < BKK; ++k) {
      float4 av = *(const float4*)&As[k * LDP + ty * 4];
      float4 bv = *(const float4*)&Bs[k * LDP + tx * 4];
      float aa[4] = {av.x, av.y, av.z, av.w};
      float bb[4] = {bv.x, bv.y, bv.z, bv.w};
#pragma unroll
      for (int q = 0; q < 4; ++q)
#pragma unroll
        for (int c = 0; c < 4; ++c) acc[q][c] = fmaf(aa[q], bb[c], acc[q][c]);
    }
  }
  int r0 = bi * 64 + ty * 4, c0 = bj * 64 + tx * 4;
#pragma unroll
  for (int q = 0; q < 4; ++q) {
    float4 v = make_float4(acc[q][0], acc[q][1], acc[q][2], acc[q][3]);
    *(float4*)&C[(size_t)(r0 + q) * 256 + c0] = v;
  }
}

// ---- SpMM: out = alpha*Anorm@X + (1-alpha)*Wsym@X (+relu), 4-way edge-parallel ----
__global__ __launch_bounds__(256) void spmm_kernel(const float* __restrict__ X,
    const int* __restrict__ rpN, const int* __restrict__ colN, const float* __restrict__ wN,
    const int* __restrict__ rpK, const int* __restrict__ colK, const float* __restrict__ wK,
    const float* __restrict__ alphaP, float* __restrict__ out, int doRelu) {
  int i = blockIdx.x;
  int tid = threadIdx.x;
  int g = tid >> 6;    // edge group (wave)
  int jt = tid & 63;   // float4 column
  float alpha = alphaP[0];
  const float4* X4 = (const float4*)X;
  float ax = 0.f, ay = 0.f, az = 0.f, aw = 0.f;
  float kx = 0.f, ky = 0.f, kz = 0.f, kw = 0.f;
  int e1 = rpN[i + 1];
  for (int e = rpN[i] + g; e < e1; e += 4) {
    float w = wN[e];
    float4 xv = X4[(size_t)colN[e] * 64 + jt];
    ax = fmaf(w, xv.x, ax); ay = fmaf(w, xv.y, ay);
    az = fmaf(w, xv.z, az); aw = fmaf(w, xv.w, aw);
  }
  e1 = rpK[i + 1];
  for (int e = rpK[i] + g; e < e1; e += 4) {
    float w = wK[e];
    float4 xv = X4[(size_t)colK[e] * 64 + jt];
    kx = fmaf(w, xv.x, kx); ky = fmaf(w, xv.y, ky);
    kz = fmaf(w, xv.z, kz); kw = fmaf(w, xv.w, kw);
  }
  float b = 1.0f - alpha;
  __shared__ float4 red[256];
  red[tid] = make_float4(alpha * ax + b * kx, alpha * ay + b * ky,
                         alpha * az + b * kz, alpha * aw + b * kw);
  __syncthreads();
  if (g == 0) {
    float4 r0 = red[jt], r1 = red[64 + jt], r2 = red[128 + jt], r3 = red[192 + jt];
    float4 r = make_float4(r0.x + r1.x + r2.x + r3.x, r0.y + r1.y + r2.y + r3.y,
                           r0.z + r1.z + r2.z + r3.z, r0.w + r1.w + r2.w + r3.w);
    if (doRelu) {
      r.x = fmaxf(r.x, 0.f); r.y = fmaxf(r.y, 0.f);
      r.z = fmaxf(r.z, 0.f); r.w = fmaxf(r.w, 0.f);
    }
    *(float4*)&out[(size_t)i * 256 + jt * 4] = r;
  }
}

// ---- prototypes: class-owned scan, no hot atomics ----
__global__ __launch_bounds__(256) void proto_kernel(const float* __restrict__ emb,
                                                    const int* __restrict__ labels,
                                                    const int* __restrict__ nodeidx,
                                                    float* __restrict__ proto,
                                                    float* __restrict__ cntC) {
  int c = blockIdx.x >> 3;
  int chunk = blockIdx.x & 7;
  int j = threadIdx.x;
  __shared__ int labL[512];
  __shared__ int niL[512];
  int r0 = chunk * 512;
  labL[j] = labels[r0 + j];
  labL[256 + j] = labels[r0 + 256 + j];
  niL[j] = nodeidx[r0 + j];
  niL[256 + j] = nodeidx[r0 + 256 + j];
  __syncthreads();
  float a0 = 0.f, a1 = 0.f, a2 = 0.f, a3 = 0.f;
  int cnt = 0;
  for (int r = 0; r < 512; r += 4) {
    int l0 = labL[r], l1 = labL[r + 1], l2 = labL[r + 2], l3 = labL[r + 3];
    if (l0 == c) a0 += emb[(size_t)niL[r] * 256 + j];
    if (l1 == c) a1 += emb[(size_t)niL[r + 1] * 256 + j];
    if (l2 == c) a2 += emb[(size_t)niL[r + 2] * 256 + j];
    if (l3 == c) a3 += emb[(size_t)niL[r + 3] * 256 + j];
    cnt += (l0 == c) + (l1 == c) + (l2 == c) + (l3 == c);
  }
  atomicAdd(&proto[c * 256 + j], (a0 + a1) + (a2 + a3));
  if (j == 0) atomicAdd(&cntC[c], (float)cnt);
}

__global__ void pn_kernel(const float* __restrict__ proto, const float* __restrict__ cntC,
                          float* __restrict__ pn) {
  int c = blockIdx.x, j = threadIdx.x;
  float p = proto[c * 256 + j] / fmaxf(cntC[c], 1.0f);
  float ss = p * p;
  __shared__ float red[4];
  __shared__ float bc;
#pragma unroll
  for (int off = 32; off >= 1; off >>= 1) ss += __shfl_down(ss, off);
  if ((j & 63) == 0) red[j >> 6] = ss;
  __syncthreads();
  if (j == 0) bc = sqrtf(red[0] + red[1] + red[2] + red[3]);
  __syncthreads();
  pn[c * 256 + j] = p / (bc + EPSF);
}

__global__ void out_kernel(const float* __restrict__ emb, const int* __restrict__ nodeidx,
                           const float* __restrict__ pn, float* __restrict__ outp) {
  int rr = blockIdx.x, j = threadIdx.x;
  int ni = nodeidx[rr];
  float v = emb[(size_t)ni * 256 + j];
  __shared__ float red[4];
  __shared__ float bc;
  float ss = v * v;
#pragma unroll
  for (int off = 32; off >= 1; off >>= 1) ss += __shfl_down(ss, off);
  if ((j & 63) == 0) red[j >> 6] = ss;
  __syncthreads();
  if (j == 0) bc = sqrtf(red[0] + red[1] + red[2] + red[3]);
  __syncthreads();
  float inv = 1.0f / (bc + EPSF);
  for (int c = 0; c < NCLSN; ++c) {
    float part = v * pn[c * 256 + j];
#pragma unroll
    for (int off = 32; off >= 1; off >>= 1) part += __shfl_down(part, off);
    __syncthreads();
    if ((j & 63) == 0) red[j >> 6] = part;
    __syncthreads();
    if (j == 0) outp[rr * NCLSN + c] = ((red[0] + red[1] + red[2] + red[3]) * inv) / 0.2f;
  }
}

// ---------------- host launcher ----------------
extern "C" void kernel_launch(void* const* d_in, const int* in_sizes, int n_in,
                              void* d_out, int out_size, void* d_ws, size_t ws_size,
                              hipStream_t stream) {
  (void)in_sizes; (void)n_in;
  const float* x      = (const float*)d_in[0];
  const float* cw     = (const float*)d_in[1];
  const float* alphaP = (const float*)d_in[2];
  const float* ps     = (const float*)d_in[3];
  const float* st     = (const float*)d_in[4];
  const float* bal    = (const float*)d_in[5];
  const float* W1     = (const float*)d_in[6];
  const float* W2     = (const float*)d_in[7];
  const int*   ei     = (const int*)d_in[8];
  const int*   labels = (const int*)d_in[9];
  const int*   nodei  = (const int*)d_in[10];
  float* out = (float*)d_out;

  char* base = (char*)d_ws;
  size_t off = 0;
  auto alloc = [&](size_t bytes) -> void* {
    void* p = base + off;
    off += (bytes + 255) & ~(size_t)255;
    return p;
  };
  float* fea    = (float*)alloc((size_t)NND * 256 * 4);      // 8 MB; reused as t2
  short* hhi    = (short*)alloc((size_t)NND * 512 * 2);      // 8 MB; reused as emb
  short* hlo    = (short*)alloc((size_t)NND * 512 * 2);      // 8 MB
  float* deg    = (float*)alloc((size_t)NND * 4);
  float* dinv   = (float*)alloc((size_t)NND * 4);
  int*   cntN   = (int*)alloc((size_t)NND * 4);
  int*   rpN    = (int*)alloc((size_t)(NND + 1) * 4);
  int*   curN   = (int*)alloc((size_t)NND * 4);
  int*   colN   = (int*)alloc((size_t)TOTE * 4);
  float* wN     = (float*)alloc((size_t)TOTE * 4);
  float* tkv    = (float*)alloc((size_t)NND * KTOP * 4);
  int*   tki    = (int*)alloc((size_t)NND * KTOP * 4);
  float* symw   = (float*)alloc((size_t)NND * KTOP * 4);
  int*   symf   = (int*)alloc((size_t)NND * KTOP * 4);
  int*   cntK   = (int*)alloc((size_t)NND * 4);
  int*   rpK    = (int*)alloc((size_t)(NND + 1) * 4);
  int*   curK   = (int*)alloc((size_t)NND * 4);
  int*   colK   = (int*)alloc((size_t)2 * NND * KTOP * 4);
  float* wKv    = (float*)alloc((size_t)2 * NND * KTOP * 4);
  float* proto  = (float*)alloc((size_t)NCLSN * 256 * 4);
  float* cntC   = (float*)alloc((size_t)NCLSN * 4);
  float* pn     = (float*)alloc((size_t)NCLSN * 256 * 4);

  size_t rem = (ws_size > off) ? (ws_size - off) : 0;
  int RS;
  if (rem >= (size_t)1024 * NND * 4) RS = 1024;
  else if (rem >= (size_t)512 * NND * 4) RS = 512;
  else {
    fill_f32<<<64, 256, 0, stream>>>(out, 12345.0f, out_size);
    return;
  }
  float* strip = (float*)alloc((size_t)RS * NND * 4);
  if (off > ws_size) {
    fill_f32<<<64, 256, 0, stream>>>(out, 12345.0f, out_size);
    return;
  }

  // aliases (lifetimes disjoint in stream order):
  float* t1  = strip;                         // strip dead after last topk
  float* h1  = strip + (size_t)NND * 256;
  float* t2  = fea;                           // fea dead after gemm_rm #1
  float* emb = (float*)hhi;                   // hhi/hlo dead after last strip GEMM

  init_misc<<<32, 256, 0, stream>>>(deg, curN, cntK, curK, proto, cntC);

  fea_elu_kernel<<<2048, 256, 0, stream>>>(x, cw, ps, st, fea);
  deg_kernel<<<NE / 256, 256, 0, stream>>>(ei, deg);
  dinv_kernel<<<NND / 256, 256, 0, stream>>>(deg, dinv, cntN);
  scan_kernel<<<1, 1024, 0, stream>>>(cntN, rpN);
  csr_norm_kernel<<<(TOTE + 255) / 256, 256, 0, stream>>>(ei, dinv, rpN, curN, colN, wN);
  agg_hn_kernel<<<NND, 256, 0, stream>>>(fea, rpN, colN, wN, bal, hhi, hlo);

  for (int s = 0; s < NND / RS; ++s) {
    gemm_strip_mfma<<<dim3(RS / 128, 64), 256, 0, stream>>>(hhi, hlo, strip, s * RS);
    topk_kernel<<<RS, 256, 0, stream>>>(strip, tkv, tki, s * RS);
  }

  sym_kernel<<<(NND * KTOP + 255) / 256, 256, 0, stream>>>(tkv, tki, symw, symf, cntK);
  scan_kernel<<<1, 1024, 0, stream>>>(cntK, rpK);
  csr_knn_kernel<<<(NND * KTOP + 255) / 256, 256, 0, stream>>>(tki, symw, symf, rpK, curK,
                                                               colK, wKv);

  gemm_rm_kernel<<<dim3(4, 128), 256, 0, stream>>>(fea, W1, t1, 256);
  spmm_kernel<<<NND, 256, 0, stream>>>(t1, rpN, colN, wN, rpK, colK, wKv, alphaP, h1, 1);
  gemm_rm_kernel<<<dim3(4, 128), 256, 0, stream>>>(h1, W2, t2, 256);
  spmm_kernel<<<NND, 256, 0, stream>>>(t2, rpN, colN, wN, rpK, colK, wKv, alphaP, emb, 0);

  proto_kernel<<<NCLSN * 8, 256, 0, stream>>>(emb, labels, nodei, proto, cntC);
  pn_kernel<<<NCLSN, 256, 0, stream>>>(proto, cntC, pn);
  out_kernel<<<NSELN, 256, 0, stream>>>(emb, nodei, pn, out);
}

// Round 8
// 812.707 us; speedup vs baseline: 2.4289x; 1.0542x over previous
//
#include <hip/hip_runtime.h>
#include <hip/hip_bf16.h>
#include <math.h>

#define NND 8192
#define FIN 256
#define NE 131072
#define TOTE (NE + NND)
#define KTOP 17
#define NSELN 4096
#define NCLSN 10
#define EPSF 1e-8f

#define BKK 32
#define LDP 68

typedef __attribute__((ext_vector_type(8))) short short8;
typedef __attribute__((ext_vector_type(4))) float f32x4;

// async 16B global->LDS (dest = wave-uniform base + lane*16, src per-lane)
#define GL16(gp, lp)                                              \
  __builtin_amdgcn_global_load_lds(                               \
      (const __attribute__((address_space(1))) void*)(gp),        \
      (__attribute__((address_space(3))) void*)(lp), 16, 0, 0)

// ---------------- utility fills ----------------
__global__ void fill_f32(float* p, float v, int n) {
  int i = blockIdx.x * blockDim.x + threadIdx.x;
  int st = gridDim.x * blockDim.x;
  for (; i < n; i += st) p[i] = v;
}

__global__ void init_misc(float* deg, int* curN, int* cntK, int* curK,
                          float* proto, float* cntC) {
  int i = blockIdx.x * blockDim.x + threadIdx.x;
  if (i < NND) {
    deg[i] = 1.0f;
    curN[i] = 0;
    cntK[i] = KTOP;
    curK[i] = 0;
  }
  if (i < NCLSN * 256) proto[i] = 0.0f;
  if (i < NCLSN) cntC[i] = 0.0f;
}

__device__ __forceinline__ void split_bf16(float v, short& h, short& l) {
  __hip_bfloat16 bh = __float2bfloat16(v);
  float fh = __bfloat162float(bh);
  __hip_bfloat16 bl = __float2bfloat16(v - fh);
  h = *reinterpret_cast<short*>(&bh);
  l = *reinterpret_cast<short*>(&bl);
}

// ---------------- fea = elu(x * (c0*ps + c1*st)) ----------------
__global__ void fea_elu_kernel(const float* __restrict__ x, const float* __restrict__ cw,
                               const float* __restrict__ ps, const float* __restrict__ st,
                               float* __restrict__ fea) {
  int i = blockIdx.x * blockDim.x + threadIdx.x;
  const int total = NND * FIN / 4;
  int stride = gridDim.x * blockDim.x;
  float c0 = cw[0], c1 = cw[1];
  const float4* x4 = (const float4*)x;
  const float4* ps4 = (const float4*)ps;
  const float4* st4 = (const float4*)st;
  float4* f4 = (float4*)fea;
  for (; i < total; i += stride) {
    int j4 = i & (FIN / 4 - 1);
    float4 xv = x4[i], pv = ps4[j4], sv = st4[j4];
    float4 r;
    float t;
    t = xv.x * (c0 * pv.x + c1 * sv.x); r.x = t > 0.0f ? t : expm1f(t);
    t = xv.y * (c0 * pv.y + c1 * sv.y); r.y = t > 0.0f ? t : expm1f(t);
    t = xv.z * (c0 * pv.z + c1 * sv.z); r.z = t > 0.0f ? t : expm1f(t);
    t = xv.w * (c0 * pv.w + c1 * sv.w); r.w = t > 0.0f ? t : expm1f(t);
    f4[i] = r;
  }
}

// ---------------- degree (dst occurrences) ----------------
__global__ void deg_kernel(const int* __restrict__ ei, float* __restrict__ deg) {
  int e = blockIdx.x * blockDim.x + threadIdx.x;
  if (e < NE) atomicAdd(&deg[ei[NE + e]], 1.0f);
}

__global__ void dinv_kernel(const float* __restrict__ deg, float* __restrict__ dinv,
                            int* __restrict__ cntN) {
  int i = blockIdx.x * blockDim.x + threadIdx.x;
  if (i < NND) {
    float d = deg[i];
    dinv[i] = 1.0f / sqrtf(d);
    cntN[i] = (int)(d + 0.5f);
  }
}

// ---------------- exclusive scan of 8192 ints, one block of 1024 ----------------
__global__ __launch_bounds__(1024) void scan_kernel(const int* __restrict__ cnt,
                                                    int* __restrict__ rowptr) {
  __shared__ int wtot[17];
  int tid = threadIdx.x;
  int lane = tid & 63;
  int v[8], pre[8];
  int s = 0;
  int base = tid * 8;
#pragma unroll
  for (int u = 0; u < 8; ++u) { v[u] = cnt[base + u]; s += v[u]; pre[u] = s; }
  int tsum = s;
  int x = tsum;
#pragma unroll
  for (int off = 1; off < 64; off <<= 1) {
    int t = __shfl_up(x, off);
    if (lane >= off) x += t;
  }
  if (lane == 63) wtot[tid >> 6] = x;
  __syncthreads();
  if (tid == 0) {
    int run = 0;
    for (int w = 0; w < 16; ++w) { int t = wtot[w]; wtot[w] = run; run += t; }
    wtot[16] = run;
  }
  __syncthreads();
  int basex = wtot[tid >> 6] + (x - tsum);
#pragma unroll
  for (int u = 0; u < 8; ++u) rowptr[base + u] = basex + pre[u] - v[u];
  if (tid == 0) rowptr[NND] = wtot[16];
}

// ---------------- CSR fill for normalized graph (row = dst, col = src) ----------------
__global__ void csr_norm_kernel(const int* __restrict__ ei, const float* __restrict__ dinv,
                                const int* __restrict__ rowptr, int* __restrict__ cur,
                                int* __restrict__ col, float* __restrict__ w) {
  int e = blockIdx.x * blockDim.x + threadIdx.x;
  if (e >= TOTE) return;
  int s, d;
  if (e < NE) { s = ei[e]; d = ei[NE + e]; } else { s = e - NE; d = s; }
  int pos = atomicAdd(&cur[d], 1);
  int at = rowptr[d] + pos;
  col[at] = s;
  w[at] = dinv[s] * dinv[d];
}

// ---- agg + h + row-normalize -> hi/lo bf16 split; LDS-staged edge list ----
__global__ __launch_bounds__(256) void agg_hn_kernel(const float* __restrict__ fea,
    const int* __restrict__ rpN, const int* __restrict__ colN, const float* __restrict__ wN,
    const float* __restrict__ bal, short* __restrict__ hhi, short* __restrict__ hlo) {
  int i = blockIdx.x, j = threadIdx.x;
  __shared__ int colS[128];
  __shared__ float wS[128];
  float f = fea[(size_t)i * 256 + j];
  float acc = 0.0f;
  int e0 = rpN[i], e1 = rpN[i + 1];
  for (int base = e0; base < e1; base += 128) {
    int cnt = e1 - base;
    if (cnt > 128) cnt = 128;
    __syncthreads();
    if (j < cnt) { colS[j] = colN[base + j]; wS[j] = wN[base + j]; }
    __syncthreads();
    for (int t = 0; t < cnt; ++t)
      acc += wS[t] * fea[(size_t)colS[t] * 256 + j];
  }
  float hl = f * bal[j];
  float hh = acc * bal[256 + j];
  float ss = hl * hl + hh * hh;
  __shared__ float red[4];
  __shared__ float bc;
  __syncthreads();
#pragma unroll
  for (int off = 32; off >= 1; off >>= 1) ss += __shfl_down(ss, off);
  if ((j & 63) == 0) red[j >> 6] = ss;
  __syncthreads();
  if (j == 0) bc = sqrtf(red[0] + red[1] + red[2] + red[3]);
  __syncthreads();
  float inv = 1.0f / (bc + EPSF);
  short h0, l0, h1, l1;
  split_bf16(hl * inv, h0, l0);
  split_bf16(hh * inv, h1, l1);
  hhi[(size_t)i * 512 + j] = h0;
  hlo[(size_t)i * 512 + j] = l0;
  hhi[(size_t)i * 512 + 256 + j] = h1;
  hlo[(size_t)i * 512 + 256 + j] = l1;
}

// ---- strip GEMM via split-bf16 MFMA, global_load_lds staging (m97 structure) ----
// sims = hi.hi^T + hi.lo^T + lo.hi^T (3 passes per k0, fp32 MFMA accumulate)
// LDS content swizzled via pre-swizzled global source (rule 21): linear dest,
// src chunk = (lane&3) ^ ((row>>1)&3); read side uses the same XOR.
__global__ __launch_bounds__(256, 2) void gemm_strip_mfma(const short* __restrict__ hhi,
                                                          const short* __restrict__ hlo,
                                                          float* __restrict__ strip, int r0) {
  __shared__ short smem[4][128 * 32];   // [Ahi, Alo, Bhi, Blo], 8 KB each
  int by = blockIdx.x;   // row tile within strip
  int bx = blockIdx.y;   // col tile (0..63)
  int tid = threadIdx.x;
  int lane = tid & 63;
  int wid = tid >> 6;
  int wm = wid >> 1, wn = wid & 1;   // 2x2 wave grid, 64x64 per wave
  int arow0 = r0 + by * 128;
  int brow0 = bx * 128;

  // staging assignment: wave wid stages array wid
  const short* sArr = (wid == 0 || wid == 2) ? hhi : hlo;
  int sRow0 = (wid < 2) ? arow0 : brow0;
  short* sLds = &smem[wid][0];
  int sr = lane >> 2;          // row-within-16 block
  int cSrc0 = lane & 3;

  f32x4 acc[4][4];
#pragma unroll
  for (int m = 0; m < 4; ++m)
#pragma unroll
    for (int n = 0; n < 4; ++n) acc[m][n] = (f32x4){0.f, 0.f, 0.f, 0.f};

  for (int k0 = 0; k0 < 512; k0 += 32) {
    __syncthreads();   // previous compute done, LDS free
#pragma unroll
    for (int q = 0; q < 8; ++q) {
      int r = q * 16 + sr;
      int cSrc = cSrc0 ^ ((r >> 1) & 3);
      const short* gp = sArr + (size_t)(sRow0 + r) * 512 + k0 + cSrc * 8;
      GL16(gp, sLds + q * 512);
    }
    __syncthreads();   // drains vmcnt: staged data visible
    short8 ah[4], al[4], bh[4], bl[4];
#pragma unroll
    for (int m = 0; m < 4; ++m) {
      int rr = wm * 64 + m * 16 + (lane & 15);
      int ca = (lane >> 4) ^ ((rr >> 1) & 3);
      ah[m] = *(const short8*)&smem[0][rr * 32 + ca * 8];
      al[m] = *(const short8*)&smem[1][rr * 32 + ca * 8];
      int cc = wn * 64 + m * 16 + (lane & 15);
      int cb = (lane >> 4) ^ ((cc >> 1) & 3);
      bh[m] = *(const short8*)&smem[2][cc * 32 + cb * 8];
      bl[m] = *(const short8*)&smem[3][cc * 32 + cb * 8];
    }
#pragma unroll
    for (int m = 0; m < 4; ++m)
#pragma unroll
      for (int n = 0; n < 4; ++n)
        acc[m][n] = __builtin_amdgcn_mfma_f32_16x16x32_bf16(ah[m], bh[n], acc[m][n], 0, 0, 0);
#pragma unroll
    for (int m = 0; m < 4; ++m)
#pragma unroll
      for (int n = 0; n < 4; ++n)
        acc[m][n] = __builtin_amdgcn_mfma_f32_16x16x32_bf16(ah[m], bl[n], acc[m][n], 0, 0, 0);
#pragma unroll
    for (int m = 0; m < 4; ++m)
#pragma unroll
      for (int n = 0; n < 4; ++n)
        acc[m][n] = __builtin_amdgcn_mfma_f32_16x16x32_bf16(al[m], bh[n], acc[m][n], 0, 0, 0);
  }
  // C/D layout: col = lane&15, row = (lane>>4)*4 + r
#pragma unroll
  for (int m = 0; m < 4; ++m) {
    int lr = by * 128 + wm * 64 + m * 16 + ((lane >> 4) << 2);
#pragma unroll
    for (int n = 0; n < 4; ++n) {
      int gc = bx * 128 + wn * 64 + n * 16 + (lane & 15);
#pragma unroll
      for (int r = 0; r < 4; ++r)
        strip[(size_t)(lr + r) * NND + gc] = acc[m][n][r];
    }
  }
}

// ---- top-17 per strip row: cached lane-local argmax, 1 sync/round ----
__global__ __launch_bounds__(256) void topk_kernel(const float* __restrict__ strip,
                                                   float* __restrict__ tkv,
                                                   int* __restrict__ tki, int r0) {
  int gi = r0 + blockIdx.x;
  int tid = threadIdx.x;
  int lane = tid & 63, wvid = tid >> 6;
  const float* srow = strip + (size_t)blockIdx.x * NND;
  float v[32];
#pragma unroll
  for (int u = 0; u < 32; ++u) v[u] = srow[u * 256 + tid];
  float lmx = v[0];
  int lmu = 0;
#pragma unroll
  for (int u = 1; u < 32; ++u)
    if (v[u] > lmx) { lmx = v[u]; lmu = u; }

  __shared__ float swv[2][4];
  __shared__ int swi[2][4];
  for (int r = 0; r < KTOP; ++r) {
    int p = r & 1;
    float mx = lmx;
    int mcol = lmu * 256 + tid;
#pragma unroll
    for (int off = 32; off >= 1; off >>= 1) {
      float ov = __shfl_down(mx, off);
      int oc = __shfl_down(mcol, off);
      if (ov > mx || (ov == mx && oc < mcol)) { mx = ov; mcol = oc; }
    }
    if (lane == 0) { swv[p][wvid] = mx; swi[p][wvid] = mcol; }
    __syncthreads();
    float b = swv[p][0];
    int bc = swi[p][0];
#pragma unroll
    for (int w = 1; w < 4; ++w) {
      float bw = swv[p][w];
      int iw = swi[p][w];
      if (bw > b || (bw == b && iw < bc)) { b = bw; bc = iw; }
    }
    if (tid == 0) { tkv[gi * KTOP + r] = b; tki[gi * KTOP + r] = bc; }
    if ((bc & 255) == tid) {
      int uu = bc >> 8;
#pragma unroll
      for (int u = 0; u < 32; ++u)
        if (u == uu) v[u] = -3.0e38f;
      lmx = v[0]; lmu = 0;
#pragma unroll
      for (int u = 1; u < 32; ++u)
        if (v[u] > lmx) { lmx = v[u]; lmu = u; }
    }
  }
}

// ---------------- symmetrized kNN weights + mirror counts ----------------
__global__ void sym_kernel(const float* __restrict__ tkv, const int* __restrict__ tki,
                           float* __restrict__ symw, int* __restrict__ symflag,
                           int* __restrict__ cntK) {
  int s = blockIdx.x * blockDim.x + threadIdx.x;
  if (s >= NND * KTOP) return;
  int i = s / KTOP;
  int j = tki[s];
  float vv = tkv[s];
  float v2 = 0.0f;
  int found = 0;
#pragma unroll
  for (int t = 0; t < KTOP; ++t) {
    if (tki[j * KTOP + t] == i) { found = 1; v2 = tkv[j * KTOP + t]; }
  }
  float w = found ? 0.5f * (vv + v2) : vv;
  w = fmaxf(w, 0.0f);
  symw[s] = w;
  symflag[s] = 1 - found;
  if (!found) atomicAdd(&cntK[j], 1);
}

__global__ void csr_knn_kernel(const int* __restrict__ tki, const float* __restrict__ symw,
                               const int* __restrict__ symflag, const int* __restrict__ rpK,
                               int* __restrict__ curK, int* __restrict__ colK,
                               float* __restrict__ wK) {
  int s = blockIdx.x * blockDim.x + threadIdx.x;
  if (s >= NND * KTOP) return;
  int i = s / KTOP, k = s - i * KTOP;
  int j = tki[s];
  float w = symw[s];
  int at = rpK[i] + k;
  colK[at] = j;
  wK[at] = w;
  if (symflag[s]) {
    int p = atomicAdd(&curK[j], 1);
    int at2 = rpK[j] + KTOP + p;
    colK[at2] = i;
    wK[at2] = w;
  }
}

// ---------------- dense C(8192x256) = A(8192xK) @ B(Kx256) ----------------
__global__ __launch_bounds__(256) void gemm_rm_kernel(const float* __restrict__ A,
                                                      const float* __restrict__ B,
                                                      float* __restrict__ C, int K) {
  __shared__ float As[BKK * LDP];
  __shared__ float Bs[BKK * LDP];
  int bj = blockIdx.x, bi = blockIdx.y;
  int tid = threadIdx.x;
  int tx = tid & 15, ty = tid >> 4;
  const float4* A4 = (const float4*)A;
  const float4* B4 = (const float4*)B;
  int K4 = K >> 2;
  float acc[4][4] = {{0.f}};
  for (int kt = 0; kt < K / BKK; ++kt) {
    __syncthreads();
    {
      int rr = tid >> 3, k4 = tid & 7;
#pragma unroll
      for (int h = 0; h < 2; ++h) {
        int row = rr + h * 32;
        float4 a = A4[(size_t)(bi * 64 + row) * K4 + kt * 8 + k4];
        As[(k4 * 4 + 0) * LDP + row] = a.x;
        As[(k4 * 4 + 1) * LDP + row] = a.y;
        As[(k4 * 4 + 2) * LDP + row] = a.z;
        As[(k4 * 4 + 3) * LDP + row] = a.w;
      }
      int kk = tid >> 4, c4 = tid & 15;
#pragma unroll
      for (int h = 0; h < 2; ++h) {
        int krow = kk + h * 16;
        float4 b = B4[(size_t)(kt * 32 + krow) * 64 + bj * 16 + c4];
        *(float4*)&Bs[krow * LDP + c4 * 4] = b;
      }
    }
    __syncthreads();
#pragma unroll
    for (int k = 0; k < BKK; ++k) {
      float4 av = *(const float4*)&As[k * LDP + ty * 4];
      float4 bv = *(const float4*)&Bs[k * LDP + tx * 4];
      float aa[4] = {av.x, av.y, av.z, av.w};
      float bb[4] = {bv.x, bv.y, bv.z, bv.w};
#pragma unroll
      for (int q = 0; q < 4; ++q)
#pragma unroll
        for (int c = 0; c < 4; ++c) acc[q][c] = fmaf(aa[q], bb[c], acc[q][c]);
    }
  }
  int r0 = bi * 64 + ty * 4, c0 = bj * 64 + tx * 4;
#pragma unroll
  for (int q = 0; q < 4; ++q) {
    float4 v = make_float4(acc[q][0], acc[q][1], acc[q][2], acc[q][3]);
    *(float4*)&C[(size_t)(r0 + q) * 256 + c0] = v;
  }
}

// ---- SpMM: out = alpha*Anorm@X + (1-alpha)*Wsym@X (+relu) ----
// LDS-staged edge lists to break the col-load -> gather dependency chain.
__global__ __launch_bounds__(256) void spmm_kernel(const float* __restrict__ X,
    const int* __restrict__ rpN, const int* __restrict__ colN, const float* __restrict__ wN,
    const int* __restrict__ rpK, const int* __restrict__ colK, const float* __restrict__ wK,
    const float* __restrict__ alphaP, float* __restrict__ out, int doRelu) {
  int i = blockIdx.x;
  int tid = threadIdx.x;
  int g = tid >> 6;    // edge group (wave)
  int jt = tid & 63;   // float4 column
  float alpha = alphaP[0];
  const float4* X4 = (const float4*)X;
  __shared__ int colS[256];
  __shared__ float wS[256];
  float ax = 0.f, ay = 0.f, az = 0.f, aw = 0.f;
  float kx = 0.f, ky = 0.f, kz = 0.f, kw = 0.f;
  int e0 = rpN[i], e1 = rpN[i + 1];
  for (int base = e0; base < e1; base += 256) {
    int cnt = e1 - base;
    if (cnt > 256) cnt = 256;
    __syncthreads();
    if (tid < cnt) { colS[tid] = colN[base + tid]; wS[tid] = wN[base + tid]; }
    __syncthreads();
    for (int t = g; t < cnt; t += 4) {
      float w = wS[t];
      float4 xv = X4[(size_t)colS[t] * 64 + jt];
      ax = fmaf(w, xv.x, ax); ay = fmaf(w, xv.y, ay);
      az = fmaf(w, xv.z, az); aw = fmaf(w, xv.w, aw);
    }
  }
  e0 = rpK[i]; e1 = rpK[i + 1];
  for (int base = e0; base < e1; base += 256) {
    int cnt = e1 - base;
    if (cnt > 256) cnt = 256;
    __syncthreads();
    if (tid < cnt) { colS[tid] = colK[base + tid]; wS[tid] = wK[base + tid]; }
    __syncthreads();
    for (int t = g; t < cnt; t += 4) {
      float w = wS[t];
      float4 xv = X4[(size_t)colS[t] * 64 + jt];
      kx = fmaf(w, xv.x, kx); ky = fmaf(w, xv.y, ky);
      kz = fmaf(w, xv.z, kz); kw = fmaf(w, xv.w, kw);
    }
  }
  float b = 1.0f - alpha;
  __shared__ float4 red[256];
  __syncthreads();
  red[tid] = make_float4(alpha * ax + b * kx, alpha * ay + b * ky,
                         alpha * az + b * kz, alpha * aw + b * kw);
  __syncthreads();
  if (g == 0) {
    float4 r0 = red[jt], r1 = red[64 + jt], r2 = red[128 + jt], r3 = red[192 + jt];
    float4 r = make_float4(r0.x + r1.x + r2.x + r3.x, r0.y + r1.y + r2.y + r3.y,
                           r0.z + r1.z + r2.z + r3.z, r0.w + r1.w + r2.w + r3.w);
    if (doRelu) {
      r.x = fmaxf(r.x, 0.f); r.y = fmaxf(r.y, 0.f);
      r.z = fmaxf(r.z, 0.f); r.w = fmaxf(r.w, 0.f);
    }
    *(float4*)&out[(size_t)i * 256 + jt * 4] = r;
  }
}

// ---- prototypes: class-owned scan, no hot atomics ----
__global__ __launch_bounds__(256) void proto_kernel(const float* __restrict__ emb,
                                                    const int* __restrict__ labels,
                                                    const int* __restrict__ nodeidx,
                                                    float* __restrict__ proto,
                                                    float* __restrict__ cntC) {
  int c = blockIdx.x >> 3;
  int chunk = blockIdx.x & 7;
  int j = threadIdx.x;
  __shared__ int labL[512];
  __shared__ int niL[512];
  int r0 = chunk * 512;
  labL[j] = labels[r0 + j];
  labL[256 + j] = labels[r0 + 256 + j];
  niL[j] = nodeidx[r0 + j];
  niL[256 + j] = nodeidx[r0 + 256 + j];
  __syncthreads();
  float a0 = 0.f, a1 = 0.f, a2 = 0.f, a3 = 0.f;
  int cnt = 0;
  for (int r = 0; r < 512; r += 4) {
    int l0 = labL[r], l1 = labL[r + 1], l2 = labL[r + 2], l3 = labL[r + 3];
    if (l0 == c) a0 += emb[(size_t)niL[r] * 256 + j];
    if (l1 == c) a1 += emb[(size_t)niL[r + 1] * 256 + j];
    if (l2 == c) a2 += emb[(size_t)niL[r + 2] * 256 + j];
    if (l3 == c) a3 += emb[(size_t)niL[r + 3] * 256 + j];
    cnt += (l0 == c) + (l1 == c) + (l2 == c) + (l3 == c);
  }
  atomicAdd(&proto[c * 256 + j], (a0 + a1) + (a2 + a3));
  if (j == 0) atomicAdd(&cntC[c], (float)cnt);
}

__global__ void pn_kernel(const float* __restrict__ proto, const float* __restrict__ cntC,
                          float* __restrict__ pn) {
  int c = blockIdx.x, j = threadIdx.x;
  float p = proto[c * 256 + j] / fmaxf(cntC[c], 1.0f);
  float ss = p * p;
  __shared__ float red[4];
  __shared__ float bc;
#pragma unroll
  for (int off = 32; off >= 1; off >>= 1) ss += __shfl_down(ss, off);
  if ((j & 63) == 0) red[j >> 6] = ss;
  __syncthreads();
  if (j == 0) bc = sqrtf(red[0] + red[1] + red[2] + red[3]);
  __syncthreads();
  pn[c * 256 + j] = p / (bc + EPSF);
}

__global__ void out_kernel(const float* __restrict__ emb, const int* __restrict__ nodeidx,
                           const float* __restrict__ pn, float* __restrict__ outp) {
  int rr = blockIdx.x, j = threadIdx.x;
  int ni = nodeidx[rr];
  float v = emb[(size_t)ni * 256 + j];
  __shared__ float red[4];
  __shared__ float bc;
  float ss = v * v;
#pragma unroll
  for (int off = 32; off >= 1; off >>= 1) ss += __shfl_down(ss, off);
  if ((j & 63) == 0) red[j >> 6] = ss;
  __syncthreads();
  if (j == 0) bc = sqrtf(red[0] + red[1] + red[2] + red[3]);
  __syncthreads();
  float inv = 1.0f / (bc + EPSF);
  for (int c = 0; c < NCLSN; ++c) {
    float part = v * pn[c * 256 + j];
#pragma unroll
    for (int off = 32; off >= 1; off >>= 1) part += __shfl_down(part, off);
    __syncthreads();
    if ((j & 63) == 0) red[j >> 6] = part;
    __syncthreads();
    if (j == 0) outp[rr * NCLSN + c] = ((red[0] + red[1] + red[2] + red[3]) * inv) / 0.2f;
  }
}

// ---------------- host launcher ----------------
extern "C" void kernel_launch(void* const* d_in, const int* in_sizes, int n_in,
                              void* d_out, int out_size, void* d_ws, size_t ws_size,
                              hipStream_t stream) {
  (void)in_sizes; (void)n_in;
  const float* x      = (const float*)d_in[0];
  const float* cw     = (const float*)d_in[1];
  const float* alphaP = (const float*)d_in[2];
  const float* ps     = (const float*)d_in[3];
  const float* st     = (const float*)d_in[4];
  const float* bal    = (const float*)d_in[5];
  const float* W1     = (const float*)d_in[6];
  const float* W2     = (const float*)d_in[7];
  const int*   ei     = (const int*)d_in[8];
  const int*   labels = (const int*)d_in[9];
  const int*   nodei  = (const int*)d_in[10];
  float* out = (float*)d_out;

  char* base = (char*)d_ws;
  size_t off = 0;
  auto alloc = [&](size_t bytes) -> void* {
    void* p = base + off;
    off += (bytes + 255) & ~(size_t)255;
    return p;
  };
  float* fea    = (float*)alloc((size_t)NND * 256 * 4);      // 8 MB; reused as t2
  short* hhi    = (short*)alloc((size_t)NND * 512 * 2);      // 8 MB; reused as emb
  short* hlo    = (short*)alloc((size_t)NND * 512 * 2);      // 8 MB
  float* deg    = (float*)alloc((size_t)NND * 4);
  float* dinv   = (float*)alloc((size_t)NND * 4);
  int*   cntN   = (int*)alloc((size_t)NND * 4);
  int*   rpN    = (int*)alloc((size_t)(NND + 1) * 4);
  int*   curN   = (int*)alloc((size_t)NND * 4);
  int*   colN   = (int*)alloc((size_t)TOTE * 4);
  float* wN     = (float*)alloc((size_t)TOTE * 4);
  float* tkv    = (float*)alloc((size_t)NND * KTOP * 4);
  int*   tki    = (int*)alloc((size_t)NND * KTOP * 4);
  float* symw   = (float*)alloc((size_t)NND * KTOP * 4);
  int*   symf   = (int*)alloc((size_t)NND * KTOP * 4);
  int*   cntK   = (int*)alloc((size_t)NND * 4);
  int*   rpK    = (int*)alloc((size_t)(NND + 1) * 4);
  int*   curK   = (int*)alloc((size_t)NND * 4);
  int*   colK   = (int*)alloc((size_t)2 * NND * KTOP * 4);
  float* wKv    = (float*)alloc((size_t)2 * NND * KTOP * 4);
  float* proto  = (float*)alloc((size_t)NCLSN * 256 * 4);
  float* cntC   = (float*)alloc((size_t)NCLSN * 4);
  float* pn     = (float*)alloc((size_t)NCLSN * 256 * 4);

  size_t rem = (ws_size > off) ? (ws_size - off) : 0;
  int RS;
  if (rem >= (size_t)1024 * NND * 4) RS = 1024;
  else if (rem >= (size_t)512 * NND * 4) RS = 512;
  else {
    fill_f32<<<64, 256, 0, stream>>>(out, 12345.0f, out_size);
    return;
  }
  float* strip = (float*)alloc((size_t)RS * NND * 4);
  if (off > ws_size) {
    fill_f32<<<64, 256, 0, stream>>>(out, 12345.0f, out_size);
    return;
  }

  // aliases (lifetimes disjoint in stream order):
  float* t1  = strip;                         // strip dead after last topk
  float* h1  = strip + (size_t)NND * 256;
  float* t2  = fea;                           // fea dead after gemm_rm #1
  float* emb = (float*)hhi;                   // hhi/hlo dead after last strip GEMM

  init_misc<<<32, 256, 0, stream>>>(deg, curN, cntK, curK, proto, cntC);

  fea_elu_kernel<<<2048, 256, 0, stream>>>(x, cw, ps, st, fea);
  deg_kernel<<<NE / 256, 256, 0, stream>>>(ei, deg);
  dinv_kernel<<<NND / 256, 256, 0, stream>>>(deg, dinv, cntN);
  scan_kernel<<<1, 1024, 0, stream>>>(cntN, rpN);
  csr_norm_kernel<<<(TOTE + 255) / 256, 256, 0, stream>>>(ei, dinv, rpN, curN, colN, wN);
  agg_hn_kernel<<<NND, 256, 0, stream>>>(fea, rpN, colN, wN, bal, hhi, hlo);

  for (int s = 0; s < NND / RS; ++s) {
    gemm_strip_mfma<<<dim3(RS / 128, 64), 256, 0, stream>>>(hhi, hlo, strip, s * RS);
    topk_kernel<<<RS, 256, 0, stream>>>(strip, tkv, tki, s * RS);
  }

  sym_kernel<<<(NND * KTOP + 255) / 256, 256, 0, stream>>>(tkv, tki, symw, symf, cntK);
  scan_kernel<<<1, 1024, 0, stream>>>(cntK, rpK);
  csr_knn_kernel<<<(NND * KTOP + 255) / 256, 256, 0, stream>>>(tki, symw, symf, rpK, curK,
                                                               colK, wKv);

  gemm_rm_kernel<<<dim3(4, 128), 256, 0, stream>>>(fea, W1, t1, 256);
  spmm_kernel<<<NND, 256, 0, stream>>>(t1, rpN, colN, wN, rpK, colK, wKv, alphaP, h1, 1);
  gemm_rm_kernel<<<dim3(4, 128), 256, 0, stream>>>(h1, W2, t2, 256);
  spmm_kernel<<<NND, 256, 0, stream>>>(t2, rpN, colN, wN, rpK, colK, wKv, alphaP, emb, 0);

  proto_kernel<<<NCLSN * 8, 256, 0, stream>>>(emb, labels, nodei, proto, cntC);
  pn_kernel<<<NCLSN, 256, 0, stream>>>(proto, cntC, pn);
  out_kernel<<<NSELN, 256, 0, stream>>>(emb, nodei, pn, out);
}

// Round 9
// 682.492 us; speedup vs baseline: 2.8923x; 1.1908x over previous
//
#include <hip/hip_runtime.h>
#include <hip/hip_bf16.h>
#include <math.h>

#define NND 8192
#define FIN 256
#define NE 131072
#define TOTE (NE + NND)
#define KTOP 17
#define NSELN 4096
#define NCLSN 10
#define EPSF 1e-8f

#define BKK 32
#define LDP 68

typedef __attribute__((ext_vector_type(8))) short short8;
typedef __attribute__((ext_vector_type(4))) float f32x4;

// async 16B global->LDS (dest = wave-uniform base + lane*16, src per-lane)
#define GL16(gp, lp)                                              \
  __builtin_amdgcn_global_load_lds(                               \
      (const __attribute__((address_space(1))) void*)(gp),        \
      (__attribute__((address_space(3))) void*)(lp), 16, 0, 0)

// ---------------- utility fills ----------------
__global__ void fill_f32(float* p, float v, int n) {
  int i = blockIdx.x * blockDim.x + threadIdx.x;
  int st = gridDim.x * blockDim.x;
  for (; i < n; i += st) p[i] = v;
}

__global__ void init_misc(float* deg, int* curN, int* cntK, int* curK,
                          float* proto, float* cntC) {
  int i = blockIdx.x * blockDim.x + threadIdx.x;
  if (i < NND) {
    deg[i] = 1.0f;
    curN[i] = 0;
    cntK[i] = KTOP;
    curK[i] = 0;
  }
  if (i < NCLSN * 256) proto[i] = 0.0f;
  if (i < NCLSN) cntC[i] = 0.0f;
}

__device__ __forceinline__ void split_bf16(float v, short& h, short& l) {
  __hip_bfloat16 bh = __float2bfloat16(v);
  float fh = __bfloat162float(bh);
  __hip_bfloat16 bl = __float2bfloat16(v - fh);
  h = *reinterpret_cast<short*>(&bh);
  l = *reinterpret_cast<short*>(&bl);
}

// ---------------- fea = elu(x * (c0*ps + c1*st)) ----------------
__global__ void fea_elu_kernel(const float* __restrict__ x, const float* __restrict__ cw,
                               const float* __restrict__ ps, const float* __restrict__ st,
                               float* __restrict__ fea) {
  int i = blockIdx.x * blockDim.x + threadIdx.x;
  const int total = NND * FIN / 4;
  int stride = gridDim.x * blockDim.x;
  float c0 = cw[0], c1 = cw[1];
  const float4* x4 = (const float4*)x;
  const float4* ps4 = (const float4*)ps;
  const float4* st4 = (const float4*)st;
  float4* f4 = (float4*)fea;
  for (; i < total; i += stride) {
    int j4 = i & (FIN / 4 - 1);
    float4 xv = x4[i], pv = ps4[j4], sv = st4[j4];
    float4 r;
    float t;
    t = xv.x * (c0 * pv.x + c1 * sv.x); r.x = t > 0.0f ? t : expm1f(t);
    t = xv.y * (c0 * pv.y + c1 * sv.y); r.y = t > 0.0f ? t : expm1f(t);
    t = xv.z * (c0 * pv.z + c1 * sv.z); r.z = t > 0.0f ? t : expm1f(t);
    t = xv.w * (c0 * pv.w + c1 * sv.w); r.w = t > 0.0f ? t : expm1f(t);
    f4[i] = r;
  }
}

// ---------------- degree (dst occurrences) ----------------
__global__ void deg_kernel(const int* __restrict__ ei, float* __restrict__ deg) {
  int e = blockIdx.x * blockDim.x + threadIdx.x;
  if (e < NE) atomicAdd(&deg[ei[NE + e]], 1.0f);
}

__global__ void dinv_kernel(const float* __restrict__ deg, float* __restrict__ dinv,
                            int* __restrict__ cntN) {
  int i = blockIdx.x * blockDim.x + threadIdx.x;
  if (i < NND) {
    float d = deg[i];
    dinv[i] = 1.0f / sqrtf(d);
    cntN[i] = (int)(d + 0.5f);
  }
}

// ---------------- exclusive scan of 8192 ints, one block of 1024 ----------------
__global__ __launch_bounds__(1024) void scan_kernel(const int* __restrict__ cnt,
                                                    int* __restrict__ rowptr) {
  __shared__ int wtot[17];
  int tid = threadIdx.x;
  int lane = tid & 63;
  int v[8], pre[8];
  int s = 0;
  int base = tid * 8;
#pragma unroll
  for (int u = 0; u < 8; ++u) { v[u] = cnt[base + u]; s += v[u]; pre[u] = s; }
  int tsum = s;
  int x = tsum;
#pragma unroll
  for (int off = 1; off < 64; off <<= 1) {
    int t = __shfl_up(x, off);
    if (lane >= off) x += t;
  }
  if (lane == 63) wtot[tid >> 6] = x;
  __syncthreads();
  if (tid == 0) {
    int run = 0;
    for (int w = 0; w < 16; ++w) { int t = wtot[w]; wtot[w] = run; run += t; }
    wtot[16] = run;
  }
  __syncthreads();
  int basex = wtot[tid >> 6] + (x - tsum);
#pragma unroll
  for (int u = 0; u < 8; ++u) rowptr[base + u] = basex + pre[u] - v[u];
  if (tid == 0) rowptr[NND] = wtot[16];
}

// ---------------- CSR fill for normalized graph (row = dst, col = src) ----------------
__global__ void csr_norm_kernel(const int* __restrict__ ei, const float* __restrict__ dinv,
                                const int* __restrict__ rowptr, int* __restrict__ cur,
                                int* __restrict__ col, float* __restrict__ w) {
  int e = blockIdx.x * blockDim.x + threadIdx.x;
  if (e >= TOTE) return;
  int s, d;
  if (e < NE) { s = ei[e]; d = ei[NE + e]; } else { s = e - NE; d = s; }
  int pos = atomicAdd(&cur[d], 1);
  int at = rowptr[d] + pos;
  col[at] = s;
  w[at] = dinv[s] * dinv[d];
}

// ---- agg + h + row-normalize -> hi/lo bf16 split; LDS-staged edge list ----
__global__ __launch_bounds__(256) void agg_hn_kernel(const float* __restrict__ fea,
    const int* __restrict__ rpN, const int* __restrict__ colN, const float* __restrict__ wN,
    const float* __restrict__ bal, short* __restrict__ hhi, short* __restrict__ hlo) {
  int i = blockIdx.x, j = threadIdx.x;
  __shared__ int colS[128];
  __shared__ float wS[128];
  float f = fea[(size_t)i * 256 + j];
  float acc = 0.0f;
  int e0 = rpN[i], e1 = rpN[i + 1];
  for (int base = e0; base < e1; base += 128) {
    int cnt = e1 - base;
    if (cnt > 128) cnt = 128;
    __syncthreads();
    if (j < cnt) { colS[j] = colN[base + j]; wS[j] = wN[base + j]; }
    __syncthreads();
    for (int t = 0; t < cnt; ++t)
      acc += wS[t] * fea[(size_t)colS[t] * 256 + j];
  }
  float hl = f * bal[j];
  float hh = acc * bal[256 + j];
  float ss = hl * hl + hh * hh;
  __shared__ float red[4];
  __shared__ float bc;
  __syncthreads();
#pragma unroll
  for (int off = 32; off >= 1; off >>= 1) ss += __shfl_down(ss, off);
  if ((j & 63) == 0) red[j >> 6] = ss;
  __syncthreads();
  if (j == 0) bc = sqrtf(red[0] + red[1] + red[2] + red[3]);
  __syncthreads();
  float inv = 1.0f / (bc + EPSF);
  short h0, l0, h1, l1;
  split_bf16(hl * inv, h0, l0);
  split_bf16(hh * inv, h1, l1);
  hhi[(size_t)i * 512 + j] = h0;
  hlo[(size_t)i * 512 + j] = l0;
  hhi[(size_t)i * 512 + 256 + j] = h1;
  hlo[(size_t)i * 512 + 256 + j] = l1;
}

// ---- strip GEMM via split-bf16 MFMA, global_load_lds staging (m97 structure) ----
// sims = hi.hi^T + hi.lo^T + lo.hi^T (3 passes per k0, fp32 MFMA accumulate)
// LDS swizzle via pre-swizzled global source (rule 21): linear dest,
// src chunk = (lane&3) ^ ((row>>1)&3); read side uses the same XOR.
__global__ __launch_bounds__(256, 3) void gemm_strip_mfma(const short* __restrict__ hhi,
                                                          const short* __restrict__ hlo,
                                                          float* __restrict__ strip, int r0) {
  __shared__ short smem[4][128 * 32];   // [Ahi, Alo, Bhi, Blo], 8 KB each
  int by = blockIdx.x;   // row tile within strip
  int bx = blockIdx.y;   // col tile (0..63)
  int tid = threadIdx.x;
  int lane = tid & 63;
  int wid = tid >> 6;
  int wm = wid >> 1, wn = wid & 1;   // 2x2 wave grid, 64x64 per wave
  int arow0 = r0 + by * 128;
  int brow0 = bx * 128;

  // staging assignment: wave wid stages array wid
  const short* sArr = (wid == 0 || wid == 2) ? hhi : hlo;
  int sRow0 = (wid < 2) ? arow0 : brow0;
  short* sLds = &smem[wid][0];
  int sr = lane >> 2;          // row-within-16 block
  int cSrc0 = lane & 3;

  f32x4 acc[4][4];
#pragma unroll
  for (int m = 0; m < 4; ++m)
#pragma unroll
    for (int n = 0; n < 4; ++n) acc[m][n] = (f32x4){0.f, 0.f, 0.f, 0.f};

  for (int k0 = 0; k0 < 512; k0 += 32) {
    __syncthreads();   // previous compute done, LDS free
#pragma unroll
    for (int q = 0; q < 8; ++q) {
      int r = q * 16 + sr;
      int cSrc = cSrc0 ^ ((r >> 1) & 3);
      const short* gp = sArr + (size_t)(sRow0 + r) * 512 + k0 + cSrc * 8;
      GL16(gp, sLds + q * 512);
    }
    __syncthreads();   // drains vmcnt: staged data visible
    short8 ah[4], al[4], bh[4], bl[4];
#pragma unroll
    for (int m = 0; m < 4; ++m) {
      int rr = wm * 64 + m * 16 + (lane & 15);
      int ca = (lane >> 4) ^ ((rr >> 1) & 3);
      ah[m] = *(const short8*)&smem[0][rr * 32 + ca * 8];
      al[m] = *(const short8*)&smem[1][rr * 32 + ca * 8];
      int cc = wn * 64 + m * 16 + (lane & 15);
      int cb = (lane >> 4) ^ ((cc >> 1) & 3);
      bh[m] = *(const short8*)&smem[2][cc * 32 + cb * 8];
      bl[m] = *(const short8*)&smem[3][cc * 32 + cb * 8];
    }
#pragma unroll
    for (int m = 0; m < 4; ++m)
#pragma unroll
      for (int n = 0; n < 4; ++n)
        acc[m][n] = __builtin_amdgcn_mfma_f32_16x16x32_bf16(ah[m], bh[n], acc[m][n], 0, 0, 0);
#pragma unroll
    for (int m = 0; m < 4; ++m)
#pragma unroll
      for (int n = 0; n < 4; ++n)
        acc[m][n] = __builtin_amdgcn_mfma_f32_16x16x32_bf16(ah[m], bl[n], acc[m][n], 0, 0, 0);
#pragma unroll
    for (int m = 0; m < 4; ++m)
#pragma unroll
      for (int n = 0; n < 4; ++n)
        acc[m][n] = __builtin_amdgcn_mfma_f32_16x16x32_bf16(al[m], bh[n], acc[m][n], 0, 0, 0);
  }
  // C/D layout: col = lane&15, row = (lane>>4)*4 + r
#pragma unroll
  for (int m = 0; m < 4; ++m) {
    int lr = by * 128 + wm * 64 + m * 16 + ((lane >> 4) << 2);
#pragma unroll
    for (int n = 0; n < 4; ++n) {
      int gc = bx * 128 + wn * 64 + n * 16 + (lane & 15);
#pragma unroll
      for (int r = 0; r < 4; ++r)
        strip[(size_t)(lr + r) * NND + gc] = acc[m][n][r];
    }
  }
}

// ---- top-17 per strip row: cached lane-local argmax, 1 sync/round ----
__global__ __launch_bounds__(256) void topk_kernel(const float* __restrict__ strip,
                                                   float* __restrict__ tkv,
                                                   int* __restrict__ tki, int r0) {
  int gi = r0 + blockIdx.x;
  int tid = threadIdx.x;
  int lane = tid & 63, wvid = tid >> 6;
  const float* srow = strip + (size_t)blockIdx.x * NND;
  float v[32];
#pragma unroll
  for (int u = 0; u < 32; ++u) v[u] = srow[u * 256 + tid];
  float lmx = v[0];
  int lmu = 0;
#pragma unroll
  for (int u = 1; u < 32; ++u)
    if (v[u] > lmx) { lmx = v[u]; lmu = u; }

  __shared__ float swv[2][4];
  __shared__ int swi[2][4];
  for (int r = 0; r < KTOP; ++r) {
    int p = r & 1;
    float mx = lmx;
    int mcol = lmu * 256 + tid;
#pragma unroll
    for (int off = 32; off >= 1; off >>= 1) {
      float ov = __shfl_down(mx, off);
      int oc = __shfl_down(mcol, off);
      if (ov > mx || (ov == mx && oc < mcol)) { mx = ov; mcol = oc; }
    }
    if (lane == 0) { swv[p][wvid] = mx; swi[p][wvid] = mcol; }
    __syncthreads();
    float b = swv[p][0];
    int bc = swi[p][0];
#pragma unroll
    for (int w = 1; w < 4; ++w) {
      float bw = swv[p][w];
      int iw = swi[p][w];
      if (bw > b || (bw == b && iw < bc)) { b = bw; bc = iw; }
    }
    if (tid == 0) { tkv[gi * KTOP + r] = b; tki[gi * KTOP + r] = bc; }
    if ((bc & 255) == tid) {
      int uu = bc >> 8;
#pragma unroll
      for (int u = 0; u < 32; ++u)
        if (u == uu) v[u] = -3.0e38f;
      lmx = v[0]; lmu = 0;
#pragma unroll
      for (int u = 1; u < 32; ++u)
        if (v[u] > lmx) { lmx = v[u]; lmu = u; }
    }
  }
}

// ---------------- symmetrized kNN weights + mirror counts ----------------
__global__ void sym_kernel(const float* __restrict__ tkv, const int* __restrict__ tki,
                           float* __restrict__ symw, int* __restrict__ symflag,
                           int* __restrict__ cntK) {
  int s = blockIdx.x * blockDim.x + threadIdx.x;
  if (s >= NND * KTOP) return;
  int i = s / KTOP;
  int j = tki[s];
  float vv = tkv[s];
  float v2 = 0.0f;
  int found = 0;
#pragma unroll
  for (int t = 0; t < KTOP; ++t) {
    if (tki[j * KTOP + t] == i) { found = 1; v2 = tkv[j * KTOP + t]; }
  }
  float w = found ? 0.5f * (vv + v2) : vv;
  w = fmaxf(w, 0.0f);
  symw[s] = w;
  symflag[s] = 1 - found;
  if (!found) atomicAdd(&cntK[j], 1);
}

__global__ void csr_knn_kernel(const int* __restrict__ tki, const float* __restrict__ symw,
                               const int* __restrict__ symflag, const int* __restrict__ rpK,
                               int* __restrict__ curK, int* __restrict__ colK,
                               float* __restrict__ wK) {
  int s = blockIdx.x * blockDim.x + threadIdx.x;
  if (s >= NND * KTOP) return;
  int i = s / KTOP, k = s - i * KTOP;
  int j = tki[s];
  float w = symw[s];
  int at = rpK[i] + k;
  colK[at] = j;
  wK[at] = w;
  if (symflag[s]) {
    int p = atomicAdd(&curK[j], 1);
    int at2 = rpK[j] + KTOP + p;
    colK[at2] = i;
    wK[at2] = w;
  }
}

// ---------------- dense C(8192x256) = A(8192xK) @ B(Kx256) ----------------
__global__ __launch_bounds__(256) void gemm_rm_kernel(const float* __restrict__ A,
                                                      const float* __restrict__ B,
                                                      float* __restrict__ C, int K) {
  __shared__ float As[BKK * LDP];
  __shared__ float Bs[BKK * LDP];
  int bj = blockIdx.x, bi = blockIdx.y;
  int tid = threadIdx.x;
  int tx = tid & 15, ty = tid >> 4;
  const float4* A4 = (const float4*)A;
  const float4* B4 = (const float4*)B;
  int K4 = K >> 2;
  float acc[4][4] = {{0.f}};
  for (int kt = 0; kt < K / BKK; ++kt) {
    __syncthreads();
    {
      int rr = tid >> 3, k4 = tid & 7;
#pragma unroll
      for (int h = 0; h < 2; ++h) {
        int row = rr + h * 32;
        float4 a = A4[(size_t)(bi * 64 + row) * K4 + kt * 8 + k4];
        As[(k4 * 4 + 0) * LDP + row] = a.x;
        As[(k4 * 4 + 1) * LDP + row] = a.y;
        As[(k4 * 4 + 2) * LDP + row] = a.z;
        As[(k4 * 4 + 3) * LDP + row] = a.w;
      }
      int kk = tid >> 4, c4 = tid & 15;
#pragma unroll
      for (int h = 0; h < 2; ++h) {
        int krow = kk + h * 16;
        float4 b = B4[(size_t)(kt * 32 + krow) * 64 + bj * 16 + c4];
        *(float4*)&Bs[krow * LDP + c4 * 4] = b;
      }
    }
    __syncthreads();
#pragma unroll
    for (int k = 0; k < BKK; ++k) {
      float4 av = *(const float4*)&As[k * LDP + ty * 4];
      float4 bv = *(const float4*)&Bs[k * LDP + tx * 4];
      float aa[4] = {av.x, av.y, av.z, av.w};
      float bb[4] = {bv.x, bv.y, bv.z, bv.w};
#pragma unroll
      for (int q = 0; q < 4; ++q)
#pragma unroll
        for (int c = 0; c < 4; ++c) acc[q][c] = fmaf(aa[q], bb[c], acc[q][c]);
    }
  }
  int r0 = bi * 64 + ty * 4, c0 = bj * 64 + tx * 4;
#pragma unroll
  for (int q = 0; q < 4; ++q) {
    float4 v = make_float4(acc[q][0], acc[q][1], acc[q][2], acc[q][3]);
    *(float4*)&C[(size_t)(r0 + q) * 256 + c0] = v;
  }
}

// ---- SpMM: out = alpha*Anorm@X + (1-alpha)*Wsym@X (+relu) ----
// LDS-staged edge lists to break the col-load -> gather dependency chain.
__global__ __launch_bounds__(256) void spmm_kernel(const float* __restrict__ X,
    const int* __restrict__ rpN, const int* __restrict__ colN, const float* __restrict__ wN,
    const int* __restrict__ rpK, const int* __restrict__ colK, const float* __restrict__ wK,
    const float* __restrict__ alphaP, float* __restrict__ out, int doRelu) {
  int i = blockIdx.x;
  int tid = threadIdx.x;
  int g = tid >> 6;    // edge group (wave)
  int jt = tid & 63;   // float4 column
  float alpha = alphaP[0];
  const float4* X4 = (const float4*)X;
  __shared__ int colS[256];
  __shared__ float wS[256];
  float ax = 0.f, ay = 0.f, az = 0.f, aw = 0.f;
  float kx = 0.f, ky = 0.f, kz = 0.f, kw = 0.f;
  int e0 = rpN[i], e1 = rpN[i + 1];
  for (int base = e0; base < e1; base += 256) {
    int cnt = e1 - base;
    if (cnt > 256) cnt = 256;
    __syncthreads();
    if (tid < cnt) { colS[tid] = colN[base + tid]; wS[tid] = wN[base + tid]; }
    __syncthreads();
    for (int t = g; t < cnt; t += 4) {
      float w = wS[t];
      float4 xv = X4[(size_t)colS[t] * 64 + jt];
      ax = fmaf(w, xv.x, ax); ay = fmaf(w, xv.y, ay);
      az = fmaf(w, xv.z, az); aw = fmaf(w, xv.w, aw);
    }
  }
  e0 = rpK[i]; e1 = rpK[i + 1];
  for (int base = e0; base < e1; base += 256) {
    int cnt = e1 - base;
    if (cnt > 256) cnt = 256;
    __syncthreads();
    if (tid < cnt) { colS[tid] = colK[base + tid]; wS[tid] = wK[base + tid]; }
    __syncthreads();
    for (int t = g; t < cnt; t += 4) {
      float w = wS[t];
      float4 xv = X4[(size_t)colS[t] * 64 + jt];
      kx = fmaf(w, xv.x, kx); ky = fmaf(w, xv.y, ky);
      kz = fmaf(w, xv.z, kz); kw = fmaf(w, xv.w, kw);
    }
  }
  float b = 1.0f - alpha;
  __shared__ float4 red[256];
  __syncthreads();
  red[tid] = make_float4(alpha * ax + b * kx, alpha * ay + b * ky,
                         alpha * az + b * kz, alpha * aw + b * kw);
  __syncthreads();
  if (g == 0) {
    float4 r0 = red[jt], r1 = red[64 + jt], r2 = red[128 + jt], r3 = red[192 + jt];
    float4 r = make_float4(r0.x + r1.x + r2.x + r3.x, r0.y + r1.y + r2.y + r3.y,
                           r0.z + r1.z + r2.z + r3.z, r0.w + r1.w + r2.w + r3.w);
    if (doRelu) {
      r.x = fmaxf(r.x, 0.f); r.y = fmaxf(r.y, 0.f);
      r.z = fmaxf(r.z, 0.f); r.w = fmaxf(r.w, 0.f);
    }
    *(float4*)&out[(size_t)i * 256 + jt * 4] = r;
  }
}

// ---- prototypes: class-owned scan, no hot atomics ----
__global__ __launch_bounds__(256) void proto_kernel(const float* __restrict__ emb,
                                                    const int* __restrict__ labels,
                                                    const int* __restrict__ nodeidx,
                                                    float* __restrict__ proto,
                                                    float* __restrict__ cntC) {
  int c = blockIdx.x >> 3;
  int chunk = blockIdx.x & 7;
  int j = threadIdx.x;
  __shared__ int labL[512];
  __shared__ int niL[512];
  int r0 = chunk * 512;
  labL[j] = labels[r0 + j];
  labL[256 + j] = labels[r0 + 256 + j];
  niL[j] = nodeidx[r0 + j];
  niL[256 + j] = nodeidx[r0 + 256 + j];
  __syncthreads();
  float a0 = 0.f, a1 = 0.f, a2 = 0.f, a3 = 0.f;
  int cnt = 0;
  for (int r = 0; r < 512; r += 4) {
    int l0 = labL[r], l1 = labL[r + 1], l2 = labL[r + 2], l3 = labL[r + 3];
    if (l0 == c) a0 += emb[(size_t)niL[r] * 256 + j];
    if (l1 == c) a1 += emb[(size_t)niL[r + 1] * 256 + j];
    if (l2 == c) a2 += emb[(size_t)niL[r + 2] * 256 + j];
    if (l3 == c) a3 += emb[(size_t)niL[r + 3] * 256 + j];
    cnt += (l0 == c) + (l1 == c) + (l2 == c) + (l3 == c);
  }
  atomicAdd(&proto[c * 256 + j], (a0 + a1) + (a2 + a3));
  if (j == 0) atomicAdd(&cntC[c], (float)cnt);
}

__global__ void pn_kernel(const float* __restrict__ proto, const float* __restrict__ cntC,
                          float* __restrict__ pn) {
  int c = blockIdx.x, j = threadIdx.x;
  float p = proto[c * 256 + j] / fmaxf(cntC[c], 1.0f);
  float ss = p * p;
  __shared__ float red[4];
  __shared__ float bc;
#pragma unroll
  for (int off = 32; off >= 1; off >>= 1) ss += __shfl_down(ss, off);
  if ((j & 63) == 0) red[j >> 6] = ss;
  __syncthreads();
  if (j == 0) bc = sqrtf(red[0] + red[1] + red[2] + red[3]);
  __syncthreads();
  pn[c * 256 + j] = p / (bc + EPSF);
}

__global__ void out_kernel(const float* __restrict__ emb, const int* __restrict__ nodeidx,
                           const float* __restrict__ pn, float* __restrict__ outp) {
  int rr = blockIdx.x, j = threadIdx.x;
  int ni = nodeidx[rr];
  float v = emb[(size_t)ni * 256 + j];
  __shared__ float red[4];
  __shared__ float bc;
  float ss = v * v;
#pragma unroll
  for (int off = 32; off >= 1; off >>= 1) ss += __shfl_down(ss, off);
  if ((j & 63) == 0) red[j >> 6] = ss;
  __syncthreads();
  if (j == 0) bc = sqrtf(red[0] + red[1] + red[2] + red[3]);
  __syncthreads();
  float inv = 1.0f / (bc + EPSF);
  for (int c = 0; c < NCLSN; ++c) {
    float part = v * pn[c * 256 + j];
#pragma unroll
    for (int off = 32; off >= 1; off >>= 1) part += __shfl_down(part, off);
    __syncthreads();
    if ((j & 63) == 0) red[j >> 6] = part;
    __syncthreads();
    if (j == 0) outp[rr * NCLSN + c] = ((red[0] + red[1] + red[2] + red[3]) * inv) / 0.2f;
  }
}

// ---------------- host launcher ----------------
extern "C" void kernel_launch(void* const* d_in, const int* in_sizes, int n_in,
                              void* d_out, int out_size, void* d_ws, size_t ws_size,
                              hipStream_t stream) {
  (void)in_sizes; (void)n_in;
  const float* x      = (const float*)d_in[0];
  const float* cw     = (const float*)d_in[1];
  const float* alphaP = (const float*)d_in[2];
  const float* ps     = (const float*)d_in[3];
  const float* st     = (const float*)d_in[4];
  const float* bal    = (const float*)d_in[5];
  const float* W1     = (const float*)d_in[6];
  const float* W2     = (const float*)d_in[7];
  const int*   ei     = (const int*)d_in[8];
  const int*   labels = (const int*)d_in[9];
  const int*   nodei  = (const int*)d_in[10];
  float* out = (float*)d_out;

  char* base = (char*)d_ws;
  size_t off = 0;
  auto alloc = [&](size_t bytes) -> void* {
    void* p = base + off;
    off += (bytes + 255) & ~(size_t)255;
    return p;
  };
  float* fea    = (float*)alloc((size_t)NND * 256 * 4);      // 8 MB; reused as t2
  short* hhi    = (short*)alloc((size_t)NND * 512 * 2);      // 8 MB; reused as emb
  short* hlo    = (short*)alloc((size_t)NND * 512 * 2);      // 8 MB
  float* deg    = (float*)alloc((size_t)NND * 4);
  float* dinv   = (float*)alloc((size_t)NND * 4);
  int*   cntN   = (int*)alloc((size_t)NND * 4);
  int*   rpN    = (int*)alloc((size_t)(NND + 1) * 4);
  int*   curN   = (int*)alloc((size_t)NND * 4);
  int*   colN   = (int*)alloc((size_t)TOTE * 4);
  float* wN     = (float*)alloc((size_t)TOTE * 4);
  float* tkv    = (float*)alloc((size_t)NND * KTOP * 4);
  int*   tki    = (int*)alloc((size_t)NND * KTOP * 4);
  float* symw   = (float*)alloc((size_t)NND * KTOP * 4);
  int*   symf   = (int*)alloc((size_t)NND * KTOP * 4);
  int*   cntK   = (int*)alloc((size_t)NND * 4);
  int*   rpK    = (int*)alloc((size_t)(NND + 1) * 4);
  int*   curK   = (int*)alloc((size_t)NND * 4);
  int*   colK   = (int*)alloc((size_t)2 * NND * KTOP * 4);
  float* wKv    = (float*)alloc((size_t)2 * NND * KTOP * 4);
  float* proto  = (float*)alloc((size_t)NCLSN * 256 * 4);
  float* cntC   = (float*)alloc((size_t)NCLSN * 4);
  float* pn     = (float*)alloc((size_t)NCLSN * 256 * 4);

  // strip buffer last: largest strip that fits (evidence: ws ~256 MB -> RS=4096)
  size_t rem = (ws_size > off) ? (ws_size - off) : 0;
  int RS;
  if (rem >= (size_t)4096 * NND * 4) RS = 4096;
  else if (rem >= (size_t)2048 * NND * 4) RS = 2048;
  else if (rem >= (size_t)1024 * NND * 4) RS = 1024;
  else if (rem >= (size_t)512 * NND * 4) RS = 512;
  else {
    fill_f32<<<64, 256, 0, stream>>>(out, 12345.0f, out_size);
    return;
  }
  float* strip = (float*)alloc((size_t)RS * NND * 4);
  if (off > ws_size) {
    fill_f32<<<64, 256, 0, stream>>>(out, 12345.0f, out_size);
    return;
  }

  // aliases (lifetimes disjoint in stream order):
  float* t1  = strip;                         // strip dead after last topk
  float* h1  = strip + (size_t)NND * 256;
  float* t2  = fea;                           // fea dead after gemm_rm #1
  float* emb = (float*)hhi;                   // hhi/hlo dead after last strip GEMM

  init_misc<<<32, 256, 0, stream>>>(deg, curN, cntK, curK, proto, cntC);

  fea_elu_kernel<<<2048, 256, 0, stream>>>(x, cw, ps, st, fea);
  deg_kernel<<<NE / 256, 256, 0, stream>>>(ei, deg);
  dinv_kernel<<<NND / 256, 256, 0, stream>>>(deg, dinv, cntN);
  scan_kernel<<<1, 1024, 0, stream>>>(cntN, rpN);
  csr_norm_kernel<<<(TOTE + 255) / 256, 256, 0, stream>>>(ei, dinv, rpN, curN, colN, wN);
  agg_hn_kernel<<<NND, 256, 0, stream>>>(fea, rpN, colN, wN, bal, hhi, hlo);

  for (int s = 0; s < NND / RS; ++s) {
    gemm_strip_mfma<<<dim3(RS / 128, 64), 256, 0, stream>>>(hhi, hlo, strip, s * RS);
    topk_kernel<<<RS, 256, 0, stream>>>(strip, tkv, tki, s * RS);
  }

  sym_kernel<<<(NND * KTOP + 255) / 256, 256, 0, stream>>>(tkv, tki, symw, symf, cntK);
  scan_kernel<<<1, 1024, 0, stream>>>(cntK, rpK);
  csr_knn_kernel<<<(NND * KTOP + 255) / 256, 256, 0, stream>>>(tki, symw, symf, rpK, curK,
                                                               colK, wKv);

  gemm_rm_kernel<<<dim3(4, 128), 256, 0, stream>>>(fea, W1, t1, 256);
  spmm_kernel<<<NND, 256, 0, stream>>>(t1, rpN, colN, wN, rpK, colK, wKv, alphaP, h1, 1);
  gemm_rm_kernel<<<dim3(4, 128), 256, 0, stream>>>(h1, W2, t2, 256);
  spmm_kernel<<<NND, 256, 0, stream>>>(t2, rpN, colN, wN, rpK, colK, wKv, alphaP, emb, 0);

  proto_kernel<<<NCLSN * 8, 256, 0, stream>>>(emb, labels, nodei, proto, cntC);
  pn_kernel<<<NCLSN, 256, 0, stream>>>(proto, cntC, pn);
  out_kernel<<<NSELN, 256, 0, stream>>>(emb, nodei, pn, out);
}

// Round 12
// 657.844 us; speedup vs baseline: 3.0007x; 1.0375x over previous
//
#include <hip/hip_runtime.h>
#include <hip/hip_bf16.h>
#include <math.h>

#define NND 8192
#define FIN 256
#define NE 131072
#define TOTE (NE + NND)
#define KTOP 17
#define NSELN 4096
#define NCLSN 10
#define EPSF 1e-8f

#define BKK 32
#define LDP 68

typedef __attribute__((ext_vector_type(8))) short short8;
typedef __attribute__((ext_vector_type(4))) float f32x4;

// async 16B global->LDS (dest = wave-uniform base + lane*16, src per-lane)
#define GL16(gp, lp)                                              \
  __builtin_amdgcn_global_load_lds(                               \
      (const __attribute__((address_space(1))) void*)(gp),        \
      (__attribute__((address_space(3))) void*)(lp), 16, 0, 0)

// ---------------- utility fills ----------------
__global__ void fill_f32(float* p, float v, int n) {
  int i = blockIdx.x * blockDim.x + threadIdx.x;
  int st = gridDim.x * blockDim.x;
  for (; i < n; i += st) p[i] = v;
}

__global__ void init_misc(float* deg, int* curN, int* cntK, int* curK,
                          float* proto, float* cntC) {
  int i = blockIdx.x * blockDim.x + threadIdx.x;
  if (i < NND) {
    deg[i] = 1.0f;
    curN[i] = 0;
    cntK[i] = KTOP;
    curK[i] = 0;
  }
  if (i < NCLSN * 256) proto[i] = 0.0f;
  if (i < NCLSN) cntC[i] = 0.0f;
}

__device__ __forceinline__ void split_bf16(float v, short& h, short& l) {
  __hip_bfloat16 bh = __float2bfloat16(v);
  float fh = __bfloat162float(bh);
  __hip_bfloat16 bl = __float2bfloat16(v - fh);
  h = *reinterpret_cast<short*>(&bh);
  l = *reinterpret_cast<short*>(&bl);
}

// ---------------- fea = elu(x * (c0*ps + c1*st)) ----------------
__global__ void fea_elu_kernel(const float* __restrict__ x, const float* __restrict__ cw,
                               const float* __restrict__ ps, const float* __restrict__ st,
                               float* __restrict__ fea) {
  int i = blockIdx.x * blockDim.x + threadIdx.x;
  const int total = NND * FIN / 4;
  int stride = gridDim.x * blockDim.x;
  float c0 = cw[0], c1 = cw[1];
  const float4* x4 = (const float4*)x;
  const float4* ps4 = (const float4*)ps;
  const float4* st4 = (const float4*)st;
  float4* f4 = (float4*)fea;
  for (; i < total; i += stride) {
    int j4 = i & (FIN / 4 - 1);
    float4 xv = x4[i], pv = ps4[j4], sv = st4[j4];
    float4 r;
    float t;
    t = xv.x * (c0 * pv.x + c1 * sv.x); r.x = t > 0.0f ? t : expm1f(t);
    t = xv.y * (c0 * pv.y + c1 * sv.y); r.y = t > 0.0f ? t : expm1f(t);
    t = xv.z * (c0 * pv.z + c1 * sv.z); r.z = t > 0.0f ? t : expm1f(t);
    t = xv.w * (c0 * pv.w + c1 * sv.w); r.w = t > 0.0f ? t : expm1f(t);
    f4[i] = r;
  }
}

// ---------------- degree (dst occurrences) ----------------
__global__ void deg_kernel(const int* __restrict__ ei, float* __restrict__ deg) {
  int e = blockIdx.x * blockDim.x + threadIdx.x;
  if (e < NE) atomicAdd(&deg[ei[NE + e]], 1.0f);
}

__global__ void dinv_kernel(const float* __restrict__ deg, float* __restrict__ dinv,
                            int* __restrict__ cntN) {
  int i = blockIdx.x * blockDim.x + threadIdx.x;
  if (i < NND) {
    float d = deg[i];
    dinv[i] = 1.0f / sqrtf(d);
    cntN[i] = (int)(d + 0.5f);
  }
}

// ---------------- exclusive scan of 8192 ints, one block of 1024 ----------------
__global__ __launch_bounds__(1024) void scan_kernel(const int* __restrict__ cnt,
                                                    int* __restrict__ rowptr) {
  __shared__ int wtot[17];
  int tid = threadIdx.x;
  int lane = tid & 63;
  int v[8], pre[8];
  int s = 0;
  int base = tid * 8;
#pragma unroll
  for (int u = 0; u < 8; ++u) { v[u] = cnt[base + u]; s += v[u]; pre[u] = s; }
  int tsum = s;
  int x = tsum;
#pragma unroll
  for (int off = 1; off < 64; off <<= 1) {
    int t = __shfl_up(x, off);
    if (lane >= off) x += t;
  }
  if (lane == 63) wtot[tid >> 6] = x;
  __syncthreads();
  if (tid == 0) {
    int run = 0;
    for (int w = 0; w < 16; ++w) { int t = wtot[w]; wtot[w] = run; run += t; }
    wtot[16] = run;
  }
  __syncthreads();
  int basex = wtot[tid >> 6] + (x - tsum);
#pragma unroll
  for (int u = 0; u < 8; ++u) rowptr[base + u] = basex + pre[u] - v[u];
  if (tid == 0) rowptr[NND] = wtot[16];
}

// ---------------- CSR fill for normalized graph (row = dst, col = src) ----------------
__global__ void csr_norm_kernel(const int* __restrict__ ei, const float* __restrict__ dinv,
                                const int* __restrict__ rowptr, int* __restrict__ cur,
                                int* __restrict__ col, float* __restrict__ w) {
  int e = blockIdx.x * blockDim.x + threadIdx.x;
  if (e >= TOTE) return;
  int s, d;
  if (e < NE) { s = ei[e]; d = ei[NE + e]; } else { s = e - NE; d = s; }
  int pos = atomicAdd(&cur[d], 1);
  int at = rowptr[d] + pos;
  col[at] = s;
  w[at] = dinv[s] * dinv[d];
}

// ---- agg + h + row-normalize -> hi/lo bf16 split; LDS-staged edge list ----
__global__ __launch_bounds__(256) void agg_hn_kernel(const float* __restrict__ fea,
    const int* __restrict__ rpN, const int* __restrict__ colN, const float* __restrict__ wN,
    const float* __restrict__ bal, short* __restrict__ hhi, short* __restrict__ hlo) {
  int i = blockIdx.x, j = threadIdx.x;
  __shared__ int colS[128];
  __shared__ float wS[128];
  float f = fea[(size_t)i * 256 + j];
  float acc = 0.0f;
  int e0 = rpN[i], e1 = rpN[i + 1];
  for (int base = e0; base < e1; base += 128) {
    int cnt = e1 - base;
    if (cnt > 128) cnt = 128;
    __syncthreads();
    if (j < cnt) { colS[j] = colN[base + j]; wS[j] = wN[base + j]; }
    __syncthreads();
    for (int t = 0; t < cnt; ++t)
      acc += wS[t] * fea[(size_t)colS[t] * 256 + j];
  }
  float hl = f * bal[j];
  float hh = acc * bal[256 + j];
  float ss = hl * hl + hh * hh;
  __shared__ float red[4];
  __shared__ float bc;
  __syncthreads();
#pragma unroll
  for (int off = 32; off >= 1; off >>= 1) ss += __shfl_down(ss, off);
  if ((j & 63) == 0) red[j >> 6] = ss;
  __syncthreads();
  if (j == 0) bc = sqrtf(red[0] + red[1] + red[2] + red[3]);
  __syncthreads();
  float inv = 1.0f / (bc + EPSF);
  short h0, l0, h1, l1;
  split_bf16(hl * inv, h0, l0);
  split_bf16(hh * inv, h1, l1);
  hhi[(size_t)i * 512 + j] = h0;
  hlo[(size_t)i * 512 + j] = l0;
  hhi[(size_t)i * 512 + 256 + j] = h1;
  hlo[(size_t)i * 512 + 256 + j] = l1;
}

// ======== shared MFMA core for the sims GEMM tile (128x128, split-bf16) ========
// Computes acc = hn[arow0..+128] . hn[brow0..+128]^T via global_load_lds staging.
#define GEMM_TILE_BODY(arow0, brow0)                                              \
  const short* sArr = (wid == 0 || wid == 2) ? hhi : hlo;                         \
  int sRow0 = (wid < 2) ? (arow0) : (brow0);                                      \
  short* sLds = &smem[wid][0];                                                    \
  int sr = lane >> 2;                                                             \
  int cSrc0 = lane & 3;                                                           \
  f32x4 acc[4][4];                                                                \
  _Pragma("unroll") for (int m = 0; m < 4; ++m)                                   \
      _Pragma("unroll") for (int n = 0; n < 4; ++n)                               \
          acc[m][n] = (f32x4){0.f, 0.f, 0.f, 0.f};                                \
  for (int k0 = 0; k0 < 512; k0 += 32) {                                          \
    __syncthreads();                                                              \
    _Pragma("unroll") for (int q = 0; q < 8; ++q) {                               \
      int r = q * 16 + sr;                                                        \
      int cSrc = cSrc0 ^ ((r >> 1) & 3);                                          \
      const short* gp = sArr + (size_t)(sRow0 + r) * 512 + k0 + cSrc * 8;         \
      GL16(gp, sLds + q * 512);                                                   \
    }                                                                             \
    __syncthreads();                                                              \
    short8 ah[4], al[4], bh[4], bl[4];                                            \
    _Pragma("unroll") for (int m = 0; m < 4; ++m) {                               \
      int rr = wm * 64 + m * 16 + (lane & 15);                                    \
      int ca = (lane >> 4) ^ ((rr >> 1) & 3);                                     \
      ah[m] = *(const short8*)&smem[0][rr * 32 + ca * 8];                         \
      al[m] = *(const short8*)&smem[1][rr * 32 + ca * 8];                         \
      int cc = wn * 64 + m * 16 + (lane & 15);                                    \
      int cb = (lane >> 4) ^ ((cc >> 1) & 3);                                     \
      bh[m] = *(const short8*)&smem[2][cc * 32 + cb * 8];                         \
      bl[m] = *(const short8*)&smem[3][cc * 32 + cb * 8];                         \
    }                                                                             \
    _Pragma("unroll") for (int m = 0; m < 4; ++m)                                 \
        _Pragma("unroll") for (int n = 0; n < 4; ++n)                             \
            acc[m][n] = __builtin_amdgcn_mfma_f32_16x16x32_bf16(ah[m], bh[n],     \
                                                                acc[m][n], 0, 0, 0); \
    _Pragma("unroll") for (int m = 0; m < 4; ++m)                                 \
        _Pragma("unroll") for (int n = 0; n < 4; ++n)                             \
            acc[m][n] = __builtin_amdgcn_mfma_f32_16x16x32_bf16(ah[m], bl[n],     \
                                                                acc[m][n], 0, 0, 0); \
    _Pragma("unroll") for (int m = 0; m < 4; ++m)                                 \
        _Pragma("unroll") for (int n = 0; n < 4; ++n)                             \
            acc[m][n] = __builtin_amdgcn_mfma_f32_16x16x32_bf16(al[m], bh[n],     \
                                                                acc[m][n], 0, 0, 0); \
  }

// ---- symmetric strip GEMM: diag upper-tri tiles (mirror write) + cross tiles
// (normal write + transposed float4 write into T). Exploits sims symmetry:
// MFMA makes (i,j) and (j,i) bitwise identical, so mirror writes are exact.
__global__ __launch_bounds__(256, 3) void gemm_sym_strip(const short* __restrict__ hhi,
                                                         const short* __restrict__ hlo,
                                                         float* __restrict__ strip,
                                                         float* __restrict__ T, int r0) {
  __shared__ short smem[4][128 * 32];
  int id = blockIdx.x;
  int tid = threadIdx.x;
  int lane = tid & 63;
  int wid = tid >> 6;
  int wm = wid >> 1, wn = wid & 1;

  int by, bxl, cross = 0;
  if (id < 528) {                     // upper-tri diag tile (32x32 tile grid)
    by = 0;
    while (by < 31 && (by + 1) * 32 - ((by + 1) * by) / 2 <= id) ++by;
    int off = by * 32 - (by * (by - 1)) / 2;
    bxl = by + (id - off);
  } else {                            // cross tile (strip0 only)
    int idc = id - 528;
    by = idc >> 5;
    bxl = idc & 31;
    cross = 1;
  }
  int arow0 = r0 + by * 128;
  int brow0 = cross ? (4096 + bxl * 128) : (r0 + bxl * 128);

  GEMM_TILE_BODY(arow0, brow0)

#pragma unroll
  for (int m = 0; m < 4; ++m) {
    int lrG = arow0 + wm * 64 + m * 16 + ((lane >> 4) << 2);   // global row
#pragma unroll
    for (int n = 0; n < 4; ++n) {
      int gc = brow0 + wn * 64 + n * 16 + (lane & 15);         // global col
#pragma unroll
      for (int r = 0; r < 4; ++r)
        strip[(size_t)(lrG - r0 + r) * NND + gc] = acc[m][n][r];
      if (!cross) {
        // mirror into (col, row) — both within this strip's row range
#pragma unroll
        for (int r = 0; r < 4; ++r)
          strip[(size_t)(gc - r0) * NND + (lrG + r)] = acc[m][n][r];
      } else {
        // transposed block for strip 1: T[row = gc-4096][col = lrG..+3]
        *(f32x4*)&T[(size_t)(gc - 4096) * 4096 + lrG] = acc[m][n];
      }
    }
  }
}

// ---- fallback full strip GEMM (no symmetry) ----
__global__ __launch_bounds__(256, 3) void gemm_strip_mfma(const short* __restrict__ hhi,
                                                          const short* __restrict__ hlo,
                                                          float* __restrict__ strip, int r0) {
  __shared__ short smem[4][128 * 32];
  int by = blockIdx.x;
  int bx = blockIdx.y;
  int tid = threadIdx.x;
  int lane = tid & 63;
  int wid = tid >> 6;
  int wm = wid >> 1, wn = wid & 1;
  int arow0 = r0 + by * 128;
  int brow0 = bx * 128;

  GEMM_TILE_BODY(arow0, brow0)

#pragma unroll
  for (int m = 0; m < 4; ++m) {
    int lr = by * 128 + wm * 64 + m * 16 + ((lane >> 4) << 2);
#pragma unroll
    for (int n = 0; n < 4; ++n) {
      int gc = bx * 128 + wn * 64 + n * 16 + (lane & 15);
#pragma unroll
      for (int r = 0; r < 4; ++r)
        strip[(size_t)(lr + r) * NND + gc] = acc[m][n][r];
    }
  }
}

// ---- top-17 per strip row, dual-source (left = cols 0..4095, right = 4096..8191) ----
__global__ __launch_bounds__(256) void topk_kernel(const float* __restrict__ left, int ldl,
                                                   const float* __restrict__ right, int ldr,
                                                   float* __restrict__ tkv,
                                                   int* __restrict__ tki, int r0) {
  int b = blockIdx.x;
  int gi = r0 + b;
  int tid = threadIdx.x;
  int lane = tid & 63, wvid = tid >> 6;
  float v[32];
#pragma unroll
  for (int u = 0; u < 32; ++u)
    v[u] = (u < 16) ? left[(size_t)b * ldl + u * 256 + tid]
                    : right[(size_t)b * ldr + (u - 16) * 256 + tid];
  float lmx = v[0];
  int lmu = 0;
#pragma unroll
  for (int u = 1; u < 32; ++u)
    if (v[u] > lmx) { lmx = v[u]; lmu = u; }

  __shared__ float swv[2][4];
  __shared__ int swi[2][4];
  for (int r = 0; r < KTOP; ++r) {
    int p = r & 1;
    float mx = lmx;
    int mcol = lmu * 256 + tid;
#pragma unroll
    for (int off = 32; off >= 1; off >>= 1) {
      float ov = __shfl_down(mx, off);
      int oc = __shfl_down(mcol, off);
      if (ov > mx || (ov == mx && oc < mcol)) { mx = ov; mcol = oc; }
    }
    if (lane == 0) { swv[p][wvid] = mx; swi[p][wvid] = mcol; }
    __syncthreads();
    float bb = swv[p][0];
    int bc = swi[p][0];
#pragma unroll
    for (int w = 1; w < 4; ++w) {
      float bw = swv[p][w];
      int iw = swi[p][w];
      if (bw > bb || (bw == bb && iw < bc)) { bb = bw; bc = iw; }
    }
    if (tid == 0) { tkv[gi * KTOP + r] = bb; tki[gi * KTOP + r] = bc; }
    if ((bc & 255) == tid) {
      int uu = bc >> 8;
#pragma unroll
      for (int u = 0; u < 32; ++u)
        if (u == uu) v[u] = -3.0e38f;
      lmx = v[0]; lmu = 0;
#pragma unroll
      for (int u = 1; u < 32; ++u)
        if (v[u] > lmx) { lmx = v[u]; lmu = u; }
    }
  }
}

// ---------------- symmetrized kNN weights + mirror counts ----------------
__global__ void sym_kernel(const float* __restrict__ tkv, const int* __restrict__ tki,
                           float* __restrict__ symw, int* __restrict__ symflag,
                           int* __restrict__ cntK) {
  int s = blockIdx.x * blockDim.x + threadIdx.x;
  if (s >= NND * KTOP) return;
  int i = s / KTOP;
  int j = tki[s];
  float vv = tkv[s];
  float v2 = 0.0f;
  int found = 0;
#pragma unroll
  for (int t = 0; t < KTOP; ++t) {
    if (tki[j * KTOP + t] == i) { found = 1; v2 = tkv[j * KTOP + t]; }
  }
  float w = found ? 0.5f * (vv + v2) : vv;
  w = fmaxf(w, 0.0f);
  symw[s] = w;
  symflag[s] = 1 - found;
  if (!found) atomicAdd(&cntK[j], 1);
}

__global__ void csr_knn_kernel(const int* __restrict__ tki, const float* __restrict__ symw,
                               const int* __restrict__ symflag, const int* __restrict__ rpK,
                               int* __restrict__ curK, int* __restrict__ colK,
                               float* __restrict__ wK) {
  int s = blockIdx.x * blockDim.x + threadIdx.x;
  if (s >= NND * KTOP) return;
  int i = s / KTOP, k = s - i * KTOP;
  int j = tki[s];
  float w = symw[s];
  int at = rpK[i] + k;
  colK[at] = j;
  wK[at] = w;
  if (symflag[s]) {
    int p = atomicAdd(&curK[j], 1);
    int at2 = rpK[j] + KTOP + p;
    colK[at2] = i;
    wK[at2] = w;
  }
}

// ---------------- dense C(8192x256) = A(8192xK) @ B(Kx256) ----------------
__global__ __launch_bounds__(256) void gemm_rm_kernel(const float* __restrict__ A,
                                                      const float* __restrict__ B,
                                                      float* __restrict__ C, int K) {
  __shared__ float As[BKK * LDP];
  __shared__ float Bs[BKK * LDP];
  int bj = blockIdx.x, bi = blockIdx.y;
  int tid = threadIdx.x;
  int tx = tid & 15, ty = tid >> 4;
  const float4* A4 = (const float4*)A;
  const float4* B4 = (const float4*)B;
  int K4 = K >> 2;
  float acc[4][4] = {{0.f}};
  for (int kt = 0; kt < K / BKK; ++kt) {
    __syncthreads();
    {
      int rr = tid >> 3, k4 = tid & 7;
#pragma unroll
      for (int h = 0; h < 2; ++h) {
        int row = rr + h * 32;
        float4 a = A4[(size_t)(bi * 64 + row) * K4 + kt * 8 + k4];
        As[(k4 * 4 + 0) * LDP + row] = a.x;
        As[(k4 * 4 + 1) * LDP + row] = a.y;
        As[(k4 * 4 + 2) * LDP + row] = a.z;
        As[(k4 * 4 + 3) * LDP + row] = a.w;
      }
      int kk = tid >> 4, c4 = tid & 15;
#pragma unroll
      for (int h = 0; h < 2; ++h) {
        int krow = kk + h * 16;
        float4 b = B4[(size_t)(kt * 32 + krow) * 64 + bj * 16 + c4];
        *(float4*)&Bs[krow * LDP + c4 * 4] = b;
      }
    }
    __syncthreads();
#pragma unroll
    for (int k = 0; k < BKK; ++k) {
      float4 av = *(const float4*)&As[k * LDP + ty * 4];
      float4 bv = *(const float4*)&Bs[k * LDP + tx * 4];
      float aa[4] = {av.x, av.y, av.z, av.w};
      float bb[4] = {bv.x, bv.y, bv.z, bv.w};
#pragma unroll
      for (int q = 0; q < 4; ++q)
#pragma unroll
        for (int c = 0; c < 4; ++c) acc[q][c] = fmaf(aa[q], bb[c], acc[q][c]);
    }
  }
  int r0 = bi * 64 + ty * 4, c0 = bj * 64 + tx * 4;
#pragma unroll
  for (int q = 0; q < 4; ++q) {
    float4 v = make_float4(acc[q][0], acc[q][1], acc[q][2], acc[q][3]);
    *(float4*)&C[(size_t)(r0 + q) * 256 + c0] = v;
  }
}

// ---- SpMM: out = alpha*Anorm@X + (1-alpha)*Wsym@X (+relu) ----
__global__ __launch_bounds__(256) void spmm_kernel(const float* __restrict__ X,
    const int* __restrict__ rpN, const int* __restrict__ colN, const float* __restrict__ wN,
    const int* __restrict__ rpK, const int* __restrict__ colK, const float* __restrict__ wK,
    const float* __restrict__ alphaP, float* __restrict__ out, int doRelu) {
  int i = blockIdx.x;
  int tid = threadIdx.x;
  int g = tid >> 6;
  int jt = tid & 63;
  float alpha = alphaP[0];
  const float4* X4 = (const float4*)X;
  __shared__ int colS[256];
  __shared__ float wS[256];
  float ax = 0.f, ay = 0.f, az = 0.f, aw = 0.f;
  float kx = 0.f, ky = 0.f, kz = 0.f, kw = 0.f;
  int e0 = rpN[i], e1 = rpN[i + 1];
  for (int base = e0; base < e1; base += 256) {
    int cnt = e1 - base;
    if (cnt > 256) cnt = 256;
    __syncthreads();
    if (tid < cnt) { colS[tid] = colN[base + tid]; wS[tid] = wN[base + tid]; }
    __syncthreads();
    for (int t = g; t < cnt; t += 4) {
      float w = wS[t];
      float4 xv = X4[(size_t)colS[t] * 64 + jt];
      ax = fmaf(w, xv.x, ax); ay = fmaf(w, xv.y, ay);
      az = fmaf(w, xv.z, az); aw = fmaf(w, xv.w, aw);
    }
  }
  e0 = rpK[i]; e1 = rpK[i + 1];
  for (int base = e0; base < e1; base += 256) {
    int cnt = e1 - base;
    if (cnt > 256) cnt = 256;
    __syncthreads();
    if (tid < cnt) { colS[tid] = colK[base + tid]; wS[tid] = wK[base + tid]; }
    __syncthreads();
    for (int t = g; t < cnt; t += 4) {
      float w = wS[t];
      float4 xv = X4[(size_t)colS[t] * 64 + jt];
      kx = fmaf(w, xv.x, kx); ky = fmaf(w, xv.y, ky);
      kz = fmaf(w, xv.z, kz); kw = fmaf(w, xv.w, kw);
    }
  }
  float b = 1.0f - alpha;
  __shared__ float4 red[256];
  __syncthreads();
  red[tid] = make_float4(alpha * ax + b * kx, alpha * ay + b * ky,
                         alpha * az + b * kz, alpha * aw + b * kw);
  __syncthreads();
  if (g == 0) {
    float4 r0 = red[jt], r1 = red[64 + jt], r2 = red[128 + jt], r3 = red[192 + jt];
    float4 r = make_float4(r0.x + r1.x + r2.x + r3.x, r0.y + r1.y + r2.y + r3.y,
                           r0.z + r1.z + r2.z + r3.z, r0.w + r1.w + r2.w + r3.w);
    if (doRelu) {
      r.x = fmaxf(r.x, 0.f); r.y = fmaxf(r.y, 0.f);
      r.z = fmaxf(r.z, 0.f); r.w = fmaxf(r.w, 0.f);
    }
    *(float4*)&out[(size_t)i * 256 + jt * 4] = r;
  }
}

// ---- prototypes: class-owned scan, no hot atomics ----
__global__ __launch_bounds__(256) void proto_kernel(const float* __restrict__ emb,
                                                    const int* __restrict__ labels,
                                                    const int* __restrict__ nodeidx,
                                                    float* __restrict__ proto,
                                                    float* __restrict__ cntC) {
  int c = blockIdx.x >> 3;
  int chunk = blockIdx.x & 7;
  int j = threadIdx.x;
  __shared__ int labL[512];
  __shared__ int niL[512];
  int r0 = chunk * 512;
  labL[j] = labels[r0 + j];
  labL[256 + j] = labels[r0 + 256 + j];
  niL[j] = nodeidx[r0 + j];
  niL[256 + j] = nodeidx[r0 + 256 + j];
  __syncthreads();
  float a0 = 0.f, a1 = 0.f, a2 = 0.f, a3 = 0.f;
  int cnt = 0;
  for (int r = 0; r < 512; r += 4) {
    int l0 = labL[r], l1 = labL[r + 1], l2 = labL[r + 2], l3 = labL[r + 3];
    if (l0 == c) a0 += emb[(size_t)niL[r] * 256 + j];
    if (l1 == c) a1 += emb[(size_t)niL[r + 1] * 256 + j];
    if (l2 == c) a2 += emb[(size_t)niL[r + 2] * 256 + j];
    if (l3 == c) a3 += emb[(size_t)niL[r + 3] * 256 + j];
    cnt += (l0 == c) + (l1 == c) + (l2 == c) + (l3 == c);
  }
  atomicAdd(&proto[c * 256 + j], (a0 + a1) + (a2 + a3));
  if (j == 0) atomicAdd(&cntC[c], (float)cnt);
}

__global__ void pn_kernel(const float* __restrict__ proto, const float* __restrict__ cntC,
                          float* __restrict__ pn) {
  int c = blockIdx.x, j = threadIdx.x;
  float p = proto[c * 256 + j] / fmaxf(cntC[c], 1.0f);
  float ss = p * p;
  __shared__ float red[4];
  __shared__ float bc;
#pragma unroll
  for (int off = 32; off >= 1; off >>= 1) ss += __shfl_down(ss, off);
  if ((j & 63) == 0) red[j >> 6] = ss;
  __syncthreads();
  if (j == 0) bc = sqrtf(red[0] + red[1] + red[2] + red[3]);
  __syncthreads();
  pn[c * 256 + j] = p / (bc + EPSF);
}

__global__ void out_kernel(const float* __restrict__ emb, const int* __restrict__ nodeidx,
                           const float* __restrict__ pn, float* __restrict__ outp) {
  int rr = blockIdx.x, j = threadIdx.x;
  int ni = nodeidx[rr];
  float v = emb[(size_t)ni * 256 + j];
  __shared__ float red[4];
  __shared__ float bc;
  float ss = v * v;
#pragma unroll
  for (int off = 32; off >= 1; off >>= 1) ss += __shfl_down(ss, off);
  if ((j & 63) == 0) red[j >> 6] = ss;
  __syncthreads();
  if (j == 0) bc = sqrtf(red[0] + red[1] + red[2] + red[3]);
  __syncthreads();
  float inv = 1.0f / (bc + EPSF);
  for (int c = 0; c < NCLSN; ++c) {
    float part = v * pn[c * 256 + j];
#pragma unroll
    for (int off = 32; off >= 1; off >>= 1) part += __shfl_down(part, off);
    __syncthreads();
    if ((j & 63) == 0) red[j >> 6] = part;
    __syncthreads();
    if (j == 0) outp[rr * NCLSN + c] = ((red[0] + red[1] + red[2] + red[3]) * inv) / 0.2f;
  }
}

// ---------------- host launcher ----------------
extern "C" void kernel_launch(void* const* d_in, const int* in_sizes, int n_in,
                              void* d_out, int out_size, void* d_ws, size_t ws_size,
                              hipStream_t stream) {
  (void)in_sizes; (void)n_in;
  const float* x      = (const float*)d_in[0];
  const float* cw     = (const float*)d_in[1];
  const float* alphaP = (const float*)d_in[2];
  const float* ps     = (const float*)d_in[3];
  const float* st     = (const float*)d_in[4];
  const float* bal    = (const float*)d_in[5];
  const float* W1     = (const float*)d_in[6];
  const float* W2     = (const float*)d_in[7];
  const int*   ei     = (const int*)d_in[8];
  const int*   labels = (const int*)d_in[9];
  const int*   nodei  = (const int*)d_in[10];
  float* out = (float*)d_out;

  char* base = (char*)d_ws;
  size_t off = 0;
  auto alloc = [&](size_t bytes) -> void* {
    void* p = base + off;
    off += (bytes + 255) & ~(size_t)255;
    return p;
  };
  float* fea    = (float*)alloc((size_t)NND * 256 * 4);      // 8 MB; reused as t2
  short* hhi    = (short*)alloc((size_t)NND * 512 * 2);      // 8 MB; reused as emb
  short* hlo    = (short*)alloc((size_t)NND * 512 * 2);      // 8 MB
  float* deg    = (float*)alloc((size_t)NND * 4);
  float* dinv   = (float*)alloc((size_t)NND * 4);
  int*   cntN   = (int*)alloc((size_t)NND * 4);
  int*   rpN    = (int*)alloc((size_t)(NND + 1) * 4);
  int*   curN   = (int*)alloc((size_t)NND * 4);
  int*   colN   = (int*)alloc((size_t)TOTE * 4);
  float* wN     = (float*)alloc((size_t)TOTE * 4);
  float* tkv    = (float*)alloc((size_t)NND * KTOP * 4);
  int*   tki    = (int*)alloc((size_t)NND * KTOP * 4);
  float* symw   = (float*)alloc((size_t)NND * KTOP * 4);
  int*   symf   = (int*)alloc((size_t)NND * KTOP * 4);
  int*   cntK   = (int*)alloc((size_t)NND * 4);
  int*   rpK    = (int*)alloc((size_t)(NND + 1) * 4);
  int*   curK   = (int*)alloc((size_t)NND * 4);
  int*   colK   = (int*)alloc((size_t)2 * NND * KTOP * 4);
  float* wKv    = (float*)alloc((size_t)2 * NND * KTOP * 4);
  float* proto  = (float*)alloc((size_t)NCLSN * 256 * 4);
  float* cntC   = (float*)alloc((size_t)NCLSN * 4);
  float* pn     = (float*)alloc((size_t)NCLSN * 256 * 4);

  // Preferred: symmetric 2-strip scheme (strip 4096 rows + 64 MB transpose buf)
  size_t rem = (ws_size > off) ? (ws_size - off) : 0;
  size_t needSym = (size_t)4096 * NND * 4 + (size_t)4096 * 4096 * 4;
  int useSym = (rem >= needSym) ? 1 : 0;
  float* strip = nullptr;
  float* T = nullptr;
  int RS = 0;
  if (useSym) {
    strip = (float*)alloc((size_t)4096 * NND * 4);
    T = (float*)alloc((size_t)4096 * 4096 * 4);
    RS = 4096;
  } else {
    if (rem >= (size_t)2048 * NND * 4) RS = 2048;
    else if (rem >= (size_t)1024 * NND * 4) RS = 1024;
    else if (rem >= (size_t)512 * NND * 4) RS = 512;
    else {
      fill_f32<<<64, 256, 0, stream>>>(out, 12345.0f, out_size);
      return;
    }
    strip = (float*)alloc((size_t)RS * NND * 4);
  }
  if (off > ws_size) {
    fill_f32<<<64, 256, 0, stream>>>(out, 12345.0f, out_size);
    return;
  }

  // aliases (lifetimes disjoint in stream order):
  float* t1  = strip;                         // strip dead after last topk
  float* h1  = strip + (size_t)NND * 256;
  float* t2  = fea;                           // fea dead after gemm_rm #1
  float* emb = (float*)hhi;                   // hhi/hlo dead after last strip GEMM

  init_misc<<<32, 256, 0, stream>>>(deg, curN, cntK, curK, proto, cntC);

  fea_elu_kernel<<<2048, 256, 0, stream>>>(x, cw, ps, st, fea);
  deg_kernel<<<NE / 256, 256, 0, stream>>>(ei, deg);
  dinv_kernel<<<NND / 256, 256, 0, stream>>>(deg, dinv, cntN);
  scan_kernel<<<1, 1024, 0, stream>>>(cntN, rpN);
  csr_norm_kernel<<<(TOTE + 255) / 256, 256, 0, stream>>>(ei, dinv, rpN, curN, colN, wN);
  agg_hn_kernel<<<NND, 256, 0, stream>>>(fea, rpN, colN, wN, bal, hhi, hlo);

  if (useSym) {
    // strip 0: rows 0..4095 -> 528 upper-tri diag tiles + 1024 cross tiles
    gemm_sym_strip<<<1552, 256, 0, stream>>>(hhi, hlo, strip, T, 0);
    topk_kernel<<<4096, 256, 0, stream>>>(strip, NND, strip + 4096, NND, tkv, tki, 0);
    // strip 1: rows 4096..8191 -> 528 diag tiles; left half comes from T
    gemm_sym_strip<<<528, 256, 0, stream>>>(hhi, hlo, strip, T, 4096);
    topk_kernel<<<4096, 256, 0, stream>>>(T, 4096, strip + 4096, NND, tkv, tki, 4096);
  } else {
    for (int s = 0; s < NND / RS; ++s) {
      gemm_strip_mfma<<<dim3(RS / 128, 64), 256, 0, stream>>>(hhi, hlo, strip, s * RS);
      topk_kernel<<<RS, 256, 0, stream>>>(strip, NND, strip + 4096, NND, tkv, tki, s * RS);
    }
  }

  sym_kernel<<<(NND * KTOP + 255) / 256, 256, 0, stream>>>(tkv, tki, symw, symf, cntK);
  scan_kernel<<<1, 1024, 0, stream>>>(cntK, rpK);
  csr_knn_kernel<<<(NND * KTOP + 255) / 256, 256, 0, stream>>>(tki, symw, symf, rpK, curK,
                                                               colK, wKv);

  gemm_rm_kernel<<<dim3(4, 128), 256, 0, stream>>>(fea, W1, t1, 256);
  spmm_kernel<<<NND, 256, 0, stream>>>(t1, rpN, colN, wN, rpK, colK, wKv, alphaP, h1, 1);
  gemm_rm_kernel<<<dim3(4, 128), 256, 0, stream>>>(h1, W2, t2, 256);
  spmm_kernel<<<NND, 256, 0, stream>>>(t2, rpN, colN, wN, rpK, colK, wKv, alphaP, emb, 0);

  proto_kernel<<<NCLSN * 8, 256, 0, stream>>>(emb, labels, nodei, proto, cntC);
  pn_kernel<<<NCLSN, 256, 0, stream>>>(proto, cntC, pn);
  out_kernel<<<NSELN, 256, 0, stream>>>(emb, nodei, pn, out);
}